// Round 1
// baseline (809.206 us; speedup 1.0000x reference)
//
#include <hip/hip_runtime.h>
#include <hip/hip_bf16.h>
#include <math.h>

// ---------------------------------------------------------------------------
// Problem constants
// ---------------------------------------------------------------------------
#define NBATCH 1024
#define LIN    6000
#define HCATW  7640       // 20*375 + 20*7
#define HID    100

// conv-chain chunking: T=54 final(375-res) positions per block, 7 chunks.
// R8: T=54 makes every stage's task count a multiple of 8 (28,16,16,4):
//   JOUT chain = 8T+14, 4T+6, 2T+2, T = 446, 222, 110, 54
//   s1 goes from 12 tasks (2/1 imbalance) to 16 (2/2 balanced), and 7 chunks
//   instead of 9 amortize per-chunk cost: -15% total wave-instrs, -21% critical.
// Costs LDS 52.7KB -> 64.1KB => 2 blocks/CU (was 3).
#define TCH   54
#define NCHK  7

#define ASZ 7104            // max(x-buf 3*894=2682, s1-out 32*222=7104)
#define BSZ 8920            // max(s0-out 20*446=8920, s2-out 64*110=7040)

// repacked-weight offsets (floats) inside wrep  (unchanged from T=44 version)
#define W0OFF 0             // 4ocg*3ic*16  = 192
#define W1OFF 192           // 4*20*24      = 1920
#define W2OFF 2112          // 8*32*24      = 6144
#define W3OFF 8256          // 4*64*16      = 4096
#define B0OFF 12352
#define B1OFF 12372
#define B2OFF 12404
#define B3OFF 12468
#define WREPSZ 12496

// fc01: samples per block
#define FCNS 4

// ---------------------------------------------------------------------------
// Weight repack
// ---------------------------------------------------------------------------
__device__ __forceinline__ void pack_one(int idx, int OC, int IC, int OCG,
                                         int OPG, int WSTR,
                                         const float* __restrict__ w,
                                         float* __restrict__ dst)
{
    if (idx >= OCG * IC * WSTR) return;
    int ocg = idx / (IC * WSTR);
    int r   = idx - ocg * (IC * WSTR);
    int ic  = r / WSTR;
    int q   = r - ic * WSTR;
    int o   = q / 3, k = q - o * 3;
    int oc  = ocg * OPG + o;
    dst[idx] = (o < OPG && oc < OC) ? w[(oc * IC + ic) * 3 + k] : 0.f;
}

__global__ __launch_bounds__(256) void repack_kernel(
    const float* __restrict__ w0, const float* __restrict__ b0,
    const float* __restrict__ w1, const float* __restrict__ b1,
    const float* __restrict__ w2, const float* __restrict__ b2,
    const float* __restrict__ w3, const float* __restrict__ b3,
    float* __restrict__ wrep)
{
    int idx = blockIdx.x * 256 + threadIdx.x;
    pack_one(idx, 20,  3, 4, 5, 16, w0, wrep + W0OFF);
    pack_one(idx, 32, 20, 4, 8, 24, w1, wrep + W1OFF);
    pack_one(idx, 64, 32, 8, 8, 24, w2, wrep + W2OFF);
    pack_one(idx, 20, 64, 4, 5, 16, w3, wrep + W3OFF);
    if (idx < 20)            wrep[B0OFF + idx] = b0[idx];
    else if (idx < 52)  { int i = idx - 20;  wrep[B1OFF + i] = b1[i]; }
    else if (idx < 116) { int i = idx - 52;  wrep[B2OFF + i] = b2[i]; }
    else if (idx < 136) { int i = idx - 116; wrep[B3OFF + i] = b3[i]; }
}

// ---------------------------------------------------------------------------
// One conv(K=3,SAME)+ReLU+pool2 stage on even/odd-split LDS buffers.
// 8 waves per block (512 threads), wave-strided tasks. Weights via VMEM
// (vmcnt) so the DS/SMEM lgkm counter only carries activation reads.
// ---------------------------------------------------------------------------
template<int IC, int OC, int OCG, int OPG, int WSTR, int JOUT, int LG, bool FINAL>
__device__ __forceinline__ void stage_eo(const float* __restrict__ in,
                                         float* __restrict__ out,
                                         float* __restrict__ outg,
                                         const float* __restrict__ wrep,
                                         const float* __restrict__ brep,
                                         int pbase, int o3, int wv, int lane,
                                         int zero)
{
    constexpr int PIN  = JOUT + 1;
    constexpr int POUT = JOUT / 2;
    constexpr int NJT  = (JOUT + 63) / 64;
    for (int task = wv; task < OCG * NJT; task += 8) {
        const int ocg = task / NJT;                 // wave-uniform (wv uniform)
        const int jt  = task - ocg * NJT;
        const int j   = jt * 64 + lane;
        const int jc  = (j < JOUT) ? j : (JOUT - 1);
        const int g   = pbase + j;
        const bool val = (j < JOUT) && (g >= 0) && (g < LG);
        const float* bp = brep + ocg * OPG;
        float ae[OPG], ao[OPG];
#pragma unroll
        for (int o = 0; o < OPG; ++o) { ae[o] = bp[o]; ao[o] = ae[o]; }
        const float* wbase = wrep + ocg * (IC * WSTR) + zero;  // stays VMEM
#pragma unroll 2
        for (int ic = 0; ic < IC; ++ic) {
            const float* ip = in + ic * (2 * PIN);
            float2 ev, ov;
            __builtin_memcpy(&ev, ip + jc, 8);        // ds_read2_b32
            __builtin_memcpy(&ov, ip + PIN + jc, 8);  // ds_read2_b32
            const float e0 = ev.x, e1 = ev.y;
            const float o0 = ov.x, o1 = ov.y;
            const float* wp = wbase + ic * WSTR;
            float wr[WSTR];
#pragma unroll
            for (int q = 0; q < WSTR / 4; ++q)
                *(float4*)&wr[q * 4] = *(const float4*)(wp + q * 4);
#pragma unroll
            for (int o = 0; o < OPG; ++o) {
                const float w0 = wr[o*3+0], w1 = wr[o*3+1], w2 = wr[o*3+2];
                ae[o] = fmaf(e0, w0, fmaf(o0, w1, fmaf(e1, w2, ae[o])));
                ao[o] = fmaf(o0, w0, fmaf(e1, w1, fmaf(o1, w2, ao[o])));
            }
        }
        if constexpr (FINAL) {
            const int gj = o3 + j;
            if (gj < 375 && j < JOUT) {
#pragma unroll
                for (int o = 0; o < OPG; ++o)
                    outg[(ocg*OPG+o) * 375 + gj] = fmaxf(fmaxf(ae[o], ao[o]), 0.f);
            }
        } else {
            if (j < JOUT) {
                float* dst = out + ((j & 1) ? POUT : 0) + (j >> 1);
#pragma unroll
                for (int o = 0; o < OPG; ++o)
                    dst[(ocg*OPG+o) * JOUT] = val ? fmaxf(fmaxf(ae[o], ao[o]), 0.f) : 0.f;
            }
        }
    }
}

// LDS 64,096 B -> 2 blocks/CU (16 waves/CU, 4 waves/SIMD) => min 4 waves/EU.
__global__ __launch_bounds__(512, 4) void conv_chain_eo(
    const float* __restrict__ x,
    const float* __restrict__ wrep,
    float* __restrict__ hcat)
{
    __shared__ float A[ASZ];
    __shared__ float B[BSZ];

    const int tid  = threadIdx.x;
    const int wv   = __builtin_amdgcn_readfirstlane(tid >> 6);
    const int lane = tid & 63;
    // opaque zero: compiler can't prove uniformity -> weight loads stay VMEM
    const int zero = __builtin_amdgcn_ds_bpermute(0, 0);
    const int n     = blockIdx.x / NCHK;
    const int chunk = blockIdx.x % NCHK;
    const int o3 = chunk * TCH;
    const int p2 = 2*o3 - 1, p1 = 4*o3 - 3, p0 = 8*o3 - 7, xs = 16*o3 - 15;

    // stage x -> A in even/odd split (3 ch, 447 pairs, plane stride 894)
    const float* xn = x + (size_t)n * 3 * LIN;
    for (int idx = tid; idx < 3 * 894; idx += 512) {
        int c = idx / 894, i = idx - c * 894;
        int g = xs + i;
        float v = (g >= 0 && g < LIN) ? xn[c * LIN + g] : 0.f;
        A[c * 894 + ((i & 1) ? 447 : 0) + (i >> 1)] = v;
    }
    __syncthreads();
    stage_eo< 3, 20, 4, 5, 16, 446, 3000, false>(A, B, nullptr, wrep + W0OFF, wrep + B0OFF, p0, o3, wv, lane, zero);
    __syncthreads();
    stage_eo<20, 32, 4, 8, 24, 222, 1500, false>(B, A, nullptr, wrep + W1OFF, wrep + B1OFF, p1, o3, wv, lane, zero);
    __syncthreads();
    stage_eo<32, 64, 8, 8, 24, 110,  750, false>(A, B, nullptr, wrep + W2OFF, wrep + B2OFF, p2, o3, wv, lane, zero);
    __syncthreads();
    stage_eo<64, 20, 4, 5, 16,  54,  375, true >(B, nullptr, hcat + (size_t)n * HCATW,
                                                 wrep + W3OFF, wrep + B3OFF, o3, o3, wv, lane, zero);
}

// ---------------------------------------------------------------------------
// LAPACK ssyevd (n=3, uplo='L') replica: ssytrd -> ssteqr('I') -> apply Q.
// ---------------------------------------------------------------------------
__device__ __forceinline__ float fsign(float a, float b) {
    return (b >= 0.0f) ? fabsf(a) : -fabsf(a);
}
__device__ __forceinline__ float slapy2(float xx, float yy) {
    float xa = fabsf(xx), ya = fabsf(yy);
    float w = fmaxf(xa, ya), z = fminf(xa, ya);
    if (z == 0.f) return w;
    float t = z / w;
    return w * sqrtf(1.f + t*t);
}
// LAPACK 3.10+ slartg: c >= 0 always, r = sign(f)*hypot
__device__ __forceinline__ void slartg(float f, float g, float& c, float& s, float& r) {
    if (g == 0.f)      { c = 1.f; s = 0.f; r = f; }
    else if (f == 0.f) { c = 0.f; s = (g >= 0.f ? 1.f : -1.f); r = fabsf(g); }
    else {
        float d = sqrtf(f*f + g*g);
        c = fabsf(f) / d;
        r = fsign(d, f);
        s = g / r;
    }
}
__device__ void slaev2(float a, float b, float cc,
                       float& rt1, float& rt2, float& cs1, float& sn1) {
    float sm = a + cc, df = a - cc;
    float adf = fabsf(df);
    float tb = b + b, ab = fabsf(tb);
    float acmx, acmn;
    if (fabsf(a) > fabsf(cc)) { acmx = a; acmn = cc; } else { acmx = cc; acmn = a; }
    float rt;
    if (adf > ab)      { float t = ab/adf; rt = adf*sqrtf(1.f + t*t); }
    else if (adf < ab) { float t = adf/ab; rt = ab*sqrtf(1.f + t*t); }
    else rt = ab * sqrtf(2.f);
    int sgn1;
    if (sm < 0.f)      { rt1 = 0.5f*(sm - rt); sgn1 = -1; rt2 = (acmx/rt1)*acmn - (b/rt1)*b; }
    else if (sm > 0.f) { rt1 = 0.5f*(sm + rt); sgn1 =  1; rt2 = (acmx/rt1)*acmn - (b/rt1)*b; }
    else               { rt1 = 0.5f*rt; rt2 = -0.5f*rt; sgn1 = 1; }
    float cs; int sgn2;
    if (df >= 0.f) { cs = df + rt; sgn2 = 1; } else { cs = df - rt; sgn2 = -1; }
    float acs = fabsf(cs);
    if (acs > ab) {
        float ct = -tb / cs;
        sn1 = 1.f / sqrtf(1.f + ct*ct);
        cs1 = ct * sn1;
    } else {
        if (ab == 0.f) { cs1 = 1.f; sn1 = 0.f; }
        else {
            float tn = -cs / tb;
            cs1 = 1.f / sqrtf(1.f + tn*tn);
            sn1 = tn * cs1;
        }
    }
    if (sgn1 == sgn2) { float tn = cs1; cs1 = -sn1; sn1 = tn; }
}
__device__ __forceinline__ void rot_cols(float z[3][3], int jc, float c, float s) {
    for (int i = 0; i < 3; ++i) {
        float t = z[i][jc+1];
        z[i][jc+1] = c*t - s*z[i][jc];
        z[i][jc]   = s*t + c*z[i][jc];
    }
}

__device__ void ssteqr3(float d[3], float e[2], float z[3][3]) {
    const float eps    = 5.9604645e-8f;
    const float eps2   = eps * eps;
    const float safmin = 1.17549435e-38f;
    const int n = 3;
    for (int i = 0; i < 3; ++i)
        for (int j = 0; j < 3; ++j) z[i][j] = (i == j) ? 1.f : 0.f;
    const int nmaxit = n * 30;
    int jtot = 0;
    float cw[2], sw[2];
    int l1 = 1, l, m, lend, lsv, lendsv;

L10:
    if (l1 > n) goto L160;
    if (l1 > 1) e[l1-2] = 0.f;
    if (l1 <= n-1) {
        for (m = l1; m <= n-1; ++m) {
            float tst = fabsf(e[m-1]);
            if (tst == 0.f) goto L30;
            if (tst <= (sqrtf(fabsf(d[m-1])) * sqrtf(fabsf(d[m]))) * eps) {
                e[m-1] = 0.f;
                goto L30;
            }
        }
    }
    m = n;
L30:
    l = l1; lsv = l; lend = m; lendsv = lend; l1 = m + 1;
    if (lend == l) goto L10;
    if (fabsf(d[lend-1]) < fabsf(d[l-1])) { lend = lsv; l = lendsv; }
    if (lend > l) {
L40:
        if (l != lend) {
            bool found = false;
            for (m = l; m <= lend-1; ++m) {
                float tst = e[m-1]*e[m-1];
                if (tst <= (eps2*fabsf(d[m-1]))*fabsf(d[m]) + safmin) { found = true; break; }
            }
            if (!found) m = lend;
        } else m = lend;
        if (m < lend) e[m-1] = 0.f;
        {
            float p = d[l-1];
            if (m == l) {
                d[l-1] = p;
                l = l + 1;
                if (l <= lend) goto L40;
                goto L140;
            }
            if (m == l+1) {
                float rt1, rt2, c2, s2;
                slaev2(d[l-1], e[l-1], d[l], rt1, rt2, c2, s2);
                rot_cols(z, l-1, c2, s2);
                d[l-1] = rt1; d[l] = rt2; e[l-1] = 0.f;
                l += 2;
                if (l <= lend) goto L40;
                goto L140;
            }
            if (jtot == nmaxit) goto L140;
            jtot++;
            float g = (d[l] - p) / (2.f * e[l-1]);
            float r = slapy2(g, 1.f);
            g = d[m-1] - p + e[l-1] / (g + fsign(r, g));
            float s = 1.f, c = 1.f;
            p = 0.f;
            for (int i = m-1; i >= l; --i) {
                float f = s * e[i-1];
                float b = c * e[i-1];
                slartg(g, f, c, s, r);
                if (i != m-1) e[i] = r;
                g = d[i] - p;
                r = (d[i-1] - g)*s + 2.f*c*b;
                p = s * r;
                d[i] = g + p;
                g = c*r - b;
                cw[i-l] = c; sw[i-l] = -s;
            }
            for (int jj = m-l; jj >= 1; --jj)
                rot_cols(z, l + jj - 2, cw[jj-1], sw[jj-1]);
            d[l-1] = d[l-1] - p;
            e[l-1] = g;
            goto L40;
        }
    } else {
L90:
        if (l != lend) {
            bool found = false;
            for (m = l; m >= lend+1; --m) {
                float tst = e[m-2]*e[m-2];
                if (tst <= (eps2*fabsf(d[m-1]))*fabsf(d[m-2]) + safmin) { found = true; break; }
            }
            if (!found) m = lend;
        } else m = lend;
        if (m > lend) e[m-2] = 0.f;
        {
            float p = d[l-1];
            if (m == l) {
                d[l-1] = p;
                l = l - 1;
                if (l >= lend) goto L90;
                goto L140;
            }
            if (m == l-1) {
                float rt1, rt2, c2, s2;
                slaev2(d[l-2], e[l-2], d[l-1], rt1, rt2, c2, s2);
                rot_cols(z, l-2, c2, s2);
                d[l-2] = rt1; d[l-1] = rt2; e[l-2] = 0.f;
                l -= 2;
                if (l >= lend) goto L90;
                goto L140;
            }
            if (jtot == nmaxit) goto L140;
            jtot++;
            float g = (d[l-2] - p) / (2.f * e[l-2]);
            float r = slapy2(g, 1.f);
            g = d[m-1] - p + e[l-2] / (g + fsign(r, g));
            float s = 1.f, c = 1.f;
            p = 0.f;
            for (int i = m; i <= l-1; ++i) {
                float f = s * e[i-1];
                float b = c * e[i-1];
                slartg(g, f, c, s, r);
                if (i != m) e[i-2] = r;
                g = d[i-1] - p;
                r = (d[i] - g)*s + 2.f*c*b;
                p = s * r;
                d[i-1] = g + p;
                g = c*r - b;
                cw[i-m] = c; sw[i-m] = s;
            }
            for (int jj = 1; jj <= l-m; ++jj)
                rot_cols(z, m + jj - 2, cw[jj-1], sw[jj-1]);
            d[l-1] = d[l-1] - p;
            e[l-2] = g;
            goto L90;
        }
    }
L140:
    if (jtot < nmaxit) goto L10;
L160:
    for (int ii = 2; ii <= n; ++ii) {
        int i = ii - 1, k = i;
        float p = d[i-1];
        for (int j = ii; j <= n; ++j)
            if (d[j-1] < p) { k = j; p = d[j-1]; }
        if (k != i) {
            d[k-1] = d[i-1]; d[i-1] = p;
            for (int r0 = 0; r0 < 3; ++r0) {
                float t = z[r0][i-1]; z[r0][i-1] = z[r0][k-1]; z[r0][k-1] = t;
            }
        }
    }
}

// ---------------------------------------------------------------------------
// cov + eig kernel
// ---------------------------------------------------------------------------
__global__ __launch_bounds__(256) void cov_eig_kernel(const float* __restrict__ x,
                                                      float* __restrict__ eigbuf,
                                                      unsigned int* __restrict__ gmax)
{
    __shared__ float part[4][9];
    const int n = blockIdx.x;
    const float* xn = x + (size_t)n * 3 * LIN;
    float v[9] = {0,0,0,0,0,0,0,0,0};
    for (int l = threadIdx.x; l < LIN; l += 256) {
        float a = xn[l], b = xn[LIN + l], c = xn[2*LIN + l];
        v[0] += a; v[1] += b; v[2] += c;
        v[3] = fmaf(a,a,v[3]); v[4] = fmaf(a,b,v[4]); v[5] = fmaf(a,c,v[5]);
        v[6] = fmaf(b,b,v[6]); v[7] = fmaf(b,c,v[7]); v[8] = fmaf(c,c,v[8]);
    }
#pragma unroll
    for (int off = 32; off > 0; off >>= 1)
#pragma unroll
        for (int i = 0; i < 9; ++i) v[i] += __shfl_down(v[i], off, 64);
    const int wv = threadIdx.x >> 6, lane = threadIdx.x & 63;
    if (lane == 0)
        for (int i = 0; i < 9; ++i) part[wv][i] = v[i];
    __syncthreads();
    if (threadIdx.x == 0) {
        float t[9];
        for (int i = 0; i < 9; ++i)
            t[i] = part[0][i] + part[1][i] + part[2][i] + part[3][i];
        const float Lf = (float)LIN;
        float m0 = t[0]/Lf, m1 = t[1]/Lf, m2 = t[2]/Lf;
        float c00 = (t[3] - Lf*m0*m0) / (Lf - 1.f);
        float c01 = (t[4] - Lf*m0*m1) / (Lf - 1.f);
        float c02 = (t[5] - Lf*m0*m2) / (Lf - 1.f);
        float c11 = (t[6] - Lf*m1*m1) / (Lf - 1.f);
        float c12 = (t[7] - Lf*m1*m2) / (Lf - 1.f);
        float c22 = (t[8] - Lf*m2*m2) / (Lf - 1.f);

        float dd[3], ee[2], tau, v2;
        {
            float a21 = c01, a31 = c02, a22 = c11, a32 = c12, a33 = c22;
            float xnorm = fabsf(a31);
            if (xnorm == 0.f) {
                tau = 0.f; v2 = 0.f;
                dd[0] = c00; dd[1] = a22; dd[2] = a33;
                ee[0] = a21; ee[1] = a32;
            } else {
                float beta = -fsign(slapy2(a21, xnorm), a21);
                tau = (beta - a21) / beta;
                v2  = a31 / (a21 - beta);
                ee[0] = beta;
                float x1 = tau*(a22 + a32*v2);
                float x2 = tau*(a32 + a33*v2);
                float al = -0.5f*tau*(x1 + x2*v2);
                float w1 = x1 + al;
                float w2 = x2 + al*v2;
                a22 -= 2.f*w1;
                a32 -= (v2*w1 + w2);
                a33 -= 2.f*v2*w2;
                dd[0] = c00; dd[1] = a22; dd[2] = a33;
                ee[1] = a32;
            }
        }
        float zz[3][3];
        ssteqr3(dd, ee, zz);
        if (tau != 0.f) {
            for (int j = 0; j < 3; ++j) {
                float sum = zz[1][j] + v2*zz[2][j];
                zz[1][j] -= tau * sum;
                zz[2][j] -= tau * v2 * sum;
            }
        }

        float* eb = eigbuf + n * 21;
        eb[0] = c00; eb[1] = c01; eb[2] = c02;
        eb[3] = c01; eb[4] = c11; eb[5] = c12;
        eb[6] = c02; eb[7] = c12; eb[8] = c22;
        eb[9] = dd[0]; eb[10] = dd[1]; eb[11] = dd[2];
        for (int c = 0; c < 3; ++c)
            for (int k = 0; k < 3; ++k) eb[12 + c*3 + k] = zz[c][k];

        float vmax = fmaxf(dd[0], fmaxf(dd[1], dd[2]));
        float cmax = 0.f;
        for (int i = 0; i < 9; ++i) cmax = fmaxf(cmax, fabsf(eb[i]));
        atomicMax(&gmax[0], __float_as_uint(vmax));
        atomicMax(&gmax[1], __float_as_uint(cmax));
    }
}

// ---------------------------------------------------------------------------
// feats -> 1x1 conv (wc) + relu, writes hcat[:, 7500:7640]
// ---------------------------------------------------------------------------
__global__ __launch_bounds__(256) void feats_kernel(const float* __restrict__ eigbuf,
                                                    const unsigned int* __restrict__ gmax,
                                                    const float* __restrict__ wc,
                                                    const float* __restrict__ bc,
                                                    float* __restrict__ hcat)
{
    const int n = blockIdx.x;
    const int t = threadIdx.x;
    if (t >= 140) return;
    const int o = t / 7, j = t % 7;
    const float* eb = eigbuf + n * 21;
    const float vmax = __uint_as_float(gmax[0]);
    const float cmax = __uint_as_float(gmax[1]);
    float f0, f1, f2;
    if (j < 3)       { f0 = eb[0*3+j]/cmax; f1 = eb[1*3+j]/cmax; f2 = eb[2*3+j]/cmax; }
    else if (j == 3) { f0 = eb[9]/vmax;     f1 = eb[10]/vmax;    f2 = eb[11]/vmax; }
    else             { int k = j-4; f0 = eb[12+0*3+k]; f1 = eb[12+1*3+k]; f2 = eb[12+2*3+k]; }
    float r = bc[o] + wc[o*3+0]*f0 + wc[o*3+1]*f1 + wc[o*3+2]*f2;
    hcat[(size_t)n*HCATW + 7500 + o*7 + j] = fmaxf(r, 0.f);
}

// ---------------------------------------------------------------------------
// FC0+FC1 fused, 4 samples per block (512 threads), h staged in LDS.
// Wave owns a 4-wide o-tile: 16 accumulators => each h b128 feeds 16 FMAs.
// ---------------------------------------------------------------------------
__global__ __launch_bounds__(512) void fc01_kernel(const float* __restrict__ hcat,
                                                   const float* __restrict__ wl0,
                                                   const float* __restrict__ bl0,
                                                   const float* __restrict__ wl1,
                                                   const float* __restrict__ bl1,
                                                   float* __restrict__ out)
{
    __shared__ float hl[FCNS * HCATW];     // 122,240 B
    __shared__ float hbuf[FCNS * HID];     //   1,600 B
    const int tid = threadIdx.x;
    const int n0 = blockIdx.x * FCNS;
    for (int i = tid; i < FCNS * (HCATW/4); i += 512) {
        int s  = i / (HCATW/4);
        int k4 = i - s * (HCATW/4);
        ((float4*)hl)[s * (HCATW/4) + k4] =
            *(const float4*)(hcat + (size_t)(n0 + s) * HCATW + k4 * 4);
    }
    __syncthreads();
    const int wv = tid >> 6;
    const int lane = tid & 63;
    for (int ot = wv; ot < HID / 4; ot += 8) {      // 25 o-tiles of 4
        float acc[4][FCNS];
#pragma unroll
        for (int oo = 0; oo < 4; ++oo)
#pragma unroll
            for (int s = 0; s < FCNS; ++s) acc[oo][s] = 0.f;
        for (int k = lane * 4; k < HCATW; k += 256) {
            float4 hv[FCNS];
#pragma unroll
            for (int s = 0; s < FCNS; ++s)
                hv[s] = *(const float4*)(hl + s * HCATW + k);
#pragma unroll
            for (int oo = 0; oo < 4; ++oo) {
                const float4 w4 = *(const float4*)(wl0 + (size_t)(ot*4+oo) * HCATW + k);
#pragma unroll
                for (int s = 0; s < FCNS; ++s) {
                    acc[oo][s] = fmaf(hv[s].x, w4.x, acc[oo][s]);
                    acc[oo][s] = fmaf(hv[s].y, w4.y, acc[oo][s]);
                    acc[oo][s] = fmaf(hv[s].z, w4.z, acc[oo][s]);
                    acc[oo][s] = fmaf(hv[s].w, w4.w, acc[oo][s]);
                }
            }
        }
#pragma unroll
        for (int off = 32; off > 0; off >>= 1)
#pragma unroll
            for (int oo = 0; oo < 4; ++oo)
#pragma unroll
                for (int s = 0; s < FCNS; ++s)
                    acc[oo][s] += __shfl_down(acc[oo][s], off, 64);
        if (lane == 0) {
#pragma unroll
            for (int oo = 0; oo < 4; ++oo) {
                const float b = bl0[ot*4+oo];
#pragma unroll
                for (int s = 0; s < FCNS; ++s)
                    hbuf[s * HID + ot*4+oo] = fmaxf(acc[oo][s] + b, 0.f);
            }
        }
    }
    __syncthreads();
    if (tid < 2 * FCNS) {
        const int s = tid >> 1, r = tid & 1;
        const float* w = wl1 + r * HID;
        float acc = bl1[r];
        for (int k = 0; k < HID; ++k) acc = fmaf(hbuf[s * HID + k], w[k], acc);
        out[r * NBATCH + n0 + s] = acc;
    }
}

// ---------------------------------------------------------------------------
// launch
// ---------------------------------------------------------------------------
extern "C" void kernel_launch(void* const* d_in, const int* in_sizes, int n_in,
                              void* d_out, int out_size, void* d_ws, size_t ws_size,
                              hipStream_t stream)
{
    const float* x   = (const float*)d_in[0];
    const float* w0  = (const float*)d_in[1];
    const float* b0  = (const float*)d_in[2];
    const float* w1  = (const float*)d_in[3];
    const float* b1  = (const float*)d_in[4];
    const float* w2  = (const float*)d_in[5];
    const float* b2  = (const float*)d_in[6];
    const float* w3  = (const float*)d_in[7];
    const float* b3  = (const float*)d_in[8];
    const float* wc  = (const float*)d_in[9];
    const float* bc  = (const float*)d_in[10];
    const float* wl0 = (const float*)d_in[11];
    const float* bl0 = (const float*)d_in[12];
    const float* wl1 = (const float*)d_in[13];
    const float* bl1 = (const float*)d_in[14];
    float* out = (float*)d_out;

    // workspace layout (floats)
    const size_t HCAT_N = (size_t)NBATCH * HCATW;        // 7,823,360
    const size_t EIG_N  = (size_t)NBATCH * 21;
    const size_t need_bytes = (HCAT_N + EIG_N + 4 + WREPSZ) * 4 + 16;
    if (ws_size < need_bytes) return;

    float* ws     = (float*)d_ws;
    float* hcat   = ws;
    float* eigbuf = hcat + HCAT_N;
    unsigned int* gmax = (unsigned int*)(eigbuf + EIG_N);
    float* wrep   = (float*)(gmax + 4);

    hipMemsetAsync(gmax, 0, 2 * sizeof(unsigned int), stream);

    repack_kernel<<<24, 256, 0, stream>>>(w0, b0, w1, b1, w2, b2, w3, b3, wrep);
    conv_chain_eo<<<NBATCH * NCHK, 512, 0, stream>>>(x, wrep, hcat);
    cov_eig_kernel<<<NBATCH, 256, 0, stream>>>(x, eigbuf, gmax);
    feats_kernel<<<NBATCH, 256, 0, stream>>>(eigbuf, gmax, wc, bc, hcat);
    fc01_kernel<<<NBATCH / FCNS, 512, 0, stream>>>(hcat, wl0, bl0, wl1, bl1, out);
}

// Round 2
// 722.505 us; speedup vs baseline: 1.1200x; 1.1200x over previous
//
#include <hip/hip_runtime.h>
#include <hip/hip_bf16.h>
#include <math.h>

// ---------------------------------------------------------------------------
// Problem constants
// ---------------------------------------------------------------------------
#define NBATCH 1024
#define LIN    6000
#define HCATW  7640       // 20*375 + 20*7
#define HID    100

// conv-chain chunking: T=54 final(375-res) positions per block, 7 chunks.
//   JOUT chain = 8T+14, 4T+6, 2T+2, T = 446, 222, 110, 54
// R9: JBLK=2 (128-wide j-blocks/task). 64-wide tiling already clamp-padded
// JOUT to a mult of 64, so 128-wide tasks add ZERO extra FMA issue for
// s1 (256=4x64=2x128) and s2 (128=2x64=1x128), while halving weight-load
// VMEM + addressing and doubling the independent-FMA run between dependent
// loads (96 FMA ~ 192 cyc covers LDS ~120cyc / L1 ~150cyc latency at only
// 4 waves/SIMD). Task counts: s0 16 (2/wave), s1 8, s2 8, s3 4.
#define TCH   54
#define NCHK  7

#define ASZ 7104            // max(x-buf 3*894=2682, s1-out 32*222=7104)
#define BSZ 8920            // max(s0-out 20*446=8920, s2-out 64*110=7040)

// repacked-weight offsets (floats) inside wrep
#define W0OFF 0             // 4ocg*3ic*16  = 192
#define W1OFF 192           // 4*20*24      = 1920
#define W2OFF 2112          // 8*32*24      = 6144
#define W3OFF 8256          // 4*64*16      = 4096
#define B0OFF 12352
#define B1OFF 12372
#define B2OFF 12404
#define B3OFF 12468
#define WREPSZ 12496

// fc01: samples per block
#define FCNS 4

// ---------------------------------------------------------------------------
// Weight repack
// ---------------------------------------------------------------------------
__device__ __forceinline__ void pack_one(int idx, int OC, int IC, int OCG,
                                         int OPG, int WSTR,
                                         const float* __restrict__ w,
                                         float* __restrict__ dst)
{
    if (idx >= OCG * IC * WSTR) return;
    int ocg = idx / (IC * WSTR);
    int r   = idx - ocg * (IC * WSTR);
    int ic  = r / WSTR;
    int q   = r - ic * WSTR;
    int o   = q / 3, k = q - o * 3;
    int oc  = ocg * OPG + o;
    dst[idx] = (o < OPG && oc < OC) ? w[(oc * IC + ic) * 3 + k] : 0.f;
}

__global__ __launch_bounds__(256) void repack_kernel(
    const float* __restrict__ w0, const float* __restrict__ b0,
    const float* __restrict__ w1, const float* __restrict__ b1,
    const float* __restrict__ w2, const float* __restrict__ b2,
    const float* __restrict__ w3, const float* __restrict__ b3,
    float* __restrict__ wrep)
{
    int idx = blockIdx.x * 256 + threadIdx.x;
    pack_one(idx, 20,  3, 4, 5, 16, w0, wrep + W0OFF);
    pack_one(idx, 32, 20, 4, 8, 24, w1, wrep + W1OFF);
    pack_one(idx, 64, 32, 8, 8, 24, w2, wrep + W2OFF);
    pack_one(idx, 20, 64, 4, 5, 16, w3, wrep + W3OFF);
    if (idx < 20)            wrep[B0OFF + idx] = b0[idx];
    else if (idx < 52)  { int i = idx - 20;  wrep[B1OFF + i] = b1[i]; }
    else if (idx < 116) { int i = idx - 52;  wrep[B2OFF + i] = b2[i]; }
    else if (idx < 136) { int i = idx - 116; wrep[B3OFF + i] = b3[i]; }
}

// ---------------------------------------------------------------------------
// One conv(K=3,SAME)+ReLU+pool2 stage on even/odd-split LDS buffers.
// 8 waves per block (512 threads), wave-strided tasks of JBLK*64 outputs.
// Weights via VMEM (vmcnt) so lgkm only carries activation ds_reads; with
// JBLK=2 each weight register block feeds 2x64 output columns.
// ---------------------------------------------------------------------------
template<int IC, int OC, int OCG, int OPG, int WSTR, int JOUT, int LG, int JBLK,
         bool FINAL>
__device__ __forceinline__ void stage_eo(const float* __restrict__ in,
                                         float* __restrict__ out,
                                         float* __restrict__ outg,
                                         const float* __restrict__ wrep,
                                         const float* __restrict__ brep,
                                         int pbase, int o3, int wv, int lane,
                                         int zero)
{
    constexpr int PIN  = JOUT + 1;
    constexpr int POUT = JOUT / 2;
    constexpr int NJT  = (JOUT + 64 * JBLK - 1) / (64 * JBLK);
    for (int task = wv; task < OCG * NJT; task += 8) {
        const int ocg = task / NJT;                 // wave-uniform (wv uniform)
        const int jt  = task - ocg * NJT;
        const int j0  = jt * (64 * JBLK) + lane;
        const float* bp = brep + ocg * OPG;
        float ae[JBLK][OPG], ao[JBLK][OPG];
#pragma unroll
        for (int t = 0; t < JBLK; ++t)
#pragma unroll
            for (int o = 0; o < OPG; ++o) { ae[t][o] = bp[o]; ao[t][o] = ae[t][o]; }
        const float* wbase = wrep + ocg * (IC * WSTR) + zero;  // stays VMEM
#pragma unroll 2
        for (int ic = 0; ic < IC; ++ic) {
            const float* ip = in + ic * (2 * PIN);
            const float* wp = wbase + ic * WSTR;
            float wr[WSTR];
#pragma unroll
            for (int q = 0; q < WSTR / 4; ++q)
                *(float4*)&wr[q * 4] = *(const float4*)(wp + q * 4);
#pragma unroll
            for (int t = 0; t < JBLK; ++t) {
                const int jj = j0 + t * 64;
                const int jc = (jj < JOUT) ? jj : (JOUT - 1);
                float2 ev, ov;
                __builtin_memcpy(&ev, ip + jc, 8);        // ds_read2_b32
                __builtin_memcpy(&ov, ip + PIN + jc, 8);  // ds_read2_b32
                const float e0 = ev.x, e1 = ev.y;
                const float o0 = ov.x, o1 = ov.y;
#pragma unroll
                for (int o = 0; o < OPG; ++o) {
                    const float w0 = wr[o*3+0], w1 = wr[o*3+1], w2 = wr[o*3+2];
                    ae[t][o] = fmaf(e0, w0, fmaf(o0, w1, fmaf(e1, w2, ae[t][o])));
                    ao[t][o] = fmaf(o0, w0, fmaf(e1, w1, fmaf(o1, w2, ao[t][o])));
                }
            }
        }
#pragma unroll
        for (int t = 0; t < JBLK; ++t) {
            const int jj = j0 + t * 64;
            if constexpr (FINAL) {
                const int gj = o3 + jj;
                if (gj < 375 && jj < JOUT) {
#pragma unroll
                    for (int o = 0; o < OPG; ++o)
                        outg[(ocg*OPG+o) * 375 + gj] =
                            fmaxf(fmaxf(ae[t][o], ao[t][o]), 0.f);
                }
            } else {
                const int g = pbase + jj;
                const bool val = (jj < JOUT) && (g >= 0) && (g < LG);
                if (jj < JOUT) {
                    float* dst = out + ((jj & 1) ? POUT : 0) + (jj >> 1);
#pragma unroll
                    for (int o = 0; o < OPG; ++o)
                        dst[(ocg*OPG+o) * JOUT] =
                            val ? fmaxf(fmaxf(ae[t][o], ao[t][o]), 0.f) : 0.f;
                }
            }
        }
    }
}

// LDS 64,096 B -> 2 blocks/CU (16 waves/CU, 4 waves/SIMD) => min 4 waves/EU.
__global__ __launch_bounds__(512, 4) void conv_chain_eo(
    const float* __restrict__ x,
    const float* __restrict__ wrep,
    float* __restrict__ hcat)
{
    __shared__ float A[ASZ];
    __shared__ float B[BSZ];

    const int tid  = threadIdx.x;
    const int wv   = __builtin_amdgcn_readfirstlane(tid >> 6);
    const int lane = tid & 63;
    // opaque zero: compiler can't prove uniformity -> weight loads stay VMEM
    const int zero = __builtin_amdgcn_ds_bpermute(0, 0);
    const int n     = blockIdx.x / NCHK;
    const int chunk = blockIdx.x % NCHK;
    const int o3 = chunk * TCH;
    const int p2 = 2*o3 - 1, p1 = 4*o3 - 3, p0 = 8*o3 - 7, xs = 16*o3 - 15;

    // stage x -> A in even/odd split (3 ch, 447 pairs, plane stride 894)
    const float* xn = x + (size_t)n * 3 * LIN;
    for (int idx = tid; idx < 3 * 894; idx += 512) {
        int c = idx / 894, i = idx - c * 894;
        int g = xs + i;
        float v = (g >= 0 && g < LIN) ? xn[c * LIN + g] : 0.f;
        A[c * 894 + ((i & 1) ? 447 : 0) + (i >> 1)] = v;
    }
    __syncthreads();
    stage_eo< 3, 20, 4, 5, 16, 446, 3000, 2, false>(A, B, nullptr, wrep + W0OFF, wrep + B0OFF, p0, o3, wv, lane, zero);
    __syncthreads();
    stage_eo<20, 32, 4, 8, 24, 222, 1500, 2, false>(B, A, nullptr, wrep + W1OFF, wrep + B1OFF, p1, o3, wv, lane, zero);
    __syncthreads();
    stage_eo<32, 64, 8, 8, 24, 110,  750, 2, false>(A, B, nullptr, wrep + W2OFF, wrep + B2OFF, p2, o3, wv, lane, zero);
    __syncthreads();
    stage_eo<64, 20, 4, 5, 16,  54,  375, 1, true >(B, nullptr, hcat + (size_t)n * HCATW,
                                                    wrep + W3OFF, wrep + B3OFF, o3, o3, wv, lane, zero);
}

// ---------------------------------------------------------------------------
// LAPACK ssyevd (n=3, uplo='L') replica: ssytrd -> ssteqr('I') -> apply Q.
// ---------------------------------------------------------------------------
__device__ __forceinline__ float fsign(float a, float b) {
    return (b >= 0.0f) ? fabsf(a) : -fabsf(a);
}
__device__ __forceinline__ float slapy2(float xx, float yy) {
    float xa = fabsf(xx), ya = fabsf(yy);
    float w = fmaxf(xa, ya), z = fminf(xa, ya);
    if (z == 0.f) return w;
    float t = z / w;
    return w * sqrtf(1.f + t*t);
}
// LAPACK 3.10+ slartg: c >= 0 always, r = sign(f)*hypot
__device__ __forceinline__ void slartg(float f, float g, float& c, float& s, float& r) {
    if (g == 0.f)      { c = 1.f; s = 0.f; r = f; }
    else if (f == 0.f) { c = 0.f; s = (g >= 0.f ? 1.f : -1.f); r = fabsf(g); }
    else {
        float d = sqrtf(f*f + g*g);
        c = fabsf(f) / d;
        r = fsign(d, f);
        s = g / r;
    }
}
__device__ void slaev2(float a, float b, float cc,
                       float& rt1, float& rt2, float& cs1, float& sn1) {
    float sm = a + cc, df = a - cc;
    float adf = fabsf(df);
    float tb = b + b, ab = fabsf(tb);
    float acmx, acmn;
    if (fabsf(a) > fabsf(cc)) { acmx = a; acmn = cc; } else { acmx = cc; acmn = a; }
    float rt;
    if (adf > ab)      { float t = ab/adf; rt = adf*sqrtf(1.f + t*t); }
    else if (adf < ab) { float t = adf/ab; rt = ab*sqrtf(1.f + t*t); }
    else rt = ab * sqrtf(2.f);
    int sgn1;
    if (sm < 0.f)      { rt1 = 0.5f*(sm - rt); sgn1 = -1; rt2 = (acmx/rt1)*acmn - (b/rt1)*b; }
    else if (sm > 0.f) { rt1 = 0.5f*(sm + rt); sgn1 =  1; rt2 = (acmx/rt1)*acmn - (b/rt1)*b; }
    else               { rt1 = 0.5f*rt; rt2 = -0.5f*rt; sgn1 = 1; }
    float cs; int sgn2;
    if (df >= 0.f) { cs = df + rt; sgn2 = 1; } else { cs = df - rt; sgn2 = -1; }
    float acs = fabsf(cs);
    if (acs > ab) {
        float ct = -tb / cs;
        sn1 = 1.f / sqrtf(1.f + ct*ct);
        cs1 = ct * sn1;
    } else {
        if (ab == 0.f) { cs1 = 1.f; sn1 = 0.f; }
        else {
            float tn = -cs / tb;
            cs1 = 1.f / sqrtf(1.f + tn*tn);
            sn1 = tn * cs1;
        }
    }
    if (sgn1 == sgn2) { float tn = cs1; cs1 = -sn1; sn1 = tn; }
}
__device__ __forceinline__ void rot_cols(float z[3][3], int jc, float c, float s) {
    for (int i = 0; i < 3; ++i) {
        float t = z[i][jc+1];
        z[i][jc+1] = c*t - s*z[i][jc];
        z[i][jc]   = s*t + c*z[i][jc];
    }
}

__device__ void ssteqr3(float d[3], float e[2], float z[3][3]) {
    const float eps    = 5.9604645e-8f;
    const float eps2   = eps * eps;
    const float safmin = 1.17549435e-38f;
    const int n = 3;
    for (int i = 0; i < 3; ++i)
        for (int j = 0; j < 3; ++j) z[i][j] = (i == j) ? 1.f : 0.f;
    const int nmaxit = n * 30;
    int jtot = 0;
    float cw[2], sw[2];
    int l1 = 1, l, m, lend, lsv, lendsv;

L10:
    if (l1 > n) goto L160;
    if (l1 > 1) e[l1-2] = 0.f;
    if (l1 <= n-1) {
        for (m = l1; m <= n-1; ++m) {
            float tst = fabsf(e[m-1]);
            if (tst == 0.f) goto L30;
            if (tst <= (sqrtf(fabsf(d[m-1])) * sqrtf(fabsf(d[m]))) * eps) {
                e[m-1] = 0.f;
                goto L30;
            }
        }
    }
    m = n;
L30:
    l = l1; lsv = l; lend = m; lendsv = lend; l1 = m + 1;
    if (lend == l) goto L10;
    if (fabsf(d[lend-1]) < fabsf(d[l-1])) { lend = lsv; l = lendsv; }
    if (lend > l) {
L40:
        if (l != lend) {
            bool found = false;
            for (m = l; m <= lend-1; ++m) {
                float tst = e[m-1]*e[m-1];
                if (tst <= (eps2*fabsf(d[m-1]))*fabsf(d[m]) + safmin) { found = true; break; }
            }
            if (!found) m = lend;
        } else m = lend;
        if (m < lend) e[m-1] = 0.f;
        {
            float p = d[l-1];
            if (m == l) {
                d[l-1] = p;
                l = l + 1;
                if (l <= lend) goto L40;
                goto L140;
            }
            if (m == l+1) {
                float rt1, rt2, c2, s2;
                slaev2(d[l-1], e[l-1], d[l], rt1, rt2, c2, s2);
                rot_cols(z, l-1, c2, s2);
                d[l-1] = rt1; d[l] = rt2; e[l-1] = 0.f;
                l += 2;
                if (l <= lend) goto L40;
                goto L140;
            }
            if (jtot == nmaxit) goto L140;
            jtot++;
            float g = (d[l] - p) / (2.f * e[l-1]);
            float r = slapy2(g, 1.f);
            g = d[m-1] - p + e[l-1] / (g + fsign(r, g));
            float s = 1.f, c = 1.f;
            p = 0.f;
            for (int i = m-1; i >= l; --i) {
                float f = s * e[i-1];
                float b = c * e[i-1];
                slartg(g, f, c, s, r);
                if (i != m-1) e[i] = r;
                g = d[i] - p;
                r = (d[i-1] - g)*s + 2.f*c*b;
                p = s * r;
                d[i] = g + p;
                g = c*r - b;
                cw[i-l] = c; sw[i-l] = -s;
            }
            for (int jj = m-l; jj >= 1; --jj)
                rot_cols(z, l + jj - 2, cw[jj-1], sw[jj-1]);
            d[l-1] = d[l-1] - p;
            e[l-1] = g;
            goto L40;
        }
    } else {
L90:
        if (l != lend) {
            bool found = false;
            for (m = l; m >= lend+1; --m) {
                float tst = e[m-2]*e[m-2];
                if (tst <= (eps2*fabsf(d[m-1]))*fabsf(d[m-2]) + safmin) { found = true; break; }
            }
            if (!found) m = lend;
        } else m = lend;
        if (m > lend) e[m-2] = 0.f;
        {
            float p = d[l-1];
            if (m == l) {
                d[l-1] = p;
                l = l - 1;
                if (l >= lend) goto L90;
                goto L140;
            }
            if (m == l-1) {
                float rt1, rt2, c2, s2;
                slaev2(d[l-2], e[l-2], d[l-1], rt1, rt2, c2, s2);
                rot_cols(z, l-2, c2, s2);
                d[l-2] = rt1; d[l-1] = rt2; e[l-2] = 0.f;
                l -= 2;
                if (l >= lend) goto L90;
                goto L140;
            }
            if (jtot == nmaxit) goto L140;
            jtot++;
            float g = (d[l-2] - p) / (2.f * e[l-2]);
            float r = slapy2(g, 1.f);
            g = d[m-1] - p + e[l-2] / (g + fsign(r, g));
            float s = 1.f, c = 1.f;
            p = 0.f;
            for (int i = m; i <= l-1; ++i) {
                float f = s * e[i-1];
                float b = c * e[i-1];
                slartg(g, f, c, s, r);
                if (i != m) e[i-2] = r;
                g = d[i-1] - p;
                r = (d[i] - g)*s + 2.f*c*b;
                p = s * r;
                d[i-1] = g + p;
                g = c*r - b;
                cw[i-m] = c; sw[i-m] = s;
            }
            for (int jj = 1; jj <= l-m; ++jj)
                rot_cols(z, m + jj - 2, cw[jj-1], sw[jj-1]);
            d[l-1] = d[l-1] - p;
            e[l-2] = g;
            goto L90;
        }
    }
L140:
    if (jtot < nmaxit) goto L10;
L160:
    for (int ii = 2; ii <= n; ++ii) {
        int i = ii - 1, k = i;
        float p = d[i-1];
        for (int j = ii; j <= n; ++j)
            if (d[j-1] < p) { k = j; p = d[j-1]; }
        if (k != i) {
            d[k-1] = d[i-1]; d[i-1] = p;
            for (int r0 = 0; r0 < 3; ++r0) {
                float t = z[r0][i-1]; z[r0][i-1] = z[r0][k-1]; z[r0][k-1] = t;
            }
        }
    }
}

// ---------------------------------------------------------------------------
// cov + eig kernel
// ---------------------------------------------------------------------------
__global__ __launch_bounds__(256) void cov_eig_kernel(const float* __restrict__ x,
                                                      float* __restrict__ eigbuf,
                                                      unsigned int* __restrict__ gmax)
{
    __shared__ float part[4][9];
    const int n = blockIdx.x;
    const float* xn = x + (size_t)n * 3 * LIN;
    float v[9] = {0,0,0,0,0,0,0,0,0};
    for (int l = threadIdx.x; l < LIN; l += 256) {
        float a = xn[l], b = xn[LIN + l], c = xn[2*LIN + l];
        v[0] += a; v[1] += b; v[2] += c;
        v[3] = fmaf(a,a,v[3]); v[4] = fmaf(a,b,v[4]); v[5] = fmaf(a,c,v[5]);
        v[6] = fmaf(b,b,v[6]); v[7] = fmaf(b,c,v[7]); v[8] = fmaf(c,c,v[8]);
    }
#pragma unroll
    for (int off = 32; off > 0; off >>= 1)
#pragma unroll
        for (int i = 0; i < 9; ++i) v[i] += __shfl_down(v[i], off, 64);
    const int wv = threadIdx.x >> 6, lane = threadIdx.x & 63;
    if (lane == 0)
        for (int i = 0; i < 9; ++i) part[wv][i] = v[i];
    __syncthreads();
    if (threadIdx.x == 0) {
        float t[9];
        for (int i = 0; i < 9; ++i)
            t[i] = part[0][i] + part[1][i] + part[2][i] + part[3][i];
        const float Lf = (float)LIN;
        float m0 = t[0]/Lf, m1 = t[1]/Lf, m2 = t[2]/Lf;
        float c00 = (t[3] - Lf*m0*m0) / (Lf - 1.f);
        float c01 = (t[4] - Lf*m0*m1) / (Lf - 1.f);
        float c02 = (t[5] - Lf*m0*m2) / (Lf - 1.f);
        float c11 = (t[6] - Lf*m1*m1) / (Lf - 1.f);
        float c12 = (t[7] - Lf*m1*m2) / (Lf - 1.f);
        float c22 = (t[8] - Lf*m2*m2) / (Lf - 1.f);

        float dd[3], ee[2], tau, v2;
        {
            float a21 = c01, a31 = c02, a22 = c11, a32 = c12, a33 = c22;
            float xnorm = fabsf(a31);
            if (xnorm == 0.f) {
                tau = 0.f; v2 = 0.f;
                dd[0] = c00; dd[1] = a22; dd[2] = a33;
                ee[0] = a21; ee[1] = a32;
            } else {
                float beta = -fsign(slapy2(a21, xnorm), a21);
                tau = (beta - a21) / beta;
                v2  = a31 / (a21 - beta);
                ee[0] = beta;
                float x1 = tau*(a22 + a32*v2);
                float x2 = tau*(a32 + a33*v2);
                float al = -0.5f*tau*(x1 + x2*v2);
                float w1 = x1 + al;
                float w2 = x2 + al*v2;
                a22 -= 2.f*w1;
                a32 -= (v2*w1 + w2);
                a33 -= 2.f*v2*w2;
                dd[0] = c00; dd[1] = a22; dd[2] = a33;
                ee[1] = a32;
            }
        }
        float zz[3][3];
        ssteqr3(dd, ee, zz);
        if (tau != 0.f) {
            for (int j = 0; j < 3; ++j) {
                float sum = zz[1][j] + v2*zz[2][j];
                zz[1][j] -= tau * sum;
                zz[2][j] -= tau * v2 * sum;
            }
        }

        float* eb = eigbuf + n * 21;
        eb[0] = c00; eb[1] = c01; eb[2] = c02;
        eb[3] = c01; eb[4] = c11; eb[5] = c12;
        eb[6] = c02; eb[7] = c12; eb[8] = c22;
        eb[9] = dd[0]; eb[10] = dd[1]; eb[11] = dd[2];
        for (int c = 0; c < 3; ++c)
            for (int k = 0; k < 3; ++k) eb[12 + c*3 + k] = zz[c][k];

        float vmax = fmaxf(dd[0], fmaxf(dd[1], dd[2]));
        float cmax = 0.f;
        for (int i = 0; i < 9; ++i) cmax = fmaxf(cmax, fabsf(eb[i]));
        atomicMax(&gmax[0], __float_as_uint(vmax));
        atomicMax(&gmax[1], __float_as_uint(cmax));
    }
}

// ---------------------------------------------------------------------------
// feats -> 1x1 conv (wc) + relu, writes hcat[:, 7500:7640]
// ---------------------------------------------------------------------------
__global__ __launch_bounds__(256) void feats_kernel(const float* __restrict__ eigbuf,
                                                    const unsigned int* __restrict__ gmax,
                                                    const float* __restrict__ wc,
                                                    const float* __restrict__ bc,
                                                    float* __restrict__ hcat)
{
    const int n = blockIdx.x;
    const int t = threadIdx.x;
    if (t >= 140) return;
    const int o = t / 7, j = t % 7;
    const float* eb = eigbuf + n * 21;
    const float vmax = __uint_as_float(gmax[0]);
    const float cmax = __uint_as_float(gmax[1]);
    float f0, f1, f2;
    if (j < 3)       { f0 = eb[0*3+j]/cmax; f1 = eb[1*3+j]/cmax; f2 = eb[2*3+j]/cmax; }
    else if (j == 3) { f0 = eb[9]/vmax;     f1 = eb[10]/vmax;    f2 = eb[11]/vmax; }
    else             { int k = j-4; f0 = eb[12+0*3+k]; f1 = eb[12+1*3+k]; f2 = eb[12+2*3+k]; }
    float r = bc[o] + wc[o*3+0]*f0 + wc[o*3+1]*f1 + wc[o*3+2]*f2;
    hcat[(size_t)n*HCATW + 7500 + o*7 + j] = fmaxf(r, 0.f);
}

// ---------------------------------------------------------------------------
// FC0+FC1 fused, 4 samples per block (512 threads), h staged in LDS.
// Wave owns a 4-wide o-tile: 16 accumulators => each h b128 feeds 16 FMAs.
// ---------------------------------------------------------------------------
__global__ __launch_bounds__(512) void fc01_kernel(const float* __restrict__ hcat,
                                                   const float* __restrict__ wl0,
                                                   const float* __restrict__ bl0,
                                                   const float* __restrict__ wl1,
                                                   const float* __restrict__ bl1,
                                                   float* __restrict__ out)
{
    __shared__ float hl[FCNS * HCATW];     // 122,240 B
    __shared__ float hbuf[FCNS * HID];     //   1,600 B
    const int tid = threadIdx.x;
    const int n0 = blockIdx.x * FCNS;
    for (int i = tid; i < FCNS * (HCATW/4); i += 512) {
        int s  = i / (HCATW/4);
        int k4 = i - s * (HCATW/4);
        ((float4*)hl)[s * (HCATW/4) + k4] =
            *(const float4*)(hcat + (size_t)(n0 + s) * HCATW + k4 * 4);
    }
    __syncthreads();
    const int wv = tid >> 6;
    const int lane = tid & 63;
    for (int ot = wv; ot < HID / 4; ot += 8) {      // 25 o-tiles of 4
        float acc[4][FCNS];
#pragma unroll
        for (int oo = 0; oo < 4; ++oo)
#pragma unroll
            for (int s = 0; s < FCNS; ++s) acc[oo][s] = 0.f;
        for (int k = lane * 4; k < HCATW; k += 256) {
            float4 hv[FCNS];
#pragma unroll
            for (int s = 0; s < FCNS; ++s)
                hv[s] = *(const float4*)(hl + s * HCATW + k);
#pragma unroll
            for (int oo = 0; oo < 4; ++oo) {
                const float4 w4 = *(const float4*)(wl0 + (size_t)(ot*4+oo) * HCATW + k);
#pragma unroll
                for (int s = 0; s < FCNS; ++s) {
                    acc[oo][s] = fmaf(hv[s].x, w4.x, acc[oo][s]);
                    acc[oo][s] = fmaf(hv[s].y, w4.y, acc[oo][s]);
                    acc[oo][s] = fmaf(hv[s].z, w4.z, acc[oo][s]);
                    acc[oo][s] = fmaf(hv[s].w, w4.w, acc[oo][s]);
                }
            }
        }
#pragma unroll
        for (int off = 32; off > 0; off >>= 1)
#pragma unroll
            for (int oo = 0; oo < 4; ++oo)
#pragma unroll
                for (int s = 0; s < FCNS; ++s)
                    acc[oo][s] += __shfl_down(acc[oo][s], off, 64);
        if (lane == 0) {
#pragma unroll
            for (int oo = 0; oo < 4; ++oo) {
                const float b = bl0[ot*4+oo];
#pragma unroll
                for (int s = 0; s < FCNS; ++s)
                    hbuf[s * HID + ot*4+oo] = fmaxf(acc[oo][s] + b, 0.f);
            }
        }
    }
    __syncthreads();
    if (tid < 2 * FCNS) {
        const int s = tid >> 1, r = tid & 1;
        const float* w = wl1 + r * HID;
        float acc = bl1[r];
        for (int k = 0; k < HID; ++k) acc = fmaf(hbuf[s * HID + k], w[k], acc);
        out[r * NBATCH + n0 + s] = acc;
    }
}

// ---------------------------------------------------------------------------
// launch
// ---------------------------------------------------------------------------
extern "C" void kernel_launch(void* const* d_in, const int* in_sizes, int n_in,
                              void* d_out, int out_size, void* d_ws, size_t ws_size,
                              hipStream_t stream)
{
    const float* x   = (const float*)d_in[0];
    const float* w0  = (const float*)d_in[1];
    const float* b0  = (const float*)d_in[2];
    const float* w1  = (const float*)d_in[3];
    const float* b1  = (const float*)d_in[4];
    const float* w2  = (const float*)d_in[5];
    const float* b2  = (const float*)d_in[6];
    const float* w3  = (const float*)d_in[7];
    const float* b3  = (const float*)d_in[8];
    const float* wc  = (const float*)d_in[9];
    const float* bc  = (const float*)d_in[10];
    const float* wl0 = (const float*)d_in[11];
    const float* bl0 = (const float*)d_in[12];
    const float* wl1 = (const float*)d_in[13];
    const float* bl1 = (const float*)d_in[14];
    float* out = (float*)d_out;

    // workspace layout (floats)
    const size_t HCAT_N = (size_t)NBATCH * HCATW;        // 7,823,360
    const size_t EIG_N  = (size_t)NBATCH * 21;
    const size_t need_bytes = (HCAT_N + EIG_N + 4 + WREPSZ) * 4 + 16;
    if (ws_size < need_bytes) return;

    float* ws     = (float*)d_ws;
    float* hcat   = ws;
    float* eigbuf = hcat + HCAT_N;
    unsigned int* gmax = (unsigned int*)(eigbuf + EIG_N);
    float* wrep   = (float*)(gmax + 4);

    hipMemsetAsync(gmax, 0, 2 * sizeof(unsigned int), stream);

    repack_kernel<<<24, 256, 0, stream>>>(w0, b0, w1, b1, w2, b2, w3, b3, wrep);
    conv_chain_eo<<<NBATCH * NCHK, 512, 0, stream>>>(x, wrep, hcat);
    cov_eig_kernel<<<NBATCH, 256, 0, stream>>>(x, eigbuf, gmax);
    feats_kernel<<<NBATCH, 256, 0, stream>>>(eigbuf, gmax, wc, bc, hcat);
    fc01_kernel<<<NBATCH / FCNS, 512, 0, stream>>>(hcat, wl0, bl0, wl1, bl1, out);
}

// Round 3
// 704.118 us; speedup vs baseline: 1.1492x; 1.0261x over previous
//
#include <hip/hip_runtime.h>
#include <hip/hip_bf16.h>
#include <hip/hip_fp16.h>
#include <math.h>

// ---------------------------------------------------------------------------
// Problem constants
// ---------------------------------------------------------------------------
#define NBATCH 1024
#define LIN    6000
#define HCATW  7640       // 20*375 + 20*7
#define HID    100

// conv-chain chunking: T=54 final(375-res) positions per block, 7 chunks.
//   JOUT chain = 8T+14, 4T+6, 2T+2, T = 446, 222, 110, 54
// R9: JBLK=2 (128-wide j-blocks/task) -> 579us @ 2 blocks/CU, VALUBusy 70%.
// R10: s1-out stored fp16 (E,O)-interleaved. LDS 64,096 -> 49,888 B
//   => 3 blocks/CU (the 30% idle was correlated stalls with only 2
//   near-synchronized blocks resident). s2's reads get CHEAPER: one
//   ds_read2_b32 yields (e0,o0,e1,o1). Single fp16 quantization point.
#define TCH   54
#define NCHK  7

#define ASZ 3552            // max(x-buf 3*894=2682, s1-out fp16 32*111dw=3552)
#define BSZ 8920            // max(s0-out 20*446=8920, s2-out 64*110=7040)

// repacked-weight offsets (floats) inside wrep
#define W0OFF 0             // 4ocg*3ic*16  = 192
#define W1OFF 192           // 4*20*24      = 1920
#define W2OFF 2112          // 8*32*24      = 6144
#define W3OFF 8256          // 4*64*16      = 4096
#define B0OFF 12352
#define B1OFF 12372
#define B2OFF 12404
#define B3OFF 12468
#define WREPSZ 12496

// fc01: samples per block
#define FCNS 4

// ---------------------------------------------------------------------------
// Weight repack
// ---------------------------------------------------------------------------
__device__ __forceinline__ void pack_one(int idx, int OC, int IC, int OCG,
                                         int OPG, int WSTR,
                                         const float* __restrict__ w,
                                         float* __restrict__ dst)
{
    if (idx >= OCG * IC * WSTR) return;
    int ocg = idx / (IC * WSTR);
    int r   = idx - ocg * (IC * WSTR);
    int ic  = r / WSTR;
    int q   = r - ic * WSTR;
    int o   = q / 3, k = q - o * 3;
    int oc  = ocg * OPG + o;
    dst[idx] = (o < OPG && oc < OC) ? w[(oc * IC + ic) * 3 + k] : 0.f;
}

__global__ __launch_bounds__(256) void repack_kernel(
    const float* __restrict__ w0, const float* __restrict__ b0,
    const float* __restrict__ w1, const float* __restrict__ b1,
    const float* __restrict__ w2, const float* __restrict__ b2,
    const float* __restrict__ w3, const float* __restrict__ b3,
    float* __restrict__ wrep)
{
    int idx = blockIdx.x * 256 + threadIdx.x;
    pack_one(idx, 20,  3, 4, 5, 16, w0, wrep + W0OFF);
    pack_one(idx, 32, 20, 4, 8, 24, w1, wrep + W1OFF);
    pack_one(idx, 64, 32, 8, 8, 24, w2, wrep + W2OFF);
    pack_one(idx, 20, 64, 4, 5, 16, w3, wrep + W3OFF);
    if (idx < 20)            wrep[B0OFF + idx] = b0[idx];
    else if (idx < 52)  { int i = idx - 20;  wrep[B1OFF + i] = b1[i]; }
    else if (idx < 116) { int i = idx - 52;  wrep[B2OFF + i] = b2[i]; }
    else if (idx < 136) { int i = idx - 116; wrep[B3OFF + i] = b3[i]; }
}

// ---------------------------------------------------------------------------
// One conv(K=3,SAME)+ReLU+pool2 stage on LDS buffers.
// 8 waves per block (512 threads), wave-strided tasks of JBLK*64 outputs.
// Weights via VMEM (vmcnt) so lgkm only carries activation ds_reads.
// fp32 buffers: even/odd-split planes (2*PIN floats per channel).
// fp16 buffers: (E,O)-interleaved shorts: short index p = pooled column p,
//   channel stride JOUT shorts = PIN dwords; consumer fetches
//   (e0,o0,e1,o1) with a single ds_read2_b32 at dword jc.
// ---------------------------------------------------------------------------
template<int IC, int OC, int OCG, int OPG, int WSTR, int JOUT, int LG, int JBLK,
         bool IN16, bool OUT16, bool FINAL>
__device__ __forceinline__ void stage_eo(const float* __restrict__ in,
                                         float* __restrict__ out,
                                         float* __restrict__ outg,
                                         const float* __restrict__ wrep,
                                         const float* __restrict__ brep,
                                         int pbase, int o3, int wv, int lane,
                                         int zero)
{
    constexpr int PIN  = JOUT + 1;
    constexpr int POUT = JOUT / 2;
    constexpr int NJT  = (JOUT + 64 * JBLK - 1) / (64 * JBLK);
    for (int task = wv; task < OCG * NJT; task += 8) {
        const int ocg = task / NJT;                 // wave-uniform (wv uniform)
        const int jt  = task - ocg * NJT;
        const int j0  = jt * (64 * JBLK) + lane;
        const float* bp = brep + ocg * OPG;
        float ae[JBLK][OPG], ao[JBLK][OPG];
#pragma unroll
        for (int t = 0; t < JBLK; ++t)
#pragma unroll
            for (int o = 0; o < OPG; ++o) { ae[t][o] = bp[o]; ao[t][o] = ae[t][o]; }
        const float* wbase = wrep + ocg * (IC * WSTR) + zero;  // stays VMEM
#pragma unroll 2
        for (int ic = 0; ic < IC; ++ic) {
            const float* wp = wbase + ic * WSTR;
            float wr[WSTR];
#pragma unroll
            for (int q = 0; q < WSTR / 4; ++q)
                *(float4*)&wr[q * 4] = *(const float4*)(wp + q * 4);
#pragma unroll
            for (int t = 0; t < JBLK; ++t) {
                const int jj = j0 + t * 64;
                const int jc = (jj < JOUT) ? jj : (JOUT - 1);
                float e0, e1, o0, o1;
                if constexpr (IN16) {
                    // channel plane = PIN dwords of (E,O) fp16 pairs
                    const float* ipw = in + ic * PIN;
                    uint2 pw;
                    __builtin_memcpy(&pw, ipw + jc, 8);   // ds_read2_b32
                    __half2 h0 = *reinterpret_cast<const __half2*>(&pw.x);
                    __half2 h1 = *reinterpret_cast<const __half2*>(&pw.y);
                    e0 = __low2float(h0); o0 = __high2float(h0);
                    e1 = __low2float(h1); o1 = __high2float(h1);
                } else {
                    const float* ip = in + ic * (2 * PIN);
                    float2 ev, ov;
                    __builtin_memcpy(&ev, ip + jc, 8);        // ds_read2_b32
                    __builtin_memcpy(&ov, ip + PIN + jc, 8);  // ds_read2_b32
                    e0 = ev.x; e1 = ev.y;
                    o0 = ov.x; o1 = ov.y;
                }
#pragma unroll
                for (int o = 0; o < OPG; ++o) {
                    const float w0 = wr[o*3+0], w1 = wr[o*3+1], w2 = wr[o*3+2];
                    ae[t][o] = fmaf(e0, w0, fmaf(o0, w1, fmaf(e1, w2, ae[t][o])));
                    ao[t][o] = fmaf(o0, w0, fmaf(e1, w1, fmaf(o1, w2, ao[t][o])));
                }
            }
        }
#pragma unroll
        for (int t = 0; t < JBLK; ++t) {
            const int jj = j0 + t * 64;
            if constexpr (FINAL) {
                const int gj = o3 + jj;
                if (gj < 375 && jj < JOUT) {
#pragma unroll
                    for (int o = 0; o < OPG; ++o)
                        outg[(ocg*OPG+o) * 375 + gj] =
                            fmaxf(fmaxf(ae[t][o], ao[t][o]), 0.f);
                }
            } else {
                const int g = pbase + jj;
                const bool val = (jj < JOUT) && (g >= 0) && (g < LG);
                if (jj < JOUT) {
                    if constexpr (OUT16) {
                        __half* dh = (__half*)out;
#pragma unroll
                        for (int o = 0; o < OPG; ++o) {
                            float v = val ? fmaxf(fmaxf(ae[t][o], ao[t][o]), 0.f)
                                          : 0.f;
                            dh[(ocg*OPG+o) * JOUT + jj] = __float2half(v);
                        }
                    } else {
                        float* dst = out + ((jj & 1) ? POUT : 0) + (jj >> 1);
#pragma unroll
                        for (int o = 0; o < OPG; ++o)
                            dst[(ocg*OPG+o) * JOUT] =
                                val ? fmaxf(fmaxf(ae[t][o], ao[t][o]), 0.f) : 0.f;
                    }
                }
            }
        }
    }
}

// LDS 49,888 B -> 3 blocks/CU (24 waves/CU, 6 waves/SIMD).
__global__ __launch_bounds__(512, 6) void conv_chain_eo(
    const float* __restrict__ x,
    const float* __restrict__ wrep,
    float* __restrict__ hcat)
{
    __shared__ float A[ASZ];
    __shared__ float B[BSZ];

    const int tid  = threadIdx.x;
    const int wv   = __builtin_amdgcn_readfirstlane(tid >> 6);
    const int lane = tid & 63;
    // opaque zero: compiler can't prove uniformity -> weight loads stay VMEM
    const int zero = __builtin_amdgcn_ds_bpermute(0, 0);
    const int n     = blockIdx.x / NCHK;
    const int chunk = blockIdx.x % NCHK;
    const int o3 = chunk * TCH;
    const int p2 = 2*o3 - 1, p1 = 4*o3 - 3, p0 = 8*o3 - 7, xs = 16*o3 - 15;

    // stage x -> A in even/odd split (3 ch, 447 pairs, plane stride 894)
    const float* xn = x + (size_t)n * 3 * LIN;
    for (int idx = tid; idx < 3 * 894; idx += 512) {
        int c = idx / 894, i = idx - c * 894;
        int g = xs + i;
        float v = (g >= 0 && g < LIN) ? xn[c * LIN + g] : 0.f;
        A[c * 894 + ((i & 1) ? 447 : 0) + (i >> 1)] = v;
    }
    __syncthreads();
    stage_eo< 3, 20, 4, 5, 16, 446, 3000, 2, false, false, false>(
        A, B, nullptr, wrep + W0OFF, wrep + B0OFF, p0, o3, wv, lane, zero);
    __syncthreads();
    stage_eo<20, 32, 4, 8, 24, 222, 1500, 2, false, true,  false>(
        B, A, nullptr, wrep + W1OFF, wrep + B1OFF, p1, o3, wv, lane, zero);
    __syncthreads();
    stage_eo<32, 64, 8, 8, 24, 110,  750, 2, true,  false, false>(
        A, B, nullptr, wrep + W2OFF, wrep + B2OFF, p2, o3, wv, lane, zero);
    __syncthreads();
    stage_eo<64, 20, 4, 5, 16,  54,  375, 1, false, false, true >(
        B, nullptr, hcat + (size_t)n * HCATW,
        wrep + W3OFF, wrep + B3OFF, o3, o3, wv, lane, zero);
}

// ---------------------------------------------------------------------------
// LAPACK ssyevd (n=3, uplo='L') replica: ssytrd -> ssteqr('I') -> apply Q.
// ---------------------------------------------------------------------------
__device__ __forceinline__ float fsign(float a, float b) {
    return (b >= 0.0f) ? fabsf(a) : -fabsf(a);
}
__device__ __forceinline__ float slapy2(float xx, float yy) {
    float xa = fabsf(xx), ya = fabsf(yy);
    float w = fmaxf(xa, ya), z = fminf(xa, ya);
    if (z == 0.f) return w;
    float t = z / w;
    return w * sqrtf(1.f + t*t);
}
// LAPACK 3.10+ slartg: c >= 0 always, r = sign(f)*hypot
__device__ __forceinline__ void slartg(float f, float g, float& c, float& s, float& r) {
    if (g == 0.f)      { c = 1.f; s = 0.f; r = f; }
    else if (f == 0.f) { c = 0.f; s = (g >= 0.f ? 1.f : -1.f); r = fabsf(g); }
    else {
        float d = sqrtf(f*f + g*g);
        c = fabsf(f) / d;
        r = fsign(d, f);
        s = g / r;
    }
}
__device__ void slaev2(float a, float b, float cc,
                       float& rt1, float& rt2, float& cs1, float& sn1) {
    float sm = a + cc, df = a - cc;
    float adf = fabsf(df);
    float tb = b + b, ab = fabsf(tb);
    float acmx, acmn;
    if (fabsf(a) > fabsf(cc)) { acmx = a; acmn = cc; } else { acmx = cc; acmn = a; }
    float rt;
    if (adf > ab)      { float t = ab/adf; rt = adf*sqrtf(1.f + t*t); }
    else if (adf < ab) { float t = adf/ab; rt = ab*sqrtf(1.f + t*t); }
    else rt = ab * sqrtf(2.f);
    int sgn1;
    if (sm < 0.f)      { rt1 = 0.5f*(sm - rt); sgn1 = -1; rt2 = (acmx/rt1)*acmn - (b/rt1)*b; }
    else if (sm > 0.f) { rt1 = 0.5f*(sm + rt); sgn1 =  1; rt2 = (acmx/rt1)*acmn - (b/rt1)*b; }
    else               { rt1 = 0.5f*rt; rt2 = -0.5f*rt; sgn1 = 1; }
    float cs; int sgn2;
    if (df >= 0.f) { cs = df + rt; sgn2 = 1; } else { cs = df - rt; sgn2 = -1; }
    float acs = fabsf(cs);
    if (acs > ab) {
        float ct = -tb / cs;
        sn1 = 1.f / sqrtf(1.f + ct*ct);
        cs1 = ct * sn1;
    } else {
        if (ab == 0.f) { cs1 = 1.f; sn1 = 0.f; }
        else {
            float tn = -cs / tb;
            cs1 = 1.f / sqrtf(1.f + tn*tn);
            sn1 = tn * cs1;
        }
    }
    if (sgn1 == sgn2) { float tn = cs1; cs1 = -sn1; sn1 = tn; }
}
__device__ __forceinline__ void rot_cols(float z[3][3], int jc, float c, float s) {
    for (int i = 0; i < 3; ++i) {
        float t = z[i][jc+1];
        z[i][jc+1] = c*t - s*z[i][jc];
        z[i][jc]   = s*t + c*z[i][jc];
    }
}

__device__ void ssteqr3(float d[3], float e[2], float z[3][3]) {
    const float eps    = 5.9604645e-8f;
    const float eps2   = eps * eps;
    const float safmin = 1.17549435e-38f;
    const int n = 3;
    for (int i = 0; i < 3; ++i)
        for (int j = 0; j < 3; ++j) z[i][j] = (i == j) ? 1.f : 0.f;
    const int nmaxit = n * 30;
    int jtot = 0;
    float cw[2], sw[2];
    int l1 = 1, l, m, lend, lsv, lendsv;

L10:
    if (l1 > n) goto L160;
    if (l1 > 1) e[l1-2] = 0.f;
    if (l1 <= n-1) {
        for (m = l1; m <= n-1; ++m) {
            float tst = fabsf(e[m-1]);
            if (tst == 0.f) goto L30;
            if (tst <= (sqrtf(fabsf(d[m-1])) * sqrtf(fabsf(d[m]))) * eps) {
                e[m-1] = 0.f;
                goto L30;
            }
        }
    }
    m = n;
L30:
    l = l1; lsv = l; lend = m; lendsv = lend; l1 = m + 1;
    if (lend == l) goto L10;
    if (fabsf(d[lend-1]) < fabsf(d[l-1])) { lend = lsv; l = lendsv; }
    if (lend > l) {
L40:
        if (l != lend) {
            bool found = false;
            for (m = l; m <= lend-1; ++m) {
                float tst = e[m-1]*e[m-1];
                if (tst <= (eps2*fabsf(d[m-1]))*fabsf(d[m]) + safmin) { found = true; break; }
            }
            if (!found) m = lend;
        } else m = lend;
        if (m < lend) e[m-1] = 0.f;
        {
            float p = d[l-1];
            if (m == l) {
                d[l-1] = p;
                l = l + 1;
                if (l <= lend) goto L40;
                goto L140;
            }
            if (m == l+1) {
                float rt1, rt2, c2, s2;
                slaev2(d[l-1], e[l-1], d[l], rt1, rt2, c2, s2);
                rot_cols(z, l-1, c2, s2);
                d[l-1] = rt1; d[l] = rt2; e[l-1] = 0.f;
                l += 2;
                if (l <= lend) goto L40;
                goto L140;
            }
            if (jtot == nmaxit) goto L140;
            jtot++;
            float g = (d[l] - p) / (2.f * e[l-1]);
            float r = slapy2(g, 1.f);
            g = d[m-1] - p + e[l-1] / (g + fsign(r, g));
            float s = 1.f, c = 1.f;
            p = 0.f;
            for (int i = m-1; i >= l; --i) {
                float f = s * e[i-1];
                float b = c * e[i-1];
                slartg(g, f, c, s, r);
                if (i != m-1) e[i] = r;
                g = d[i] - p;
                r = (d[i-1] - g)*s + 2.f*c*b;
                p = s * r;
                d[i] = g + p;
                g = c*r - b;
                cw[i-l] = c; sw[i-l] = -s;
            }
            for (int jj = m-l; jj >= 1; --jj)
                rot_cols(z, l + jj - 2, cw[jj-1], sw[jj-1]);
            d[l-1] = d[l-1] - p;
            e[l-1] = g;
            goto L40;
        }
    } else {
L90:
        if (l != lend) {
            bool found = false;
            for (m = l; m >= lend+1; --m) {
                float tst = e[m-2]*e[m-2];
                if (tst <= (eps2*fabsf(d[m-1]))*fabsf(d[m-2]) + safmin) { found = true; break; }
            }
            if (!found) m = lend;
        } else m = lend;
        if (m > lend) e[m-2] = 0.f;
        {
            float p = d[l-1];
            if (m == l) {
                d[l-1] = p;
                l = l - 1;
                if (l >= lend) goto L90;
                goto L140;
            }
            if (m == l-1) {
                float rt1, rt2, c2, s2;
                slaev2(d[l-2], e[l-2], d[l-1], rt1, rt2, c2, s2);
                rot_cols(z, l-2, c2, s2);
                d[l-2] = rt1; d[l-1] = rt2; e[l-2] = 0.f;
                l -= 2;
                if (l >= lend) goto L90;
                goto L140;
            }
            if (jtot == nmaxit) goto L140;
            jtot++;
            float g = (d[l-2] - p) / (2.f * e[l-2]);
            float r = slapy2(g, 1.f);
            g = d[m-1] - p + e[l-2] / (g + fsign(r, g));
            float s = 1.f, c = 1.f;
            p = 0.f;
            for (int i = m; i <= l-1; ++i) {
                float f = s * e[i-1];
                float b = c * e[i-1];
                slartg(g, f, c, s, r);
                if (i != m) e[i-2] = r;
                g = d[i-1] - p;
                r = (d[i] - g)*s + 2.f*c*b;
                p = s * r;
                d[i-1] = g + p;
                g = c*r - b;
                cw[i-m] = c; sw[i-m] = s;
            }
            for (int jj = 1; jj <= l-m; ++jj)
                rot_cols(z, m + jj - 2, cw[jj-1], sw[jj-1]);
            d[l-1] = d[l-1] - p;
            e[l-2] = g;
            goto L90;
        }
    }
L140:
    if (jtot < nmaxit) goto L10;
L160:
    for (int ii = 2; ii <= n; ++ii) {
        int i = ii - 1, k = i;
        float p = d[i-1];
        for (int j = ii; j <= n; ++j)
            if (d[j-1] < p) { k = j; p = d[j-1]; }
        if (k != i) {
            d[k-1] = d[i-1]; d[i-1] = p;
            for (int r0 = 0; r0 < 3; ++r0) {
                float t = z[r0][i-1]; z[r0][i-1] = z[r0][k-1]; z[r0][k-1] = t;
            }
        }
    }
}

// ---------------------------------------------------------------------------
// cov + eig kernel
// ---------------------------------------------------------------------------
__global__ __launch_bounds__(256) void cov_eig_kernel(const float* __restrict__ x,
                                                      float* __restrict__ eigbuf,
                                                      unsigned int* __restrict__ gmax)
{
    __shared__ float part[4][9];
    const int n = blockIdx.x;
    const float* xn = x + (size_t)n * 3 * LIN;
    float v[9] = {0,0,0,0,0,0,0,0,0};
    for (int l = threadIdx.x; l < LIN; l += 256) {
        float a = xn[l], b = xn[LIN + l], c = xn[2*LIN + l];
        v[0] += a; v[1] += b; v[2] += c;
        v[3] = fmaf(a,a,v[3]); v[4] = fmaf(a,b,v[4]); v[5] = fmaf(a,c,v[5]);
        v[6] = fmaf(b,b,v[6]); v[7] = fmaf(b,c,v[7]); v[8] = fmaf(c,c,v[8]);
    }
#pragma unroll
    for (int off = 32; off > 0; off >>= 1)
#pragma unroll
        for (int i = 0; i < 9; ++i) v[i] += __shfl_down(v[i], off, 64);
    const int wv = threadIdx.x >> 6, lane = threadIdx.x & 63;
    if (lane == 0)
        for (int i = 0; i < 9; ++i) part[wv][i] = v[i];
    __syncthreads();
    if (threadIdx.x == 0) {
        float t[9];
        for (int i = 0; i < 9; ++i)
            t[i] = part[0][i] + part[1][i] + part[2][i] + part[3][i];
        const float Lf = (float)LIN;
        float m0 = t[0]/Lf, m1 = t[1]/Lf, m2 = t[2]/Lf;
        float c00 = (t[3] - Lf*m0*m0) / (Lf - 1.f);
        float c01 = (t[4] - Lf*m0*m1) / (Lf - 1.f);
        float c02 = (t[5] - Lf*m0*m2) / (Lf - 1.f);
        float c11 = (t[6] - Lf*m1*m1) / (Lf - 1.f);
        float c12 = (t[7] - Lf*m1*m2) / (Lf - 1.f);
        float c22 = (t[8] - Lf*m2*m2) / (Lf - 1.f);

        float dd[3], ee[2], tau, v2;
        {
            float a21 = c01, a31 = c02, a22 = c11, a32 = c12, a33 = c22;
            float xnorm = fabsf(a31);
            if (xnorm == 0.f) {
                tau = 0.f; v2 = 0.f;
                dd[0] = c00; dd[1] = a22; dd[2] = a33;
                ee[0] = a21; ee[1] = a32;
            } else {
                float beta = -fsign(slapy2(a21, xnorm), a21);
                tau = (beta - a21) / beta;
                v2  = a31 / (a21 - beta);
                ee[0] = beta;
                float x1 = tau*(a22 + a32*v2);
                float x2 = tau*(a32 + a33*v2);
                float al = -0.5f*tau*(x1 + x2*v2);
                float w1 = x1 + al;
                float w2 = x2 + al*v2;
                a22 -= 2.f*w1;
                a32 -= (v2*w1 + w2);
                a33 -= 2.f*v2*w2;
                dd[0] = c00; dd[1] = a22; dd[2] = a33;
                ee[1] = a32;
            }
        }
        float zz[3][3];
        ssteqr3(dd, ee, zz);
        if (tau != 0.f) {
            for (int j = 0; j < 3; ++j) {
                float sum = zz[1][j] + v2*zz[2][j];
                zz[1][j] -= tau * sum;
                zz[2][j] -= tau * v2 * sum;
            }
        }

        float* eb = eigbuf + n * 21;
        eb[0] = c00; eb[1] = c01; eb[2] = c02;
        eb[3] = c01; eb[4] = c11; eb[5] = c12;
        eb[6] = c02; eb[7] = c12; eb[8] = c22;
        eb[9] = dd[0]; eb[10] = dd[1]; eb[11] = dd[2];
        for (int c = 0; c < 3; ++c)
            for (int k = 0; k < 3; ++k) eb[12 + c*3 + k] = zz[c][k];

        float vmax = fmaxf(dd[0], fmaxf(dd[1], dd[2]));
        float cmax = 0.f;
        for (int i = 0; i < 9; ++i) cmax = fmaxf(cmax, fabsf(eb[i]));
        atomicMax(&gmax[0], __float_as_uint(vmax));
        atomicMax(&gmax[1], __float_as_uint(cmax));
    }
}

// ---------------------------------------------------------------------------
// feats -> 1x1 conv (wc) + relu, writes hcat[:, 7500:7640]
// ---------------------------------------------------------------------------
__global__ __launch_bounds__(256) void feats_kernel(const float* __restrict__ eigbuf,
                                                    const unsigned int* __restrict__ gmax,
                                                    const float* __restrict__ wc,
                                                    const float* __restrict__ bc,
                                                    float* __restrict__ hcat)
{
    const int n = blockIdx.x;
    const int t = threadIdx.x;
    if (t >= 140) return;
    const int o = t / 7, j = t % 7;
    const float* eb = eigbuf + n * 21;
    const float vmax = __uint_as_float(gmax[0]);
    const float cmax = __uint_as_float(gmax[1]);
    float f0, f1, f2;
    if (j < 3)       { f0 = eb[0*3+j]/cmax; f1 = eb[1*3+j]/cmax; f2 = eb[2*3+j]/cmax; }
    else if (j == 3) { f0 = eb[9]/vmax;     f1 = eb[10]/vmax;    f2 = eb[11]/vmax; }
    else             { int k = j-4; f0 = eb[12+0*3+k]; f1 = eb[12+1*3+k]; f2 = eb[12+2*3+k]; }
    float r = bc[o] + wc[o*3+0]*f0 + wc[o*3+1]*f1 + wc[o*3+2]*f2;
    hcat[(size_t)n*HCATW + 7500 + o*7 + j] = fmaxf(r, 0.f);
}

// ---------------------------------------------------------------------------
// FC0+FC1 fused, 4 samples per block (512 threads), h staged in LDS.
// Wave owns a 4-wide o-tile: 16 accumulators => each h b128 feeds 16 FMAs.
// ---------------------------------------------------------------------------
__global__ __launch_bounds__(512) void fc01_kernel(const float* __restrict__ hcat,
                                                   const float* __restrict__ wl0,
                                                   const float* __restrict__ bl0,
                                                   const float* __restrict__ wl1,
                                                   const float* __restrict__ bl1,
                                                   float* __restrict__ out)
{
    __shared__ float hl[FCNS * HCATW];     // 122,240 B
    __shared__ float hbuf[FCNS * HID];     //   1,600 B
    const int tid = threadIdx.x;
    const int n0 = blockIdx.x * FCNS;
    for (int i = tid; i < FCNS * (HCATW/4); i += 512) {
        int s  = i / (HCATW/4);
        int k4 = i - s * (HCATW/4);
        ((float4*)hl)[s * (HCATW/4) + k4] =
            *(const float4*)(hcat + (size_t)(n0 + s) * HCATW + k4 * 4);
    }
    __syncthreads();
    const int wv = tid >> 6;
    const int lane = tid & 63;
    for (int ot = wv; ot < HID / 4; ot += 8) {      // 25 o-tiles of 4
        float acc[4][FCNS];
#pragma unroll
        for (int oo = 0; oo < 4; ++oo)
#pragma unroll
            for (int s = 0; s < FCNS; ++s) acc[oo][s] = 0.f;
        for (int k = lane * 4; k < HCATW; k += 256) {
            float4 hv[FCNS];
#pragma unroll
            for (int s = 0; s < FCNS; ++s)
                hv[s] = *(const float4*)(hl + s * HCATW + k);
#pragma unroll
            for (int oo = 0; oo < 4; ++oo) {
                const float4 w4 = *(const float4*)(wl0 + (size_t)(ot*4+oo) * HCATW + k);
#pragma unroll
                for (int s = 0; s < FCNS; ++s) {
                    acc[oo][s] = fmaf(hv[s].x, w4.x, acc[oo][s]);
                    acc[oo][s] = fmaf(hv[s].y, w4.y, acc[oo][s]);
                    acc[oo][s] = fmaf(hv[s].z, w4.z, acc[oo][s]);
                    acc[oo][s] = fmaf(hv[s].w, w4.w, acc[oo][s]);
                }
            }
        }
#pragma unroll
        for (int off = 32; off > 0; off >>= 1)
#pragma unroll
            for (int oo = 0; oo < 4; ++oo)
#pragma unroll
                for (int s = 0; s < FCNS; ++s)
                    acc[oo][s] += __shfl_down(acc[oo][s], off, 64);
        if (lane == 0) {
#pragma unroll
            for (int oo = 0; oo < 4; ++oo) {
                const float b = bl0[ot*4+oo];
#pragma unroll
                for (int s = 0; s < FCNS; ++s)
                    hbuf[s * HID + ot*4+oo] = fmaxf(acc[oo][s] + b, 0.f);
            }
        }
    }
    __syncthreads();
    if (tid < 2 * FCNS) {
        const int s = tid >> 1, r = tid & 1;
        const float* w = wl1 + r * HID;
        float acc = bl1[r];
        for (int k = 0; k < HID; ++k) acc = fmaf(hbuf[s * HID + k], w[k], acc);
        out[r * NBATCH + n0 + s] = acc;
    }
}

// ---------------------------------------------------------------------------
// launch
// ---------------------------------------------------------------------------
extern "C" void kernel_launch(void* const* d_in, const int* in_sizes, int n_in,
                              void* d_out, int out_size, void* d_ws, size_t ws_size,
                              hipStream_t stream)
{
    const float* x   = (const float*)d_in[0];
    const float* w0  = (const float*)d_in[1];
    const float* b0  = (const float*)d_in[2];
    const float* w1  = (const float*)d_in[3];
    const float* b1  = (const float*)d_in[4];
    const float* w2  = (const float*)d_in[5];
    const float* b2  = (const float*)d_in[6];
    const float* w3  = (const float*)d_in[7];
    const float* b3  = (const float*)d_in[8];
    const float* wc  = (const float*)d_in[9];
    const float* bc  = (const float*)d_in[10];
    const float* wl0 = (const float*)d_in[11];
    const float* bl0 = (const float*)d_in[12];
    const float* wl1 = (const float*)d_in[13];
    const float* bl1 = (const float*)d_in[14];
    float* out = (float*)d_out;

    // workspace layout (floats)
    const size_t HCAT_N = (size_t)NBATCH * HCATW;        // 7,823,360
    const size_t EIG_N  = (size_t)NBATCH * 21;
    const size_t need_bytes = (HCAT_N + EIG_N + 4 + WREPSZ) * 4 + 16;
    if (ws_size < need_bytes) return;

    float* ws     = (float*)d_ws;
    float* hcat   = ws;
    float* eigbuf = hcat + HCAT_N;
    unsigned int* gmax = (unsigned int*)(eigbuf + EIG_N);
    float* wrep   = (float*)(gmax + 4);

    hipMemsetAsync(gmax, 0, 2 * sizeof(unsigned int), stream);

    repack_kernel<<<24, 256, 0, stream>>>(w0, b0, w1, b1, w2, b2, w3, b3, wrep);
    conv_chain_eo<<<NBATCH * NCHK, 512, 0, stream>>>(x, wrep, hcat);
    cov_eig_kernel<<<NBATCH, 256, 0, stream>>>(x, eigbuf, gmax);
    feats_kernel<<<NBATCH, 256, 0, stream>>>(eigbuf, gmax, wc, bc, hcat);
    fc01_kernel<<<NBATCH / FCNS, 512, 0, stream>>>(hcat, wl0, bl0, wl1, bl1, out);
}

// Round 4
// 651.993 us; speedup vs baseline: 1.2411x; 1.0799x over previous
//
#include <hip/hip_runtime.h>
#include <hip/hip_bf16.h>
#include <hip/hip_fp16.h>
#include <math.h>

// ---------------------------------------------------------------------------
// Problem constants
// ---------------------------------------------------------------------------
#define NBATCH 1024
#define LIN    6000
#define HCATW  7640       // 20*375 + 20*7
#define HID    100

// conv-chain chunking: T=54 final(375-res) positions per block, 7 chunks.
//   JOUT chain = 8T+14, 4T+6, 2T+2, T = 446, 222, 110, 54
// R10: s1-out fp16 -> 3 blocks/CU, 529us, VALUBusy 84% (issue-bound now).
// R11: (a) s0-out also fp16; s1+s2 use packed-fp16 weights and
//   v_dot2_f32_f16 (fp16 products, FP32 accumulate): 6 fma -> 2 dot2 + 2 fma
//   per (o,t,ic), weight loads 6->4 b128/ic. (b) s3 split into 2x32-ic
//   halves across all 8 waves (partials through LDS A + one barrier).
//   Critical path/chunk 8416 -> ~5600 wave-instrs (-34%).
#define TCH   54
#define NCHK  7

#define ASZ 3552            // max(x-buf 2682, s1-out fp16 32*111dw=3552, s3 partials 2560)
#define BSZ 7040            // max(s0-out fp16 20*223dw=4460, s2-out 64*110=7040)

// repacked-weight offsets (dwords) inside wrep
// s0/s3: fp32, per (ocg,ic) 16 floats (5o x 3 + pad)
// s1/s2: packed, per (ocg,ic) 16 dwords: [0..7]=half2(w0,w1) o=0..7, [8..15]=f32 w2
#define W0OFF 0             // 4*3*16   = 192
#define W1OFF 192           // 4*20*16  = 1280
#define W2OFF 1472          // 8*32*16  = 4096
#define W3OFF 5568          // 4*64*16  = 4096
#define B0OFF 9664
#define B1OFF 9684
#define B2OFF 9716
#define B3OFF 9780
#define WREPSZ 9800

// fc01: samples per block
#define FCNS 4

typedef _Float16 v2h __attribute__((ext_vector_type(2)));

__device__ __forceinline__ float fdot2_f16(unsigned int a, unsigned int b, float c) {
#if __has_builtin(__builtin_amdgcn_fdot2)
    v2h ah, bh;
    __builtin_memcpy(&ah, &a, 4);
    __builtin_memcpy(&bh, &b, 4);
    return __builtin_amdgcn_fdot2(ah, bh, c, false);
#else
    float d;
    asm("v_dot2_f32_f16 %0, %1, %2, %3" : "=v"(d) : "v"(a), "v"(b), "v"(c));
    return d;
#endif
}

// ---------------------------------------------------------------------------
// Weight repack
// ---------------------------------------------------------------------------
__device__ __forceinline__ void pack_one(int idx, int OC, int IC, int OCG,
                                         int OPG, int WSTR,
                                         const float* __restrict__ w,
                                         float* __restrict__ dst)
{
    if (idx >= OCG * IC * WSTR) return;
    int ocg = idx / (IC * WSTR);
    int r   = idx - ocg * (IC * WSTR);
    int ic  = r / WSTR;
    int q   = r - ic * WSTR;
    int o   = q / 3, k = q - o * 3;
    int oc  = ocg * OPG + o;
    dst[idx] = (o < OPG && oc < OC) ? w[(oc * IC + ic) * 3 + k] : 0.f;
}

// packed-fp16 pack: OC multiple of 8, per (ocg,ic) 16 dwords
__device__ __forceinline__ void pack_pk(int idx, int OC, int IC,
                                        const float* __restrict__ w,
                                        unsigned int* __restrict__ dst)
{
    const int OCG = OC >> 3;
    if (idx >= OCG * IC * 16) return;
    int ocg = idx / (IC * 16);
    int r   = idx - ocg * (IC * 16);
    int ic  = r >> 4, q = r & 15;
    int o   = q & 7;
    int oc  = ocg * 8 + o;
    const float* ws = w + (oc * IC + ic) * 3;
    if (q < 8) {
        unsigned int lo = __half_as_ushort(__float2half(ws[0]));
        unsigned int hi = __half_as_ushort(__float2half(ws[1]));
        dst[idx] = lo | (hi << 16);
    } else {
        dst[idx] = __float_as_uint(ws[2]);
    }
}

__global__ __launch_bounds__(256) void repack_kernel(
    const float* __restrict__ w0, const float* __restrict__ b0,
    const float* __restrict__ w1, const float* __restrict__ b1,
    const float* __restrict__ w2, const float* __restrict__ b2,
    const float* __restrict__ w3, const float* __restrict__ b3,
    float* __restrict__ wrep)
{
    int idx = blockIdx.x * 256 + threadIdx.x;
    unsigned int* wu = (unsigned int*)wrep;
    pack_one(idx, 20,  3, 4, 5, 16, w0, wrep + W0OFF);
    pack_pk (idx, 32, 20, w1, wu + W1OFF);
    pack_pk (idx, 64, 32, w2, wu + W2OFF);
    pack_one(idx, 20, 64, 4, 5, 16, w3, wrep + W3OFF);
    if (idx < 20)            wrep[B0OFF + idx] = b0[idx];
    else if (idx < 52)  { int i = idx - 20;  wrep[B1OFF + i] = b1[i]; }
    else if (idx < 116) { int i = idx - 52;  wrep[B2OFF + i] = b2[i]; }
    else if (idx < 136) { int i = idx - 116; wrep[B3OFF + i] = b3[i]; }
}

// ---------------------------------------------------------------------------
// One conv(K=3,SAME)+ReLU+pool2 stage on LDS buffers.
// 8 waves per block (512 threads), wave-strided tasks of JBLK*64 outputs.
// fp32 buffers: even/odd-split planes (2*PIN floats per channel).
// fp16 buffers: interleaved shorts, plane stride PIN dwords; dword p =
//   (pooled[2p], pooled[2p+1]); one ds_read2_b32 at dword jc yields
//   (e0,o0,e1,o1).
// PKW: weights packed per (ocg,ic) as 16 dwords ([0..7] half2(w0,w1),
//   [8..15] f32 w2); math = 2x v_dot2_f32_f16 + 2x fma per o (fp32 accum).
// ---------------------------------------------------------------------------
template<int IC, int OC, int OCG, int OPG, int WSTR, int JOUT, int LG, int JBLK,
         bool IN16, bool OUT16, bool PKW, bool FINAL>
__device__ __forceinline__ void stage_eo(const float* __restrict__ in,
                                         float* __restrict__ out,
                                         float* __restrict__ outg,
                                         const float* __restrict__ wrep,
                                         const float* __restrict__ brep,
                                         int pbase, int o3, int wv, int lane,
                                         int zero)
{
    constexpr int PIN  = JOUT + 1;
    constexpr int POUT = JOUT / 2;
    constexpr int NJT  = (JOUT + 64 * JBLK - 1) / (64 * JBLK);
    for (int task = wv; task < OCG * NJT; task += 8) {
        const int ocg = task / NJT;                 // wave-uniform (wv uniform)
        const int jt  = task - ocg * NJT;
        const int j0  = jt * (64 * JBLK) + lane;
        const float* bp = brep + ocg * OPG;
        float ae[JBLK][OPG], ao[JBLK][OPG];
#pragma unroll
        for (int t = 0; t < JBLK; ++t)
#pragma unroll
            for (int o = 0; o < OPG; ++o) { ae[t][o] = bp[o]; ao[t][o] = ae[t][o]; }
        const float* wbase = wrep + ocg * (IC * WSTR) + zero;  // stays VMEM
#pragma unroll 2
        for (int ic = 0; ic < IC; ++ic) {
            const float* wp = wbase + ic * WSTR;
            float wr[WSTR];
#pragma unroll
            for (int q = 0; q < WSTR / 4; ++q)
                *(float4*)&wr[q * 4] = *(const float4*)(wp + q * 4);
#pragma unroll
            for (int t = 0; t < JBLK; ++t) {
                const int jj = j0 + t * 64;
                const int jc = (jj < JOUT) ? jj : (JOUT - 1);
                if constexpr (PKW) {
                    // IN16 guaranteed: dword p = (pooled[2p], pooled[2p+1])
                    const float* ipw = in + ic * PIN;
                    uint2 pw;
                    __builtin_memcpy(&pw, ipw + jc, 8);   // ds_read2_b32
                    const unsigned int crossu = (pw.x >> 16) | (pw.y << 16); // (o0,e1)
                    v2h h1; __builtin_memcpy(&h1, &pw.y, 4);
                    const float e1 = (float)h1.x, o1 = (float)h1.y;
#pragma unroll
                    for (int o = 0; o < OPG; ++o) {
                        const unsigned int wpk = __float_as_uint(wr[o]);
                        const float w2 = wr[8 + o];
                        ae[t][o] = fdot2_f16(pw.x,  wpk, ae[t][o]);   // e0*w0+o0*w1
                        ao[t][o] = fdot2_f16(crossu, wpk, ao[t][o]);  // o0*w0+e1*w1
                        ae[t][o] = fmaf(e1, w2, ae[t][o]);
                        ao[t][o] = fmaf(o1, w2, ao[t][o]);
                    }
                } else {
                    float e0, e1, o0, o1;
                    if constexpr (IN16) {
                        const float* ipw = in + ic * PIN;
                        uint2 pw;
                        __builtin_memcpy(&pw, ipw + jc, 8);   // ds_read2_b32
                        __half2 h0 = *reinterpret_cast<const __half2*>(&pw.x);
                        __half2 h1 = *reinterpret_cast<const __half2*>(&pw.y);
                        e0 = __low2float(h0); o0 = __high2float(h0);
                        e1 = __low2float(h1); o1 = __high2float(h1);
                    } else {
                        const float* ip = in + ic * (2 * PIN);
                        float2 ev, ov;
                        __builtin_memcpy(&ev, ip + jc, 8);        // ds_read2_b32
                        __builtin_memcpy(&ov, ip + PIN + jc, 8);  // ds_read2_b32
                        e0 = ev.x; e1 = ev.y;
                        o0 = ov.x; o1 = ov.y;
                    }
#pragma unroll
                    for (int o = 0; o < OPG; ++o) {
                        const float w0 = wr[o*3+0], w1 = wr[o*3+1], w2 = wr[o*3+2];
                        ae[t][o] = fmaf(e0, w0, fmaf(o0, w1, fmaf(e1, w2, ae[t][o])));
                        ao[t][o] = fmaf(o0, w0, fmaf(e1, w1, fmaf(o1, w2, ao[t][o])));
                    }
                }
            }
        }
#pragma unroll
        for (int t = 0; t < JBLK; ++t) {
            const int jj = j0 + t * 64;
            if constexpr (FINAL) {
                const int gj = o3 + jj;
                if (gj < 375 && jj < JOUT) {
#pragma unroll
                    for (int o = 0; o < OPG; ++o)
                        outg[(ocg*OPG+o) * 375 + gj] =
                            fmaxf(fmaxf(ae[t][o], ao[t][o]), 0.f);
                }
            } else {
                const int g = pbase + jj;
                const bool val = (jj < JOUT) && (g >= 0) && (g < LG);
                if (jj < JOUT) {
                    if constexpr (OUT16) {
                        __half* dh = (__half*)out;
#pragma unroll
                        for (int o = 0; o < OPG; ++o) {
                            float v = val ? fmaxf(fmaxf(ae[t][o], ao[t][o]), 0.f)
                                          : 0.f;
                            dh[(ocg*OPG+o) * JOUT + jj] = __float2half(v);
                        }
                    } else {
                        float* dst = out + ((jj & 1) ? POUT : 0) + (jj >> 1);
#pragma unroll
                        for (int o = 0; o < OPG; ++o)
                            dst[(ocg*OPG+o) * JOUT] =
                                val ? fmaxf(fmaxf(ae[t][o], ao[t][o]), 0.f) : 0.f;
                    }
                }
            }
        }
    }
}

// ---------------------------------------------------------------------------
// Final stage (s3) split across all 8 waves: wave = (ocg 0..3) x (ic-half).
// Upper-half waves publish fp32 partials through LDS `part` (buffer A, free
// during s3), one barrier, lower-half waves combine + relu-pool + store.
// ---------------------------------------------------------------------------
__device__ __forceinline__ void stage3_split(const float* __restrict__ in,
                                             float* __restrict__ part,
                                             float* __restrict__ outg,
                                             const float* __restrict__ wrep,
                                             const float* __restrict__ brep,
                                             int o3, int wv, int lane, int zero)
{
    constexpr int JOUT = 54, PIN = 55, OPG = 5, WSTR = 16;
    const int ocg = wv & 3, ih = wv >> 2;
    const int j  = lane;
    const int jc = (j < JOUT) ? j : (JOUT - 1);
    const float* bp = brep + ocg * OPG;
    float ae[OPG], ao[OPG];
#pragma unroll
    for (int o = 0; o < OPG; ++o) {
        float b = ih ? 0.f : bp[o];
        ae[o] = b; ao[o] = b;
    }
    const float* wbase = wrep + (ocg * 64 + ih * 32) * WSTR + zero;
#pragma unroll 2
    for (int ic = 0; ic < 32; ++ic) {
        const float* ip = in + (ih * 32 + ic) * (2 * PIN);
        float2 ev, ov;
        __builtin_memcpy(&ev, ip + jc, 8);        // ds_read2_b32
        __builtin_memcpy(&ov, ip + PIN + jc, 8);  // ds_read2_b32
        const float* wp = wbase + ic * WSTR;
        float wr[WSTR];
#pragma unroll
        for (int q = 0; q < WSTR / 4; ++q)
            *(float4*)&wr[q * 4] = *(const float4*)(wp + q * 4);
#pragma unroll
        for (int o = 0; o < OPG; ++o) {
            const float w0 = wr[o*3+0], w1 = wr[o*3+1], w2 = wr[o*3+2];
            ae[o] = fmaf(ev.x, w0, fmaf(ov.x, w1, fmaf(ev.y, w2, ae[o])));
            ao[o] = fmaf(ov.x, w0, fmaf(ev.y, w1, fmaf(ov.y, w2, ao[o])));
        }
    }
    if (ih == 1) {
#pragma unroll
        for (int o = 0; o < OPG; ++o) {
            float2 p = make_float2(ae[o], ao[o]);
            __builtin_memcpy(part + (ocg * OPG + o) * 128 + lane * 2, &p, 8);
        }
    }
    __syncthreads();
    if (ih == 0) {
#pragma unroll
        for (int o = 0; o < OPG; ++o) {
            float2 p;
            __builtin_memcpy(&p, part + (ocg * OPG + o) * 128 + lane * 2, 8);
            ae[o] += p.x; ao[o] += p.y;
        }
        const int gj = o3 + j;
        if (gj < 375 && j < JOUT) {
#pragma unroll
            for (int o = 0; o < OPG; ++o)
                outg[(ocg * OPG + o) * 375 + gj] =
                    fmaxf(fmaxf(ae[o], ao[o]), 0.f);
        }
    }
}

// LDS (3552+7040)*4 = 42,368 B -> 3 blocks/CU; cap VGPR for 6 waves/EU.
__global__ __launch_bounds__(512, 6) void conv_chain_eo(
    const float* __restrict__ x,
    const float* __restrict__ wrep,
    float* __restrict__ hcat)
{
    __shared__ float A[ASZ];
    __shared__ float B[BSZ];

    const int tid  = threadIdx.x;
    const int wv   = __builtin_amdgcn_readfirstlane(tid >> 6);
    const int lane = tid & 63;
    // opaque zero: compiler can't prove uniformity -> weight loads stay VMEM
    const int zero = __builtin_amdgcn_ds_bpermute(0, 0);
    const int n     = blockIdx.x / NCHK;
    const int chunk = blockIdx.x % NCHK;
    const int o3 = chunk * TCH;
    const int p2 = 2*o3 - 1, p1 = 4*o3 - 3, p0 = 8*o3 - 7, xs = 16*o3 - 15;

    // stage x -> A in even/odd split (3 ch, 447 pairs, plane stride 894)
    const float* xn = x + (size_t)n * 3 * LIN;
    for (int idx = tid; idx < 3 * 894; idx += 512) {
        int c = idx / 894, i = idx - c * 894;
        int g = xs + i;
        float v = (g >= 0 && g < LIN) ? xn[c * LIN + g] : 0.f;
        A[c * 894 + ((i & 1) ? 447 : 0) + (i >> 1)] = v;
    }
    __syncthreads();
    // s0: fp32 in (x), fp16 out, fp32 weights
    stage_eo< 3, 20, 4, 5, 16, 446, 3000, 2, false, true,  false, false>(
        A, B, nullptr, wrep + W0OFF, wrep + B0OFF, p0, o3, wv, lane, zero);
    __syncthreads();
    // s1: fp16 in, fp16 out, packed-fp16 weights + dot2
    stage_eo<20, 32, 4, 8, 16, 222, 1500, 2, true,  true,  true,  false>(
        B, A, nullptr, wrep + W1OFF, wrep + B1OFF, p1, o3, wv, lane, zero);
    __syncthreads();
    // s2: fp16 in, fp32 out, packed-fp16 weights + dot2
    stage_eo<32, 64, 8, 8, 16, 110,  750, 2, true,  false, true,  false>(
        A, B, nullptr, wrep + W2OFF, wrep + B2OFF, p2, o3, wv, lane, zero);
    __syncthreads();
    // s3: fp32 in, split 2x32 ic across 8 waves, partials via A
    stage3_split(B, A, hcat + (size_t)n * HCATW,
                 wrep + W3OFF, wrep + B3OFF, o3, wv, lane, zero);
}

// ---------------------------------------------------------------------------
// LAPACK ssyevd (n=3, uplo='L') replica: ssytrd -> ssteqr('I') -> apply Q.
// ---------------------------------------------------------------------------
__device__ __forceinline__ float fsign(float a, float b) {
    return (b >= 0.0f) ? fabsf(a) : -fabsf(a);
}
__device__ __forceinline__ float slapy2(float xx, float yy) {
    float xa = fabsf(xx), ya = fabsf(yy);
    float w = fmaxf(xa, ya), z = fminf(xa, ya);
    if (z == 0.f) return w;
    float t = z / w;
    return w * sqrtf(1.f + t*t);
}
// LAPACK 3.10+ slartg: c >= 0 always, r = sign(f)*hypot
__device__ __forceinline__ void slartg(float f, float g, float& c, float& s, float& r) {
    if (g == 0.f)      { c = 1.f; s = 0.f; r = f; }
    else if (f == 0.f) { c = 0.f; s = (g >= 0.f ? 1.f : -1.f); r = fabsf(g); }
    else {
        float d = sqrtf(f*f + g*g);
        c = fabsf(f) / d;
        r = fsign(d, f);
        s = g / r;
    }
}
__device__ void slaev2(float a, float b, float cc,
                       float& rt1, float& rt2, float& cs1, float& sn1) {
    float sm = a + cc, df = a - cc;
    float adf = fabsf(df);
    float tb = b + b, ab = fabsf(tb);
    float acmx, acmn;
    if (fabsf(a) > fabsf(cc)) { acmx = a; acmn = cc; } else { acmx = cc; acmn = a; }
    float rt;
    if (adf > ab)      { float t = ab/adf; rt = adf*sqrtf(1.f + t*t); }
    else if (adf < ab) { float t = adf/ab; rt = ab*sqrtf(1.f + t*t); }
    else rt = ab * sqrtf(2.f);
    int sgn1;
    if (sm < 0.f)      { rt1 = 0.5f*(sm - rt); sgn1 = -1; rt2 = (acmx/rt1)*acmn - (b/rt1)*b; }
    else if (sm > 0.f) { rt1 = 0.5f*(sm + rt); sgn1 =  1; rt2 = (acmx/rt1)*acmn - (b/rt1)*b; }
    else               { rt1 = 0.5f*rt; rt2 = -0.5f*rt; sgn1 = 1; }
    float cs; int sgn2;
    if (df >= 0.f) { cs = df + rt; sgn2 = 1; } else { cs = df - rt; sgn2 = -1; }
    float acs = fabsf(cs);
    if (acs > ab) {
        float ct = -tb / cs;
        sn1 = 1.f / sqrtf(1.f + ct*ct);
        cs1 = ct * sn1;
    } else {
        if (ab == 0.f) { cs1 = 1.f; sn1 = 0.f; }
        else {
            float tn = -cs / tb;
            cs1 = 1.f / sqrtf(1.f + tn*tn);
            sn1 = tn * cs1;
        }
    }
    if (sgn1 == sgn2) { float tn = cs1; cs1 = -sn1; sn1 = tn; }
}
__device__ __forceinline__ void rot_cols(float z[3][3], int jc, float c, float s) {
    for (int i = 0; i < 3; ++i) {
        float t = z[i][jc+1];
        z[i][jc+1] = c*t - s*z[i][jc];
        z[i][jc]   = s*t + c*z[i][jc];
    }
}

__device__ void ssteqr3(float d[3], float e[2], float z[3][3]) {
    const float eps    = 5.9604645e-8f;
    const float eps2   = eps * eps;
    const float safmin = 1.17549435e-38f;
    const int n = 3;
    for (int i = 0; i < 3; ++i)
        for (int j = 0; j < 3; ++j) z[i][j] = (i == j) ? 1.f : 0.f;
    const int nmaxit = n * 30;
    int jtot = 0;
    float cw[2], sw[2];
    int l1 = 1, l, m, lend, lsv, lendsv;

L10:
    if (l1 > n) goto L160;
    if (l1 > 1) e[l1-2] = 0.f;
    if (l1 <= n-1) {
        for (m = l1; m <= n-1; ++m) {
            float tst = fabsf(e[m-1]);
            if (tst == 0.f) goto L30;
            if (tst <= (sqrtf(fabsf(d[m-1])) * sqrtf(fabsf(d[m]))) * eps) {
                e[m-1] = 0.f;
                goto L30;
            }
        }
    }
    m = n;
L30:
    l = l1; lsv = l; lend = m; lendsv = lend; l1 = m + 1;
    if (lend == l) goto L10;
    if (fabsf(d[lend-1]) < fabsf(d[l-1])) { lend = lsv; l = lendsv; }
    if (lend > l) {
L40:
        if (l != lend) {
            bool found = false;
            for (m = l; m <= lend-1; ++m) {
                float tst = e[m-1]*e[m-1];
                if (tst <= (eps2*fabsf(d[m-1]))*fabsf(d[m]) + safmin) { found = true; break; }
            }
            if (!found) m = lend;
        } else m = lend;
        if (m < lend) e[m-1] = 0.f;
        {
            float p = d[l-1];
            if (m == l) {
                d[l-1] = p;
                l = l + 1;
                if (l <= lend) goto L40;
                goto L140;
            }
            if (m == l+1) {
                float rt1, rt2, c2, s2;
                slaev2(d[l-1], e[l-1], d[l], rt1, rt2, c2, s2);
                rot_cols(z, l-1, c2, s2);
                d[l-1] = rt1; d[l] = rt2; e[l-1] = 0.f;
                l += 2;
                if (l <= lend) goto L40;
                goto L140;
            }
            if (jtot == nmaxit) goto L140;
            jtot++;
            float g = (d[l] - p) / (2.f * e[l-1]);
            float r = slapy2(g, 1.f);
            g = d[m-1] - p + e[l-1] / (g + fsign(r, g));
            float s = 1.f, c = 1.f;
            p = 0.f;
            for (int i = m-1; i >= l; --i) {
                float f = s * e[i-1];
                float b = c * e[i-1];
                slartg(g, f, c, s, r);
                if (i != m-1) e[i] = r;
                g = d[i] - p;
                r = (d[i-1] - g)*s + 2.f*c*b;
                p = s * r;
                d[i] = g + p;
                g = c*r - b;
                cw[i-l] = c; sw[i-l] = -s;
            }
            for (int jj = m-l; jj >= 1; --jj)
                rot_cols(z, l + jj - 2, cw[jj-1], sw[jj-1]);
            d[l-1] = d[l-1] - p;
            e[l-1] = g;
            goto L40;
        }
    } else {
L90:
        if (l != lend) {
            bool found = false;
            for (m = l; m >= lend+1; --m) {
                float tst = e[m-2]*e[m-2];
                if (tst <= (eps2*fabsf(d[m-1]))*fabsf(d[m-2]) + safmin) { found = true; break; }
            }
            if (!found) m = lend;
        } else m = lend;
        if (m > lend) e[m-2] = 0.f;
        {
            float p = d[l-1];
            if (m == l) {
                d[l-1] = p;
                l = l - 1;
                if (l >= lend) goto L90;
                goto L140;
            }
            if (m == l-1) {
                float rt1, rt2, c2, s2;
                slaev2(d[l-2], e[l-2], d[l-1], rt1, rt2, c2, s2);
                rot_cols(z, l-2, c2, s2);
                d[l-2] = rt1; d[l-1] = rt2; e[l-2] = 0.f;
                l -= 2;
                if (l >= lend) goto L90;
                goto L140;
            }
            if (jtot == nmaxit) goto L140;
            jtot++;
            float g = (d[l-2] - p) / (2.f * e[l-2]);
            float r = slapy2(g, 1.f);
            g = d[m-1] - p + e[l-2] / (g + fsign(r, g));
            float s = 1.f, c = 1.f;
            p = 0.f;
            for (int i = m; i <= l-1; ++i) {
                float f = s * e[i-1];
                float b = c * e[i-1];
                slartg(g, f, c, s, r);
                if (i != m) e[i-2] = r;
                g = d[i-1] - p;
                r = (d[i] - g)*s + 2.f*c*b;
                p = s * r;
                d[i-1] = g + p;
                g = c*r - b;
                cw[i-m] = c; sw[i-m] = s;
            }
            for (int jj = 1; jj <= l-m; ++jj)
                rot_cols(z, m + jj - 2, cw[jj-1], sw[jj-1]);
            d[l-1] = d[l-1] - p;
            e[l-2] = g;
            goto L90;
        }
    }
L140:
    if (jtot < nmaxit) goto L10;
L160:
    for (int ii = 2; ii <= n; ++ii) {
        int i = ii - 1, k = i;
        float p = d[i-1];
        for (int j = ii; j <= n; ++j)
            if (d[j-1] < p) { k = j; p = d[j-1]; }
        if (k != i) {
            d[k-1] = d[i-1]; d[i-1] = p;
            for (int r0 = 0; r0 < 3; ++r0) {
                float t = z[r0][i-1]; z[r0][i-1] = z[r0][k-1]; z[r0][k-1] = t;
            }
        }
    }
}

// ---------------------------------------------------------------------------
// cov + eig kernel
// ---------------------------------------------------------------------------
__global__ __launch_bounds__(256) void cov_eig_kernel(const float* __restrict__ x,
                                                      float* __restrict__ eigbuf,
                                                      unsigned int* __restrict__ gmax)
{
    __shared__ float part[4][9];
    const int n = blockIdx.x;
    const float* xn = x + (size_t)n * 3 * LIN;
    float v[9] = {0,0,0,0,0,0,0,0,0};
    for (int l = threadIdx.x; l < LIN; l += 256) {
        float a = xn[l], b = xn[LIN + l], c = xn[2*LIN + l];
        v[0] += a; v[1] += b; v[2] += c;
        v[3] = fmaf(a,a,v[3]); v[4] = fmaf(a,b,v[4]); v[5] = fmaf(a,c,v[5]);
        v[6] = fmaf(b,b,v[6]); v[7] = fmaf(b,c,v[7]); v[8] = fmaf(c,c,v[8]);
    }
#pragma unroll
    for (int off = 32; off > 0; off >>= 1)
#pragma unroll
        for (int i = 0; i < 9; ++i) v[i] += __shfl_down(v[i], off, 64);
    const int wv = threadIdx.x >> 6, lane = threadIdx.x & 63;
    if (lane == 0)
        for (int i = 0; i < 9; ++i) part[wv][i] = v[i];
    __syncthreads();
    if (threadIdx.x == 0) {
        float t[9];
        for (int i = 0; i < 9; ++i)
            t[i] = part[0][i] + part[1][i] + part[2][i] + part[3][i];
        const float Lf = (float)LIN;
        float m0 = t[0]/Lf, m1 = t[1]/Lf, m2 = t[2]/Lf;
        float c00 = (t[3] - Lf*m0*m0) / (Lf - 1.f);
        float c01 = (t[4] - Lf*m0*m1) / (Lf - 1.f);
        float c02 = (t[5] - Lf*m0*m2) / (Lf - 1.f);
        float c11 = (t[6] - Lf*m1*m1) / (Lf - 1.f);
        float c12 = (t[7] - Lf*m1*m2) / (Lf - 1.f);
        float c22 = (t[8] - Lf*m2*m2) / (Lf - 1.f);

        float dd[3], ee[2], tau, v2;
        {
            float a21 = c01, a31 = c02, a22 = c11, a32 = c12, a33 = c22;
            float xnorm = fabsf(a31);
            if (xnorm == 0.f) {
                tau = 0.f; v2 = 0.f;
                dd[0] = c00; dd[1] = a22; dd[2] = a33;
                ee[0] = a21; ee[1] = a32;
            } else {
                float beta = -fsign(slapy2(a21, xnorm), a21);
                tau = (beta - a21) / beta;
                v2  = a31 / (a21 - beta);
                ee[0] = beta;
                float x1 = tau*(a22 + a32*v2);
                float x2 = tau*(a32 + a33*v2);
                float al = -0.5f*tau*(x1 + x2*v2);
                float w1 = x1 + al;
                float w2 = x2 + al*v2;
                a22 -= 2.f*w1;
                a32 -= (v2*w1 + w2);
                a33 -= 2.f*v2*w2;
                dd[0] = c00; dd[1] = a22; dd[2] = a33;
                ee[1] = a32;
            }
        }
        float zz[3][3];
        ssteqr3(dd, ee, zz);
        if (tau != 0.f) {
            for (int j = 0; j < 3; ++j) {
                float sum = zz[1][j] + v2*zz[2][j];
                zz[1][j] -= tau * sum;
                zz[2][j] -= tau * v2 * sum;
            }
        }

        float* eb = eigbuf + n * 21;
        eb[0] = c00; eb[1] = c01; eb[2] = c02;
        eb[3] = c01; eb[4] = c11; eb[5] = c12;
        eb[6] = c02; eb[7] = c12; eb[8] = c22;
        eb[9] = dd[0]; eb[10] = dd[1]; eb[11] = dd[2];
        for (int c = 0; c < 3; ++c)
            for (int k = 0; k < 3; ++k) eb[12 + c*3 + k] = zz[c][k];

        float vmax = fmaxf(dd[0], fmaxf(dd[1], dd[2]));
        float cmax = 0.f;
        for (int i = 0; i < 9; ++i) cmax = fmaxf(cmax, fabsf(eb[i]));
        atomicMax(&gmax[0], __float_as_uint(vmax));
        atomicMax(&gmax[1], __float_as_uint(cmax));
    }
}

// ---------------------------------------------------------------------------
// feats -> 1x1 conv (wc) + relu, writes hcat[:, 7500:7640]
// ---------------------------------------------------------------------------
__global__ __launch_bounds__(256) void feats_kernel(const float* __restrict__ eigbuf,
                                                    const unsigned int* __restrict__ gmax,
                                                    const float* __restrict__ wc,
                                                    const float* __restrict__ bc,
                                                    float* __restrict__ hcat)
{
    const int n = blockIdx.x;
    const int t = threadIdx.x;
    if (t >= 140) return;
    const int o = t / 7, j = t % 7;
    const float* eb = eigbuf + n * 21;
    const float vmax = __uint_as_float(gmax[0]);
    const float cmax = __uint_as_float(gmax[1]);
    float f0, f1, f2;
    if (j < 3)       { f0 = eb[0*3+j]/cmax; f1 = eb[1*3+j]/cmax; f2 = eb[2*3+j]/cmax; }
    else if (j == 3) { f0 = eb[9]/vmax;     f1 = eb[10]/vmax;    f2 = eb[11]/vmax; }
    else             { int k = j-4; f0 = eb[12+0*3+k]; f1 = eb[12+1*3+k]; f2 = eb[12+2*3+k]; }
    float r = bc[o] + wc[o*3+0]*f0 + wc[o*3+1]*f1 + wc[o*3+2]*f2;
    hcat[(size_t)n*HCATW + 7500 + o*7 + j] = fmaxf(r, 0.f);
}

// ---------------------------------------------------------------------------
// FC0+FC1 fused, 4 samples per block (512 threads), h staged in LDS.
// Wave owns a 4-wide o-tile: 16 accumulators => each h b128 feeds 16 FMAs.
// ---------------------------------------------------------------------------
__global__ __launch_bounds__(512) void fc01_kernel(const float* __restrict__ hcat,
                                                   const float* __restrict__ wl0,
                                                   const float* __restrict__ bl0,
                                                   const float* __restrict__ wl1,
                                                   const float* __restrict__ bl1,
                                                   float* __restrict__ out)
{
    __shared__ float hl[FCNS * HCATW];     // 122,240 B
    __shared__ float hbuf[FCNS * HID];     //   1,600 B
    const int tid = threadIdx.x;
    const int n0 = blockIdx.x * FCNS;
    for (int i = tid; i < FCNS * (HCATW/4); i += 512) {
        int s  = i / (HCATW/4);
        int k4 = i - s * (HCATW/4);
        ((float4*)hl)[s * (HCATW/4) + k4] =
            *(const float4*)(hcat + (size_t)(n0 + s) * HCATW + k4 * 4);
    }
    __syncthreads();
    const int wv = tid >> 6;
    const int lane = tid & 63;
    for (int ot = wv; ot < HID / 4; ot += 8) {      // 25 o-tiles of 4
        float acc[4][FCNS];
#pragma unroll
        for (int oo = 0; oo < 4; ++oo)
#pragma unroll
            for (int s = 0; s < FCNS; ++s) acc[oo][s] = 0.f;
        for (int k = lane * 4; k < HCATW; k += 256) {
            float4 hv[FCNS];
#pragma unroll
            for (int s = 0; s < FCNS; ++s)
                hv[s] = *(const float4*)(hl + s * HCATW + k);
#pragma unroll
            for (int oo = 0; oo < 4; ++oo) {
                const float4 w4 = *(const float4*)(wl0 + (size_t)(ot*4+oo) * HCATW + k);
#pragma unroll
                for (int s = 0; s < FCNS; ++s) {
                    acc[oo][s] = fmaf(hv[s].x, w4.x, acc[oo][s]);
                    acc[oo][s] = fmaf(hv[s].y, w4.y, acc[oo][s]);
                    acc[oo][s] = fmaf(hv[s].z, w4.z, acc[oo][s]);
                    acc[oo][s] = fmaf(hv[s].w, w4.w, acc[oo][s]);
                }
            }
        }
#pragma unroll
        for (int off = 32; off > 0; off >>= 1)
#pragma unroll
            for (int oo = 0; oo < 4; ++oo)
#pragma unroll
                for (int s = 0; s < FCNS; ++s)
                    acc[oo][s] += __shfl_down(acc[oo][s], off, 64);
        if (lane == 0) {
#pragma unroll
            for (int oo = 0; oo < 4; ++oo) {
                const float b = bl0[ot*4+oo];
#pragma unroll
                for (int s = 0; s < FCNS; ++s)
                    hbuf[s * HID + ot*4+oo] = fmaxf(acc[oo][s] + b, 0.f);
            }
        }
    }
    __syncthreads();
    if (tid < 2 * FCNS) {
        const int s = tid >> 1, r = tid & 1;
        const float* w = wl1 + r * HID;
        float acc = bl1[r];
        for (int k = 0; k < HID; ++k) acc = fmaf(hbuf[s * HID + k], w[k], acc);
        out[r * NBATCH + n0 + s] = acc;
    }
}

// ---------------------------------------------------------------------------
// launch
// ---------------------------------------------------------------------------
extern "C" void kernel_launch(void* const* d_in, const int* in_sizes, int n_in,
                              void* d_out, int out_size, void* d_ws, size_t ws_size,
                              hipStream_t stream)
{
    const float* x   = (const float*)d_in[0];
    const float* w0  = (const float*)d_in[1];
    const float* b0  = (const float*)d_in[2];
    const float* w1  = (const float*)d_in[3];
    const float* b1  = (const float*)d_in[4];
    const float* w2  = (const float*)d_in[5];
    const float* b2  = (const float*)d_in[6];
    const float* w3  = (const float*)d_in[7];
    const float* b3  = (const float*)d_in[8];
    const float* wc  = (const float*)d_in[9];
    const float* bc  = (const float*)d_in[10];
    const float* wl0 = (const float*)d_in[11];
    const float* bl0 = (const float*)d_in[12];
    const float* wl1 = (const float*)d_in[13];
    const float* bl1 = (const float*)d_in[14];
    float* out = (float*)d_out;

    // workspace layout (floats)
    const size_t HCAT_N = (size_t)NBATCH * HCATW;        // 7,823,360
    const size_t EIG_N  = (size_t)NBATCH * 21;
    const size_t need_bytes = (HCAT_N + EIG_N + 4 + WREPSZ) * 4 + 16;
    if (ws_size < need_bytes) return;

    float* ws     = (float*)d_ws;
    float* hcat   = ws;
    float* eigbuf = hcat + HCAT_N;
    unsigned int* gmax = (unsigned int*)(eigbuf + EIG_N);
    float* wrep   = (float*)(gmax + 4);

    hipMemsetAsync(gmax, 0, 2 * sizeof(unsigned int), stream);

    repack_kernel<<<16, 256, 0, stream>>>(w0, b0, w1, b1, w2, b2, w3, b3, wrep);
    conv_chain_eo<<<NBATCH * NCHK, 512, 0, stream>>>(x, wrep, hcat);
    cov_eig_kernel<<<NBATCH, 256, 0, stream>>>(x, eigbuf, gmax);
    feats_kernel<<<NBATCH, 256, 0, stream>>>(eigbuf, gmax, wc, bc, hcat);
    fc01_kernel<<<NBATCH / FCNS, 512, 0, stream>>>(hcat, wl0, bl0, wl1, bl1, out);
}

// Round 5
// 615.409 us; speedup vs baseline: 1.3149x; 1.0594x over previous
//
#include <hip/hip_runtime.h>
#include <hip/hip_bf16.h>
#include <hip/hip_fp16.h>
#include <math.h>

// ---------------------------------------------------------------------------
// Problem constants
// ---------------------------------------------------------------------------
#define NBATCH 1024
#define LIN    6000
#define HCATW  7640       // 20*375 + 20*7
#define HID    100

// conv-chain chunking: T=54 final(375-res) positions per block, 7 chunks.
//   JOUT chain = 8T+14, 4T+6, 2T+2, T = 446, 222, 110, 54
// R11: dot2 s1/s2 + s3 8-wave split -> 484us, VALUBusy 90.5%, occ 66.7%.
// R12: s2-out fp16 (B 7040->4460 dw => LDS 32,048 B => 4 blocks/CU) and
//   s3 goes dot2 on the interleaved-fp16 read path (36->28 instrs/ic).
//   fc01: FCNS=8, hl fp16, wl0 repacked fp16 + dot2 (wl0 HBM 783->196 MB).
#define TCH   54
#define NCHK  7

#define ASZ 3552            // max(x-buf 2682, s1-out fp16 32*111dw=3552, s3 part 2560)
#define BSZ 4460            // max(s0-out fp16 20*223dw=4460, s2-out fp16 64*55dw=3520)

// repacked-weight offsets (dwords) inside wrep
// s0: fp32, per (ocg,ic) 16 floats (5o x 3 + pad)
// s1/s2/s3: packed, per (ocg,ic) 16 dwords: [0..7]=half2(w0,w1), [8..15]=f32 w2
#define W0OFF 0             // 4*3*16   = 192
#define W1OFF 192           // 4*20*16  = 1280
#define W2OFF 1472          // 8*32*16  = 4096
#define W3OFF 5568          // 4*64*16  = 4096
#define B0OFF 9664
#define B1OFF 9684
#define B2OFF 9716
#define B3OFF 9780
#define WREPSZ 9800

#define WL0HSZ (HID * (HCATW/2))   // 382,000 dwords of packed fp16 wl0

// fc01: samples per block
#define FCNS 8

typedef _Float16 v2h __attribute__((ext_vector_type(2)));

__device__ __forceinline__ float fdot2_f16(unsigned int a, unsigned int b, float c) {
#if __has_builtin(__builtin_amdgcn_fdot2)
    v2h ah, bh;
    __builtin_memcpy(&ah, &a, 4);
    __builtin_memcpy(&bh, &b, 4);
    return __builtin_amdgcn_fdot2(ah, bh, c, false);
#else
    float d;
    asm("v_dot2_f32_f16 %0, %1, %2, %3" : "=v"(d) : "v"(a), "v"(b), "v"(c));
    return d;
#endif
}

// ---------------------------------------------------------------------------
// Weight repack
// ---------------------------------------------------------------------------
__device__ __forceinline__ void pack_one(int idx, int OC, int IC, int OCG,
                                         int OPG, int WSTR,
                                         const float* __restrict__ w,
                                         float* __restrict__ dst)
{
    if (idx >= OCG * IC * WSTR) return;
    int ocg = idx / (IC * WSTR);
    int r   = idx - ocg * (IC * WSTR);
    int ic  = r / WSTR;
    int q   = r - ic * WSTR;
    int o   = q / 3, k = q - o * 3;
    int oc  = ocg * OPG + o;
    dst[idx] = (o < OPG && oc < OC) ? w[(oc * IC + ic) * 3 + k] : 0.f;
}

// packed-fp16 pack: per (ocg,ic) 16 dwords: [0..7]=half2(w0,w1), [8..15]=f32 w2
__device__ __forceinline__ void pack_pk(int idx, int OC, int IC, int OCG, int OPG,
                                        const float* __restrict__ w,
                                        unsigned int* __restrict__ dst)
{
    if (idx >= OCG * IC * 16) return;
    int ocg = idx / (IC * 16);
    int r   = idx - ocg * (IC * 16);
    int ic  = r >> 4, q = r & 15;
    int o   = q & 7;
    int oc  = ocg * OPG + o;
    bool valid = (o < OPG) && (oc < OC);
    unsigned int v = 0;
    if (valid) {
        const float* ws = w + (oc * IC + ic) * 3;
        if (q < 8) {
            unsigned int lo = __half_as_ushort(__float2half(ws[0]));
            unsigned int hi = __half_as_ushort(__float2half(ws[1]));
            v = lo | (hi << 16);
        } else {
            v = __float_as_uint(ws[2]);
        }
    }
    dst[idx] = v;
}

__global__ __launch_bounds__(256) void repack_kernel(
    const float* __restrict__ w0, const float* __restrict__ b0,
    const float* __restrict__ w1, const float* __restrict__ b1,
    const float* __restrict__ w2, const float* __restrict__ b2,
    const float* __restrict__ w3, const float* __restrict__ b3,
    float* __restrict__ wrep)
{
    int idx = blockIdx.x * 256 + threadIdx.x;
    unsigned int* wu = (unsigned int*)wrep;
    pack_one(idx, 20,  3, 4, 5, 16, w0, wrep + W0OFF);
    pack_pk (idx, 32, 20, 4, 8, w1, wu + W1OFF);
    pack_pk (idx, 64, 32, 8, 8, w2, wu + W2OFF);
    pack_pk (idx, 20, 64, 4, 5, w3, wu + W3OFF);
    if (idx < 20)            wrep[B0OFF + idx] = b0[idx];
    else if (idx < 52)  { int i = idx - 20;  wrep[B1OFF + i] = b1[i]; }
    else if (idx < 116) { int i = idx - 52;  wrep[B2OFF + i] = b2[i]; }
    else if (idx < 136) { int i = idx - 116; wrep[B3OFF + i] = b3[i]; }
}

// wl0 (100 x 7640 fp32) -> packed fp16 dwords
__global__ __launch_bounds__(256) void wl0h_kernel(const float* __restrict__ wl0,
                                                   unsigned int* __restrict__ wl0h)
{
    int idx = blockIdx.x * 256 + threadIdx.x;
    if (idx >= WL0HSZ) return;
    float a = wl0[idx * 2], b = wl0[idx * 2 + 1];
    unsigned int lo = __half_as_ushort(__float2half(a));
    unsigned int hi = __half_as_ushort(__float2half(b));
    wl0h[idx] = lo | (hi << 16);
}

// ---------------------------------------------------------------------------
// One conv(K=3,SAME)+ReLU+pool2 stage on LDS buffers.
// 8 waves per block (512 threads), wave-strided tasks of JBLK*64 outputs.
// fp32 buffers: even/odd-split planes (2*PIN floats per channel).
// fp16 buffers: interleaved shorts, plane stride PIN dwords; dword p =
//   (pooled[2p], pooled[2p+1]); one ds_read2_b32 at dword jc yields
//   (e0,o0,e1,o1).
// PKW: weights packed per (ocg,ic) as 16 dwords; 2 dot2 + 2 fma per o.
// ---------------------------------------------------------------------------
template<int IC, int OC, int OCG, int OPG, int WSTR, int JOUT, int LG, int JBLK,
         bool IN16, bool OUT16, bool PKW, bool FINAL>
__device__ __forceinline__ void stage_eo(const float* __restrict__ in,
                                         float* __restrict__ out,
                                         float* __restrict__ outg,
                                         const float* __restrict__ wrep,
                                         const float* __restrict__ brep,
                                         int pbase, int o3, int wv, int lane,
                                         int zero)
{
    constexpr int PIN  = JOUT + 1;
    constexpr int POUT = JOUT / 2;
    constexpr int NJT  = (JOUT + 64 * JBLK - 1) / (64 * JBLK);
    for (int task = wv; task < OCG * NJT; task += 8) {
        const int ocg = task / NJT;                 // wave-uniform (wv uniform)
        const int jt  = task - ocg * NJT;
        const int j0  = jt * (64 * JBLK) + lane;
        const float* bp = brep + ocg * OPG;
        float ae[JBLK][OPG], ao[JBLK][OPG];
#pragma unroll
        for (int t = 0; t < JBLK; ++t)
#pragma unroll
            for (int o = 0; o < OPG; ++o) { ae[t][o] = bp[o]; ao[t][o] = ae[t][o]; }
        const float* wbase = wrep + ocg * (IC * WSTR) + zero;  // stays VMEM
#pragma unroll 2
        for (int ic = 0; ic < IC; ++ic) {
            const float* wp = wbase + ic * WSTR;
            float wr[WSTR];
#pragma unroll
            for (int q = 0; q < WSTR / 4; ++q)
                *(float4*)&wr[q * 4] = *(const float4*)(wp + q * 4);
#pragma unroll
            for (int t = 0; t < JBLK; ++t) {
                const int jj = j0 + t * 64;
                const int jc = (jj < JOUT) ? jj : (JOUT - 1);
                if constexpr (PKW) {
                    // IN16 guaranteed: dword p = (pooled[2p], pooled[2p+1])
                    const float* ipw = in + ic * PIN;
                    uint2 pw;
                    __builtin_memcpy(&pw, ipw + jc, 8);   // ds_read2_b32
                    const unsigned int crossu = (pw.x >> 16) | (pw.y << 16); // (o0,e1)
                    v2h h1; __builtin_memcpy(&h1, &pw.y, 4);
                    const float e1 = (float)h1.x, o1 = (float)h1.y;
#pragma unroll
                    for (int o = 0; o < OPG; ++o) {
                        const unsigned int wpk = __float_as_uint(wr[o]);
                        const float w2 = wr[8 + o];
                        ae[t][o] = fdot2_f16(pw.x,  wpk, ae[t][o]);   // e0*w0+o0*w1
                        ao[t][o] = fdot2_f16(crossu, wpk, ao[t][o]);  // o0*w0+e1*w1
                        ae[t][o] = fmaf(e1, w2, ae[t][o]);
                        ao[t][o] = fmaf(o1, w2, ao[t][o]);
                    }
                } else {
                    float e0, e1, o0, o1;
                    if constexpr (IN16) {
                        const float* ipw = in + ic * PIN;
                        uint2 pw;
                        __builtin_memcpy(&pw, ipw + jc, 8);   // ds_read2_b32
                        __half2 h0 = *reinterpret_cast<const __half2*>(&pw.x);
                        __half2 h1 = *reinterpret_cast<const __half2*>(&pw.y);
                        e0 = __low2float(h0); o0 = __high2float(h0);
                        e1 = __low2float(h1); o1 = __high2float(h1);
                    } else {
                        const float* ip = in + ic * (2 * PIN);
                        float2 ev, ov;
                        __builtin_memcpy(&ev, ip + jc, 8);        // ds_read2_b32
                        __builtin_memcpy(&ov, ip + PIN + jc, 8);  // ds_read2_b32
                        e0 = ev.x; e1 = ev.y;
                        o0 = ov.x; o1 = ov.y;
                    }
#pragma unroll
                    for (int o = 0; o < OPG; ++o) {
                        const float w0 = wr[o*3+0], w1 = wr[o*3+1], w2 = wr[o*3+2];
                        ae[t][o] = fmaf(e0, w0, fmaf(o0, w1, fmaf(e1, w2, ae[t][o])));
                        ao[t][o] = fmaf(o0, w0, fmaf(e1, w1, fmaf(o1, w2, ao[t][o])));
                    }
                }
            }
        }
#pragma unroll
        for (int t = 0; t < JBLK; ++t) {
            const int jj = j0 + t * 64;
            if constexpr (FINAL) {
                const int gj = o3 + jj;
                if (gj < 375 && jj < JOUT) {
#pragma unroll
                    for (int o = 0; o < OPG; ++o)
                        outg[(ocg*OPG+o) * 375 + gj] =
                            fmaxf(fmaxf(ae[t][o], ao[t][o]), 0.f);
                }
            } else {
                const int g = pbase + jj;
                const bool val = (jj < JOUT) && (g >= 0) && (g < LG);
                if (jj < JOUT) {
                    if constexpr (OUT16) {
                        __half* dh = (__half*)out;
#pragma unroll
                        for (int o = 0; o < OPG; ++o) {
                            float v = val ? fmaxf(fmaxf(ae[t][o], ao[t][o]), 0.f)
                                          : 0.f;
                            dh[(ocg*OPG+o) * JOUT + jj] = __float2half(v);
                        }
                    } else {
                        float* dst = out + ((jj & 1) ? POUT : 0) + (jj >> 1);
#pragma unroll
                        for (int o = 0; o < OPG; ++o)
                            dst[(ocg*OPG+o) * JOUT] =
                                val ? fmaxf(fmaxf(ae[t][o], ao[t][o]), 0.f) : 0.f;
                    }
                }
            }
        }
    }
}

// ---------------------------------------------------------------------------
// Final stage (s3) split across all 8 waves: wave = (ocg 0..3) x (ic-half).
// fp16 interleaved input (plane stride 55 dwords), packed-fp16 weights.
// Upper-half waves publish fp32 partials through LDS `part` (buffer A),
// one barrier, lower-half waves combine + relu-pool + store.
// ---------------------------------------------------------------------------
__device__ __forceinline__ void stage3_split(const float* __restrict__ in,
                                             float* __restrict__ part,
                                             float* __restrict__ outg,
                                             const float* __restrict__ wrep,
                                             const float* __restrict__ brep,
                                             int o3, int wv, int lane, int zero)
{
    constexpr int JOUT = 54, PIND = 55, OPG = 5, WSTR = 16;
    const int ocg = wv & 3, ih = wv >> 2;
    const int j  = lane;
    const int jc = (j < JOUT) ? j : (JOUT - 1);
    const float* bp = brep + ocg * OPG;
    float ae[OPG], ao[OPG];
#pragma unroll
    for (int o = 0; o < OPG; ++o) {
        float b = ih ? 0.f : bp[o];
        ae[o] = b; ao[o] = b;
    }
    const float* wbase = wrep + (ocg * 64 + ih * 32) * WSTR + zero;
#pragma unroll 2
    for (int ic = 0; ic < 32; ++ic) {
        const float* ipw = in + (ih * 32 + ic) * PIND;
        uint2 pw;
        __builtin_memcpy(&pw, ipw + jc, 8);           // ds_read2_b32
        const unsigned int crossu = (pw.x >> 16) | (pw.y << 16);
        v2h h1; __builtin_memcpy(&h1, &pw.y, 4);
        const float e1 = (float)h1.x, o1 = (float)h1.y;
        const float* wp = wbase + ic * WSTR;
        float wr[WSTR];
#pragma unroll
        for (int q = 0; q < WSTR / 4; ++q)
            *(float4*)&wr[q * 4] = *(const float4*)(wp + q * 4);
#pragma unroll
        for (int o = 0; o < OPG; ++o) {
            const unsigned int wpk = __float_as_uint(wr[o]);
            const float w2 = wr[8 + o];
            ae[o] = fdot2_f16(pw.x,   wpk, ae[o]);
            ao[o] = fdot2_f16(crossu, wpk, ao[o]);
            ae[o] = fmaf(e1, w2, ae[o]);
            ao[o] = fmaf(o1, w2, ao[o]);
        }
    }
    if (ih == 1) {
#pragma unroll
        for (int o = 0; o < OPG; ++o) {
            float2 p = make_float2(ae[o], ao[o]);
            __builtin_memcpy(part + (ocg * OPG + o) * 128 + lane * 2, &p, 8);
        }
    }
    __syncthreads();
    if (ih == 0) {
#pragma unroll
        for (int o = 0; o < OPG; ++o) {
            float2 p;
            __builtin_memcpy(&p, part + (ocg * OPG + o) * 128 + lane * 2, 8);
            ae[o] += p.x; ao[o] += p.y;
        }
        const int gj = o3 + j;
        if (gj < 375 && j < JOUT) {
#pragma unroll
            for (int o = 0; o < OPG; ++o)
                outg[(ocg * OPG + o) * 375 + gj] =
                    fmaxf(fmaxf(ae[o], ao[o]), 0.f);
        }
    }
}

// LDS (3552+4460)*4 = 32,048 B -> 4 blocks/CU (wave-capped); 8 waves/EU.
__global__ __launch_bounds__(512, 8) void conv_chain_eo(
    const float* __restrict__ x,
    const float* __restrict__ wrep,
    float* __restrict__ hcat)
{
    __shared__ float A[ASZ];
    __shared__ float B[BSZ];

    const int tid  = threadIdx.x;
    const int wv   = __builtin_amdgcn_readfirstlane(tid >> 6);
    const int lane = tid & 63;
    // opaque zero: compiler can't prove uniformity -> weight loads stay VMEM
    const int zero = __builtin_amdgcn_ds_bpermute(0, 0);
    const int n     = blockIdx.x / NCHK;
    const int chunk = blockIdx.x % NCHK;
    const int o3 = chunk * TCH;
    const int p2 = 2*o3 - 1, p1 = 4*o3 - 3, p0 = 8*o3 - 7, xs = 16*o3 - 15;

    // stage x -> A in even/odd split (3 ch, 447 pairs, plane stride 894)
    const float* xn = x + (size_t)n * 3 * LIN;
    for (int idx = tid; idx < 3 * 894; idx += 512) {
        int c = idx / 894, i = idx - c * 894;
        int g = xs + i;
        float v = (g >= 0 && g < LIN) ? xn[c * LIN + g] : 0.f;
        A[c * 894 + ((i & 1) ? 447 : 0) + (i >> 1)] = v;
    }
    __syncthreads();
    // s0: fp32 in (x), fp16 out, fp32 weights
    stage_eo< 3, 20, 4, 5, 16, 446, 3000, 2, false, true,  false, false>(
        A, B, nullptr, wrep + W0OFF, wrep + B0OFF, p0, o3, wv, lane, zero);
    __syncthreads();
    // s1: fp16 in, fp16 out, packed weights + dot2
    stage_eo<20, 32, 4, 8, 16, 222, 1500, 2, true,  true,  true,  false>(
        B, A, nullptr, wrep + W1OFF, wrep + B1OFF, p1, o3, wv, lane, zero);
    __syncthreads();
    // s2: fp16 in, fp16 out, packed weights + dot2
    stage_eo<32, 64, 8, 8, 16, 110,  750, 2, true,  true,  true,  false>(
        A, B, nullptr, wrep + W2OFF, wrep + B2OFF, p2, o3, wv, lane, zero);
    __syncthreads();
    // s3: fp16 in, packed weights + dot2, split 2x32 ic across 8 waves
    stage3_split(B, A, hcat + (size_t)n * HCATW,
                 wrep + W3OFF, wrep + B3OFF, o3, wv, lane, zero);
}

// ---------------------------------------------------------------------------
// LAPACK ssyevd (n=3, uplo='L') replica: ssytrd -> ssteqr('I') -> apply Q.
// ---------------------------------------------------------------------------
__device__ __forceinline__ float fsign(float a, float b) {
    return (b >= 0.0f) ? fabsf(a) : -fabsf(a);
}
__device__ __forceinline__ float slapy2(float xx, float yy) {
    float xa = fabsf(xx), ya = fabsf(yy);
    float w = fmaxf(xa, ya), z = fminf(xa, ya);
    if (z == 0.f) return w;
    float t = z / w;
    return w * sqrtf(1.f + t*t);
}
// LAPACK 3.10+ slartg: c >= 0 always, r = sign(f)*hypot
__device__ __forceinline__ void slartg(float f, float g, float& c, float& s, float& r) {
    if (g == 0.f)      { c = 1.f; s = 0.f; r = f; }
    else if (f == 0.f) { c = 0.f; s = (g >= 0.f ? 1.f : -1.f); r = fabsf(g); }
    else {
        float d = sqrtf(f*f + g*g);
        c = fabsf(f) / d;
        r = fsign(d, f);
        s = g / r;
    }
}
__device__ void slaev2(float a, float b, float cc,
                       float& rt1, float& rt2, float& cs1, float& sn1) {
    float sm = a + cc, df = a - cc;
    float adf = fabsf(df);
    float tb = b + b, ab = fabsf(tb);
    float acmx, acmn;
    if (fabsf(a) > fabsf(cc)) { acmx = a; acmn = cc; } else { acmx = cc; acmn = a; }
    float rt;
    if (adf > ab)      { float t = ab/adf; rt = adf*sqrtf(1.f + t*t); }
    else if (adf < ab) { float t = adf/ab; rt = ab*sqrtf(1.f + t*t); }
    else rt = ab * sqrtf(2.f);
    int sgn1;
    if (sm < 0.f)      { rt1 = 0.5f*(sm - rt); sgn1 = -1; rt2 = (acmx/rt1)*acmn - (b/rt1)*b; }
    else if (sm > 0.f) { rt1 = 0.5f*(sm + rt); sgn1 =  1; rt2 = (acmx/rt1)*acmn - (b/rt1)*b; }
    else               { rt1 = 0.5f*rt; rt2 = -0.5f*rt; sgn1 = 1; }
    float cs; int sgn2;
    if (df >= 0.f) { cs = df + rt; sgn2 = 1; } else { cs = df - rt; sgn2 = -1; }
    float acs = fabsf(cs);
    if (acs > ab) {
        float ct = -tb / cs;
        sn1 = 1.f / sqrtf(1.f + ct*ct);
        cs1 = ct * sn1;
    } else {
        if (ab == 0.f) { cs1 = 1.f; sn1 = 0.f; }
        else {
            float tn = -cs / tb;
            cs1 = 1.f / sqrtf(1.f + tn*tn);
            sn1 = tn * cs1;
        }
    }
    if (sgn1 == sgn2) { float tn = cs1; cs1 = -sn1; sn1 = tn; }
}
__device__ __forceinline__ void rot_cols(float z[3][3], int jc, float c, float s) {
    for (int i = 0; i < 3; ++i) {
        float t = z[i][jc+1];
        z[i][jc+1] = c*t - s*z[i][jc];
        z[i][jc]   = s*t + c*z[i][jc];
    }
}

__device__ void ssteqr3(float d[3], float e[2], float z[3][3]) {
    const float eps    = 5.9604645e-8f;
    const float eps2   = eps * eps;
    const float safmin = 1.17549435e-38f;
    const int n = 3;
    for (int i = 0; i < 3; ++i)
        for (int j = 0; j < 3; ++j) z[i][j] = (i == j) ? 1.f : 0.f;
    const int nmaxit = n * 30;
    int jtot = 0;
    float cw[2], sw[2];
    int l1 = 1, l, m, lend, lsv, lendsv;

L10:
    if (l1 > n) goto L160;
    if (l1 > 1) e[l1-2] = 0.f;
    if (l1 <= n-1) {
        for (m = l1; m <= n-1; ++m) {
            float tst = fabsf(e[m-1]);
            if (tst == 0.f) goto L30;
            if (tst <= (sqrtf(fabsf(d[m-1])) * sqrtf(fabsf(d[m]))) * eps) {
                e[m-1] = 0.f;
                goto L30;
            }
        }
    }
    m = n;
L30:
    l = l1; lsv = l; lend = m; lendsv = lend; l1 = m + 1;
    if (lend == l) goto L10;
    if (fabsf(d[lend-1]) < fabsf(d[l-1])) { lend = lsv; l = lendsv; }
    if (lend > l) {
L40:
        if (l != lend) {
            bool found = false;
            for (m = l; m <= lend-1; ++m) {
                float tst = e[m-1]*e[m-1];
                if (tst <= (eps2*fabsf(d[m-1]))*fabsf(d[m]) + safmin) { found = true; break; }
            }
            if (!found) m = lend;
        } else m = lend;
        if (m < lend) e[m-1] = 0.f;
        {
            float p = d[l-1];
            if (m == l) {
                d[l-1] = p;
                l = l + 1;
                if (l <= lend) goto L40;
                goto L140;
            }
            if (m == l+1) {
                float rt1, rt2, c2, s2;
                slaev2(d[l-1], e[l-1], d[l], rt1, rt2, c2, s2);
                rot_cols(z, l-1, c2, s2);
                d[l-1] = rt1; d[l] = rt2; e[l-1] = 0.f;
                l += 2;
                if (l <= lend) goto L40;
                goto L140;
            }
            if (jtot == nmaxit) goto L140;
            jtot++;
            float g = (d[l] - p) / (2.f * e[l-1]);
            float r = slapy2(g, 1.f);
            g = d[m-1] - p + e[l-1] / (g + fsign(r, g));
            float s = 1.f, c = 1.f;
            p = 0.f;
            for (int i = m-1; i >= l; --i) {
                float f = s * e[i-1];
                float b = c * e[i-1];
                slartg(g, f, c, s, r);
                if (i != m-1) e[i] = r;
                g = d[i] - p;
                r = (d[i-1] - g)*s + 2.f*c*b;
                p = s * r;
                d[i] = g + p;
                g = c*r - b;
                cw[i-l] = c; sw[i-l] = -s;
            }
            for (int jj = m-l; jj >= 1; --jj)
                rot_cols(z, l + jj - 2, cw[jj-1], sw[jj-1]);
            d[l-1] = d[l-1] - p;
            e[l-1] = g;
            goto L40;
        }
    } else {
L90:
        if (l != lend) {
            bool found = false;
            for (m = l; m >= lend+1; --m) {
                float tst = e[m-2]*e[m-2];
                if (tst <= (eps2*fabsf(d[m-1]))*fabsf(d[m-2]) + safmin) { found = true; break; }
            }
            if (!found) m = lend;
        } else m = lend;
        if (m > lend) e[m-2] = 0.f;
        {
            float p = d[l-1];
            if (m == l) {
                d[l-1] = p;
                l = l - 1;
                if (l >= lend) goto L90;
                goto L140;
            }
            if (m == l-1) {
                float rt1, rt2, c2, s2;
                slaev2(d[l-2], e[l-2], d[l-1], rt1, rt2, c2, s2);
                rot_cols(z, l-2, c2, s2);
                d[l-2] = rt1; d[l-1] = rt2; e[l-2] = 0.f;
                l -= 2;
                if (l >= lend) goto L90;
                goto L140;
            }
            if (jtot == nmaxit) goto L140;
            jtot++;
            float g = (d[l-2] - p) / (2.f * e[l-2]);
            float r = slapy2(g, 1.f);
            g = d[m-1] - p + e[l-2] / (g + fsign(r, g));
            float s = 1.f, c = 1.f;
            p = 0.f;
            for (int i = m; i <= l-1; ++i) {
                float f = s * e[i-1];
                float b = c * e[i-1];
                slartg(g, f, c, s, r);
                if (i != m) e[i-2] = r;
                g = d[i-1] - p;
                r = (d[i] - g)*s + 2.f*c*b;
                p = s * r;
                d[i-1] = g + p;
                g = c*r - b;
                cw[i-m] = c; sw[i-m] = s;
            }
            for (int jj = 1; jj <= l-m; ++jj)
                rot_cols(z, m + jj - 2, cw[jj-1], sw[jj-1]);
            d[l-1] = d[l-1] - p;
            e[l-2] = g;
            goto L90;
        }
    }
L140:
    if (jtot < nmaxit) goto L10;
L160:
    for (int ii = 2; ii <= n; ++ii) {
        int i = ii - 1, k = i;
        float p = d[i-1];
        for (int j = ii; j <= n; ++j)
            if (d[j-1] < p) { k = j; p = d[j-1]; }
        if (k != i) {
            d[k-1] = d[i-1]; d[i-1] = p;
            for (int r0 = 0; r0 < 3; ++r0) {
                float t = z[r0][i-1]; z[r0][i-1] = z[r0][k-1]; z[r0][k-1] = t;
            }
        }
    }
}

// ---------------------------------------------------------------------------
// cov + eig kernel
// ---------------------------------------------------------------------------
__global__ __launch_bounds__(256) void cov_eig_kernel(const float* __restrict__ x,
                                                      float* __restrict__ eigbuf,
                                                      unsigned int* __restrict__ gmax)
{
    __shared__ float part[4][9];
    const int n = blockIdx.x;
    const float* xn = x + (size_t)n * 3 * LIN;
    float v[9] = {0,0,0,0,0,0,0,0,0};
    for (int l = threadIdx.x; l < LIN; l += 256) {
        float a = xn[l], b = xn[LIN + l], c = xn[2*LIN + l];
        v[0] += a; v[1] += b; v[2] += c;
        v[3] = fmaf(a,a,v[3]); v[4] = fmaf(a,b,v[4]); v[5] = fmaf(a,c,v[5]);
        v[6] = fmaf(b,b,v[6]); v[7] = fmaf(b,c,v[7]); v[8] = fmaf(c,c,v[8]);
    }
#pragma unroll
    for (int off = 32; off > 0; off >>= 1)
#pragma unroll
        for (int i = 0; i < 9; ++i) v[i] += __shfl_down(v[i], off, 64);
    const int wv = threadIdx.x >> 6, lane = threadIdx.x & 63;
    if (lane == 0)
        for (int i = 0; i < 9; ++i) part[wv][i] = v[i];
    __syncthreads();
    if (threadIdx.x == 0) {
        float t[9];
        for (int i = 0; i < 9; ++i)
            t[i] = part[0][i] + part[1][i] + part[2][i] + part[3][i];
        const float Lf = (float)LIN;
        float m0 = t[0]/Lf, m1 = t[1]/Lf, m2 = t[2]/Lf;
        float c00 = (t[3] - Lf*m0*m0) / (Lf - 1.f);
        float c01 = (t[4] - Lf*m0*m1) / (Lf - 1.f);
        float c02 = (t[5] - Lf*m0*m2) / (Lf - 1.f);
        float c11 = (t[6] - Lf*m1*m1) / (Lf - 1.f);
        float c12 = (t[7] - Lf*m1*m2) / (Lf - 1.f);
        float c22 = (t[8] - Lf*m2*m2) / (Lf - 1.f);

        float dd[3], ee[2], tau, v2;
        {
            float a21 = c01, a31 = c02, a22 = c11, a32 = c12, a33 = c22;
            float xnorm = fabsf(a31);
            if (xnorm == 0.f) {
                tau = 0.f; v2 = 0.f;
                dd[0] = c00; dd[1] = a22; dd[2] = a33;
                ee[0] = a21; ee[1] = a32;
            } else {
                float beta = -fsign(slapy2(a21, xnorm), a21);
                tau = (beta - a21) / beta;
                v2  = a31 / (a21 - beta);
                ee[0] = beta;
                float x1 = tau*(a22 + a32*v2);
                float x2 = tau*(a32 + a33*v2);
                float al = -0.5f*tau*(x1 + x2*v2);
                float w1 = x1 + al;
                float w2 = x2 + al*v2;
                a22 -= 2.f*w1;
                a32 -= (v2*w1 + w2);
                a33 -= 2.f*v2*w2;
                dd[0] = c00; dd[1] = a22; dd[2] = a33;
                ee[1] = a32;
            }
        }
        float zz[3][3];
        ssteqr3(dd, ee, zz);
        if (tau != 0.f) {
            for (int j = 0; j < 3; ++j) {
                float sum = zz[1][j] + v2*zz[2][j];
                zz[1][j] -= tau * sum;
                zz[2][j] -= tau * v2 * sum;
            }
        }

        float* eb = eigbuf + n * 21;
        eb[0] = c00; eb[1] = c01; eb[2] = c02;
        eb[3] = c01; eb[4] = c11; eb[5] = c12;
        eb[6] = c02; eb[7] = c12; eb[8] = c22;
        eb[9] = dd[0]; eb[10] = dd[1]; eb[11] = dd[2];
        for (int c = 0; c < 3; ++c)
            for (int k = 0; k < 3; ++k) eb[12 + c*3 + k] = zz[c][k];

        float vmax = fmaxf(dd[0], fmaxf(dd[1], dd[2]));
        float cmax = 0.f;
        for (int i = 0; i < 9; ++i) cmax = fmaxf(cmax, fabsf(eb[i]));
        atomicMax(&gmax[0], __float_as_uint(vmax));
        atomicMax(&gmax[1], __float_as_uint(cmax));
    }
}

// ---------------------------------------------------------------------------
// feats -> 1x1 conv (wc) + relu, writes hcat[:, 7500:7640]
// ---------------------------------------------------------------------------
__global__ __launch_bounds__(256) void feats_kernel(const float* __restrict__ eigbuf,
                                                    const unsigned int* __restrict__ gmax,
                                                    const float* __restrict__ wc,
                                                    const float* __restrict__ bc,
                                                    float* __restrict__ hcat)
{
    const int n = blockIdx.x;
    const int t = threadIdx.x;
    if (t >= 140) return;
    const int o = t / 7, j = t % 7;
    const float* eb = eigbuf + n * 21;
    const float vmax = __uint_as_float(gmax[0]);
    const float cmax = __uint_as_float(gmax[1]);
    float f0, f1, f2;
    if (j < 3)       { f0 = eb[0*3+j]/cmax; f1 = eb[1*3+j]/cmax; f2 = eb[2*3+j]/cmax; }
    else if (j == 3) { f0 = eb[9]/vmax;     f1 = eb[10]/vmax;    f2 = eb[11]/vmax; }
    else             { int k = j-4; f0 = eb[12+0*3+k]; f1 = eb[12+1*3+k]; f2 = eb[12+2*3+k]; }
    float r = bc[o] + wc[o*3+0]*f0 + wc[o*3+1]*f1 + wc[o*3+2]*f2;
    hcat[(size_t)n*HCATW + 7500 + o*7 + j] = fmaxf(r, 0.f);
}

// ---------------------------------------------------------------------------
// FC0+FC1 fused, 8 samples per block (512 threads), h staged in LDS as fp16,
// wl0 pre-packed fp16 -> v_dot2_f32_f16 with fp32 accumulate.
// wl0 HBM traffic: 128 blocks x 1.53 MB = 196 MB (was 783 MB).
// ---------------------------------------------------------------------------
__global__ __launch_bounds__(512) void fc01_kernel(const float* __restrict__ hcat,
                                                   const unsigned int* __restrict__ wl0h,
                                                   const float* __restrict__ bl0,
                                                   const float* __restrict__ wl1,
                                                   const float* __restrict__ bl1,
                                                   float* __restrict__ out)
{
    __shared__ __half hl[FCNS * HCATW];    // 122,240 B
    __shared__ float hbuf[FCNS * HID];     //   3,200 B
    const int tid = threadIdx.x;
    const int n0 = blockIdx.x * FCNS;
    // stage hcat fp32 -> fp16 LDS
    for (int i = tid; i < FCNS * (HCATW/4); i += 512) {
        int s  = i / (HCATW/4);
        int k4 = i - s * (HCATW/4);
        float4 v = *(const float4*)(hcat + (size_t)(n0 + s) * HCATW + k4 * 4);
        __half2 h01 = __floats2half2_rn(v.x, v.y);
        __half2 h23 = __floats2half2_rn(v.z, v.w);
        *(__half2*)(hl + s * HCATW + k4 * 4)     = h01;
        *(__half2*)(hl + s * HCATW + k4 * 4 + 2) = h23;
    }
    __syncthreads();
    const int wv = tid >> 6;
    const int lane = tid & 63;
    for (int ot = wv; ot < HID / 4; ot += 8) {      // 25 o-tiles of 4
        float acc[4][FCNS];
#pragma unroll
        for (int oo = 0; oo < 4; ++oo)
#pragma unroll
            for (int s = 0; s < FCNS; ++s) acc[oo][s] = 0.f;
        for (int k = lane * 8; k < HCATW; k += 512) {   // 8 halves per lane
            uint4 hv[FCNS];
#pragma unroll
            for (int s = 0; s < FCNS; ++s)
                hv[s] = *(const uint4*)(hl + s * HCATW + k);
#pragma unroll
            for (int oo = 0; oo < 4; ++oo) {
                const uint4 wp = *(const uint4*)(wl0h + (ot*4+oo) * (HCATW/2) + (k >> 1));
#pragma unroll
                for (int s = 0; s < FCNS; ++s) {
                    float a = acc[oo][s];
                    a = fdot2_f16(hv[s].x, wp.x, a);
                    a = fdot2_f16(hv[s].y, wp.y, a);
                    a = fdot2_f16(hv[s].z, wp.z, a);
                    a = fdot2_f16(hv[s].w, wp.w, a);
                    acc[oo][s] = a;
                }
            }
        }
#pragma unroll
        for (int off = 32; off > 0; off >>= 1)
#pragma unroll
            for (int oo = 0; oo < 4; ++oo)
#pragma unroll
                for (int s = 0; s < FCNS; ++s)
                    acc[oo][s] += __shfl_down(acc[oo][s], off, 64);
        if (lane == 0) {
#pragma unroll
            for (int oo = 0; oo < 4; ++oo) {
                const float b = bl0[ot*4+oo];
#pragma unroll
                for (int s = 0; s < FCNS; ++s)
                    hbuf[s * HID + ot*4+oo] = fmaxf(acc[oo][s] + b, 0.f);
            }
        }
    }
    __syncthreads();
    if (tid < 2 * FCNS) {
        const int s = tid >> 1, r = tid & 1;
        const float* w = wl1 + r * HID;
        float acc = bl1[r];
        for (int k = 0; k < HID; ++k) acc = fmaf(hbuf[s * HID + k], w[k], acc);
        out[r * NBATCH + n0 + s] = acc;
    }
}

// ---------------------------------------------------------------------------
// launch
// ---------------------------------------------------------------------------
extern "C" void kernel_launch(void* const* d_in, const int* in_sizes, int n_in,
                              void* d_out, int out_size, void* d_ws, size_t ws_size,
                              hipStream_t stream)
{
    const float* x   = (const float*)d_in[0];
    const float* w0  = (const float*)d_in[1];
    const float* b0  = (const float*)d_in[2];
    const float* w1  = (const float*)d_in[3];
    const float* b1  = (const float*)d_in[4];
    const float* w2  = (const float*)d_in[5];
    const float* b2  = (const float*)d_in[6];
    const float* w3  = (const float*)d_in[7];
    const float* b3  = (const float*)d_in[8];
    const float* wc  = (const float*)d_in[9];
    const float* bc  = (const float*)d_in[10];
    const float* wl0 = (const float*)d_in[11];
    const float* bl0 = (const float*)d_in[12];
    const float* wl1 = (const float*)d_in[13];
    const float* bl1 = (const float*)d_in[14];
    float* out = (float*)d_out;

    // workspace layout (floats)
    const size_t HCAT_N = (size_t)NBATCH * HCATW;        // 7,823,360
    const size_t EIG_N  = (size_t)NBATCH * 21;
    const size_t need_bytes = (HCAT_N + EIG_N + 4 + WREPSZ + WL0HSZ) * 4 + 16;
    if (ws_size < need_bytes) return;

    float* ws     = (float*)d_ws;
    float* hcat   = ws;
    float* eigbuf = hcat + HCAT_N;
    unsigned int* gmax = (unsigned int*)(eigbuf + EIG_N);
    float* wrep   = (float*)(gmax + 4);
    unsigned int* wl0h = (unsigned int*)(wrep + WREPSZ);

    hipMemsetAsync(gmax, 0, 2 * sizeof(unsigned int), stream);

    repack_kernel<<<16, 256, 0, stream>>>(w0, b0, w1, b1, w2, b2, w3, b3, wrep);
    wl0h_kernel<<<(WL0HSZ + 255) / 256, 256, 0, stream>>>(wl0, wl0h);
    conv_chain_eo<<<NBATCH * NCHK, 512, 0, stream>>>(x, wrep, hcat);
    cov_eig_kernel<<<NBATCH, 256, 0, stream>>>(x, eigbuf, gmax);
    feats_kernel<<<NBATCH, 256, 0, stream>>>(eigbuf, gmax, wc, bc, hcat);
    fc01_kernel<<<NBATCH / FCNS, 512, 0, stream>>>(hcat, wl0h, bl0, wl1, bl1, out);
}

// Round 8
// 610.108 us; speedup vs baseline: 1.3263x; 1.0087x over previous
//
#include <hip/hip_runtime.h>
#include <hip/hip_fp16.h>
#include <math.h>

// ---------------------------------------------------------------------------
// Problem constants
// ---------------------------------------------------------------------------
#define NBATCH 1024
#define LIN    6000
#define HCATW  7640       // 20*375 + 20*7
#define HID    100

// conv-chain chunking: T=54 final(375-res) positions per block, 7 chunks.
//   JOUT chain = 8T+14, 4T+6, 2T+2, T = 446, 222, 110, 54
// R12: 476us conv, VALUBusy 91%, occ 87% -> purely VALU-issue-bound.
// R13: s1/s2 inner loop -> v_pk_fma_f16 on packed (ae,ao) fp16 accumulators:
//   per o 3 instrs (was 4), no cvts. Weights repacked as splat-half2
//   (WSTR 24). ~-25% per-(t,ic) VALU on the two dominant stages.
//   fp16 accum = the deliberate numerics gamble (revert: dot2-fp32).
//   (R13c: epilogue via fp32 max — __hmax2/__lowhigh2highlow don't exist
//   for __half2 in ROCm 7.2 headers; epilogue cost is negligible.)
#define TCH   54
#define NCHK  7

#define ASZ 3552            // max(x-buf 2682, s1-out fp16 32*111dw=3552, s3 part 2560)
#define BSZ 4460            // max(s0-out fp16 20*223dw=4460, s2-out fp16 64*55dw=3520)

// repacked-weight offsets (dwords) inside wrep
// s0: fp32, per (ocg,ic) 16 floats (5o x 3 + pad)
// s1/s2: PK16, per (ocg,ic) 24 dwords: splat-half2 w[k] for o=0..7, k=0..2
// s3: per (ocg,ic) 16 dwords: [0..7]=half2(w0,w1), [8..15]=f32 w2
#define W0OFF 0             // 4*3*16   = 192
#define W1OFF 192           // 4*20*24  = 1920
#define W2OFF 2112          // 8*32*24  = 6144
#define W3OFF 8256          // 4*64*16  = 4096
#define B0OFF 12352
#define B1OFF 12372
#define B2OFF 12404
#define B3OFF 12468
#define WREPSZ 12496

#define WL0HSZ (HID * (HCATW/2))   // 382,000 dwords of packed fp16 wl0

// fc01: samples per block
#define FCNS 8

typedef _Float16 v2h __attribute__((ext_vector_type(2)));

__device__ __forceinline__ float fdot2_f16(unsigned int a, unsigned int b, float c) {
#if __has_builtin(__builtin_amdgcn_fdot2)
    v2h ah, bh;
    __builtin_memcpy(&ah, &a, 4);
    __builtin_memcpy(&bh, &b, 4);
    return __builtin_amdgcn_fdot2(ah, bh, c, false);
#else
    float d;
    asm("v_dot2_f32_f16 %0, %1, %2, %3" : "=v"(d) : "v"(a), "v"(b), "v"(c));
    return d;
#endif
}

__device__ __forceinline__ __half2 u2h2(unsigned int u) {
    __half2 h; __builtin_memcpy(&h, &u, 4); return h;
}

// ---------------------------------------------------------------------------
// Weight repack
// ---------------------------------------------------------------------------
__device__ __forceinline__ void pack_one(int idx, int OC, int IC, int OCG,
                                         int OPG, int WSTR,
                                         const float* __restrict__ w,
                                         float* __restrict__ dst)
{
    if (idx >= OCG * IC * WSTR) return;
    int ocg = idx / (IC * WSTR);
    int r   = idx - ocg * (IC * WSTR);
    int ic  = r / WSTR;
    int q   = r - ic * WSTR;
    int o   = q / 3, k = q - o * 3;
    int oc  = ocg * OPG + o;
    dst[idx] = (o < OPG && oc < OC) ? w[(oc * IC + ic) * 3 + k] : 0.f;
}

// PK16 pack: OC multiple of 8; per (ocg,ic) 24 dwords of splat-half2 w[k]
__device__ __forceinline__ void pack_pk16(int idx, int OC, int IC,
                                          const float* __restrict__ w,
                                          unsigned int* __restrict__ dst)
{
    const int OCG = OC >> 3;
    if (idx >= OCG * IC * 24) return;
    int ocg = idx / (IC * 24);
    int r   = idx - ocg * (IC * 24);
    int ic  = r / 24, q = r - ic * 24;
    int o   = q / 3, k = q - o * 3;
    int oc  = ocg * 8 + o;
    float wv = w[(oc * IC + ic) * 3 + k];
    unsigned int h = __half_as_ushort(__float2half(wv));
    dst[idx] = h | (h << 16);
}

// dot2 pack (s3): per (ocg,ic) 16 dwords: [0..7]=half2(w0,w1), [8..15]=f32 w2
__device__ __forceinline__ void pack_pk(int idx, int OC, int IC, int OCG, int OPG,
                                        const float* __restrict__ w,
                                        unsigned int* __restrict__ dst)
{
    if (idx >= OCG * IC * 16) return;
    int ocg = idx / (IC * 16);
    int r   = idx - ocg * (IC * 16);
    int ic  = r >> 4, q = r & 15;
    int o   = q & 7;
    int oc  = ocg * OPG + o;
    bool valid = (o < OPG) && (oc < OC);
    unsigned int v = 0;
    if (valid) {
        const float* ws = w + (oc * IC + ic) * 3;
        if (q < 8) {
            unsigned int lo = __half_as_ushort(__float2half(ws[0]));
            unsigned int hi = __half_as_ushort(__float2half(ws[1]));
            v = lo | (hi << 16);
        } else {
            v = __float_as_uint(ws[2]);
        }
    }
    dst[idx] = v;
}

// combined: conv-weight repack + wl0 fp16 pack (one launch)
__global__ __launch_bounds__(256) void prep_kernel(
    const float* __restrict__ w0, const float* __restrict__ b0,
    const float* __restrict__ w1, const float* __restrict__ b1,
    const float* __restrict__ w2, const float* __restrict__ b2,
    const float* __restrict__ w3, const float* __restrict__ b3,
    const float* __restrict__ wl0,
    float* __restrict__ wrep, unsigned int* __restrict__ wl0h)
{
    int idx = blockIdx.x * 256 + threadIdx.x;
    if (idx < WL0HSZ) {
        float a = wl0[idx * 2], b = wl0[idx * 2 + 1];
        unsigned int lo = __half_as_ushort(__float2half(a));
        unsigned int hi = __half_as_ushort(__float2half(b));
        wl0h[idx] = lo | (hi << 16);
    }
    if (idx < 8192) {
        unsigned int* wu = (unsigned int*)wrep;
        pack_one (idx, 20,  3, 4, 5, 16, w0, wrep + W0OFF);
        pack_pk16(idx, 32, 20, w1, wu + W1OFF);
        pack_pk16(idx, 64, 32, w2, wu + W2OFF);
        pack_pk  (idx, 20, 64, 4, 5, w3, wu + W3OFF);
        if (idx < 20)            wrep[B0OFF + idx] = b0[idx];
        else if (idx < 52)  { int i = idx - 20;  wrep[B1OFF + i] = b1[i]; }
        else if (idx < 116) { int i = idx - 52;  wrep[B2OFF + i] = b2[i]; }
        else if (idx < 136) { int i = idx - 116; wrep[B3OFF + i] = b3[i]; }
    }
}

// ---------------------------------------------------------------------------
// One conv(K=3,SAME)+ReLU+pool2 stage on LDS buffers.
// 8 waves per block (512 threads), wave-strided tasks of JBLK*64 outputs.
// fp32 buffers: even/odd-split planes (2*PIN floats per channel).
// fp16 buffers: interleaved shorts, plane stride PIN dwords; dword p =
//   (pooled[2p], pooled[2p+1]); one ds_read2_b32 at dword jc yields
//   (e0,o0,e1,o1).
// PK16: splat-half2 weights (24 dw per (ocg,ic)); per o three v_pk_fma_f16
//   on the packed (ae,ao) fp16 accumulator:
//     acc += (e0,o0)*(w0,w0); acc += (o0,e1)*(w1,w1); acc += (e1,o1)*(w2,w2)
// ---------------------------------------------------------------------------
template<int IC, int OC, int OCG, int OPG, int WSTR, int JOUT, int LG, int JBLK,
         bool IN16, bool OUT16, bool PK16, bool FINAL>
__device__ __forceinline__ void stage_eo(const float* __restrict__ in,
                                         float* __restrict__ out,
                                         float* __restrict__ outg,
                                         const float* __restrict__ wrep,
                                         const float* __restrict__ brep,
                                         int pbase, int o3, int wv, int lane,
                                         int zero)
{
    constexpr int PIN  = JOUT + 1;
    constexpr int POUT = JOUT / 2;
    constexpr int NJT  = (JOUT + 64 * JBLK - 1) / (64 * JBLK);
    for (int task = wv; task < OCG * NJT; task += 8) {
        const int ocg = task / NJT;                 // wave-uniform (wv uniform)
        const int jt  = task - ocg * NJT;
        const int j0  = jt * (64 * JBLK) + lane;
        const float* bp = brep + ocg * OPG;
        float ae[JBLK][OPG], ao[JBLK][OPG];
        __half2 ap[JBLK][OPG];
        if constexpr (PK16) {
#pragma unroll
            for (int t = 0; t < JBLK; ++t)
#pragma unroll
                for (int o = 0; o < OPG; ++o) {
                    __half hb = __float2half(bp[o]);
                    ap[t][o] = __halves2half2(hb, hb);
                }
        } else {
#pragma unroll
            for (int t = 0; t < JBLK; ++t)
#pragma unroll
                for (int o = 0; o < OPG; ++o) { ae[t][o] = bp[o]; ao[t][o] = ae[t][o]; }
        }
        const float* wbase = wrep + ocg * (IC * WSTR) + zero;  // stays VMEM

        auto icbody = [&](int ic) {
            const float* wp = wbase + ic * WSTR;
            float wr[WSTR];
#pragma unroll
            for (int q = 0; q < WSTR / 4; ++q)
                *(float4*)&wr[q * 4] = *(const float4*)(wp + q * 4);
#pragma unroll
            for (int t = 0; t < JBLK; ++t) {
                const int jj = j0 + t * 64;
                const int jc = (jj < JOUT) ? jj : (JOUT - 1);
                if constexpr (PK16) {
                    const float* ipw = in + ic * PIN;
                    uint2 pw;
                    __builtin_memcpy(&pw, ipw + jc, 8);   // ds_read2_b32
                    const unsigned int crossu = (pw.x >> 16) | (pw.y << 16);
#pragma unroll
                    for (int o = 0; o < OPG; ++o) {
                        __half2 a = ap[t][o];
                        a = __hfma2(u2h2(pw.x),   u2h2(__float_as_uint(wr[o*3+0])), a);
                        a = __hfma2(u2h2(crossu), u2h2(__float_as_uint(wr[o*3+1])), a);
                        a = __hfma2(u2h2(pw.y),   u2h2(__float_as_uint(wr[o*3+2])), a);
                        ap[t][o] = a;
                    }
                } else {
                    float e0, e1, o0, o1;
                    if constexpr (IN16) {
                        const float* ipw = in + ic * PIN;
                        uint2 pw;
                        __builtin_memcpy(&pw, ipw + jc, 8);   // ds_read2_b32
                        __half2 h0 = u2h2(pw.x);
                        __half2 h1 = u2h2(pw.y);
                        e0 = __low2float(h0); o0 = __high2float(h0);
                        e1 = __low2float(h1); o1 = __high2float(h1);
                    } else {
                        const float* ip = in + ic * (2 * PIN);
                        float2 ev, ov;
                        __builtin_memcpy(&ev, ip + jc, 8);        // ds_read2_b32
                        __builtin_memcpy(&ov, ip + PIN + jc, 8);  // ds_read2_b32
                        e0 = ev.x; e1 = ev.y;
                        o0 = ov.x; o1 = ov.y;
                    }
#pragma unroll
                    for (int o = 0; o < OPG; ++o) {
                        const float w0 = wr[o*3+0], w1 = wr[o*3+1], w2 = wr[o*3+2];
                        ae[t][o] = fmaf(e0, w0, fmaf(o0, w1, fmaf(e1, w2, ae[t][o])));
                        ao[t][o] = fmaf(o0, w0, fmaf(e1, w1, fmaf(o1, w2, ao[t][o])));
                    }
                }
            }
        };
        if constexpr (PK16) {
#pragma unroll 1
            for (int ic = 0; ic < IC; ++ic) icbody(ic);
        } else {
#pragma unroll 2
            for (int ic = 0; ic < IC; ++ic) icbody(ic);
        }

#pragma unroll
        for (int t = 0; t < JBLK; ++t) {
            const int jj = j0 + t * 64;
            if constexpr (FINAL) {
                const int gj = o3 + jj;
                if (gj < 375 && jj < JOUT) {
#pragma unroll
                    for (int o = 0; o < OPG; ++o)
                        outg[(ocg*OPG+o) * 375 + gj] =
                            fmaxf(fmaxf(ae[t][o], ao[t][o]), 0.f);
                }
            } else {
                const int g = pbase + jj;
                const bool val = (jj < JOUT) && (g >= 0) && (g < LG);
                if (jj < JOUT) {
                    if constexpr (PK16) {
                        __half* dh = (__half*)out;
#pragma unroll
                        for (int o = 0; o < OPG; ++o) {
                            float ee = __low2float(ap[t][o]);
                            float oo = __high2float(ap[t][o]);
                            float v = val ? fmaxf(fmaxf(ee, oo), 0.f) : 0.f;
                            dh[(ocg*OPG+o) * JOUT + jj] = __float2half(v);
                        }
                    } else if constexpr (OUT16) {
                        __half* dh = (__half*)out;
#pragma unroll
                        for (int o = 0; o < OPG; ++o) {
                            float v = val ? fmaxf(fmaxf(ae[t][o], ao[t][o]), 0.f)
                                          : 0.f;
                            dh[(ocg*OPG+o) * JOUT + jj] = __float2half(v);
                        }
                    } else {
                        float* dst = out + ((jj & 1) ? POUT : 0) + (jj >> 1);
#pragma unroll
                        for (int o = 0; o < OPG; ++o)
                            dst[(ocg*OPG+o) * JOUT] =
                                val ? fmaxf(fmaxf(ae[t][o], ao[t][o]), 0.f) : 0.f;
                    }
                }
            }
        }
    }
}

// ---------------------------------------------------------------------------
// Final stage (s3) split across all 8 waves: wave = (ocg 0..3) x (ic-half).
// fp16 interleaved input (plane stride 55 dwords), dot2 weights (fp32 accum).
// Upper-half waves publish fp32 partials through LDS `part` (buffer A),
// one barrier, lower-half waves combine + relu-pool + store.
// ---------------------------------------------------------------------------
__device__ __forceinline__ void stage3_split(const float* __restrict__ in,
                                             float* __restrict__ part,
                                             float* __restrict__ outg,
                                             const float* __restrict__ wrep,
                                             const float* __restrict__ brep,
                                             int o3, int wv, int lane, int zero)
{
    constexpr int JOUT = 54, PIND = 55, OPG = 5, WSTR = 16;
    const int ocg = wv & 3, ih = wv >> 2;
    const int j  = lane;
    const int jc = (j < JOUT) ? j : (JOUT - 1);
    const float* bp = brep + ocg * OPG;
    float ae[OPG], ao[OPG];
#pragma unroll
    for (int o = 0; o < OPG; ++o) {
        float b = ih ? 0.f : bp[o];
        ae[o] = b; ao[o] = b;
    }
    const float* wbase = wrep + (ocg * 64 + ih * 32) * WSTR + zero;
#pragma unroll 2
    for (int ic = 0; ic < 32; ++ic) {
        const float* ipw = in + (ih * 32 + ic) * PIND;
        uint2 pw;
        __builtin_memcpy(&pw, ipw + jc, 8);           // ds_read2_b32
        const unsigned int crossu = (pw.x >> 16) | (pw.y << 16);
        v2h h1; __builtin_memcpy(&h1, &pw.y, 4);
        const float e1 = (float)h1.x, o1 = (float)h1.y;
        const float* wp = wbase + ic * WSTR;
        float wr[WSTR];
#pragma unroll
        for (int q = 0; q < WSTR / 4; ++q)
            *(float4*)&wr[q * 4] = *(const float4*)(wp + q * 4);
#pragma unroll
        for (int o = 0; o < OPG; ++o) {
            const unsigned int wpk = __float_as_uint(wr[o]);
            const float w2 = wr[8 + o];
            ae[o] = fdot2_f16(pw.x,   wpk, ae[o]);
            ao[o] = fdot2_f16(crossu, wpk, ao[o]);
            ae[o] = fmaf(e1, w2, ae[o]);
            ao[o] = fmaf(o1, w2, ao[o]);
        }
    }
    if (ih == 1) {
#pragma unroll
        for (int o = 0; o < OPG; ++o) {
            float2 p = make_float2(ae[o], ao[o]);
            __builtin_memcpy(part + (ocg * OPG + o) * 128 + lane * 2, &p, 8);
        }
    }
    __syncthreads();
    if (ih == 0) {
#pragma unroll
        for (int o = 0; o < OPG; ++o) {
            float2 p;
            __builtin_memcpy(&p, part + (ocg * OPG + o) * 128 + lane * 2, 8);
            ae[o] += p.x; ao[o] += p.y;
        }
        const int gj = o3 + j;
        if (gj < 375 && j < JOUT) {
#pragma unroll
            for (int o = 0; o < OPG; ++o)
                outg[(ocg * OPG + o) * 375 + gj] =
                    fmaxf(fmaxf(ae[o], ao[o]), 0.f);
        }
    }
}

// LDS (3552+4460)*4 = 32,048 B -> 4 blocks/CU (wave-capped); 8 waves/EU.
__global__ __launch_bounds__(512, 8) void conv_chain_eo(
    const float* __restrict__ x,
    const float* __restrict__ wrep,
    float* __restrict__ hcat)
{
    __shared__ float A[ASZ];
    __shared__ float B[BSZ];

    const int tid  = threadIdx.x;
    const int wv   = __builtin_amdgcn_readfirstlane(tid >> 6);
    const int lane = tid & 63;
    // opaque zero: compiler can't prove uniformity -> weight loads stay VMEM
    const int zero = __builtin_amdgcn_ds_bpermute(0, 0);
    const int n     = blockIdx.x / NCHK;
    const int chunk = blockIdx.x % NCHK;
    const int o3 = chunk * TCH;
    const int p2 = 2*o3 - 1, p1 = 4*o3 - 3, p0 = 8*o3 - 7, xs = 16*o3 - 15;

    // stage x -> A in even/odd split (3 ch, 447 pairs, plane stride 894)
    const float* xn = x + (size_t)n * 3 * LIN;
    for (int idx = tid; idx < 3 * 894; idx += 512) {
        int c = idx / 894, i = idx - c * 894;
        int g = xs + i;
        float v = (g >= 0 && g < LIN) ? xn[c * LIN + g] : 0.f;
        A[c * 894 + ((i & 1) ? 447 : 0) + (i >> 1)] = v;
    }
    __syncthreads();
    // s0: fp32 in (x), fp16 out, fp32 weights + fma
    stage_eo< 3, 20, 4, 5, 16, 446, 3000, 2, false, true,  false, false>(
        A, B, nullptr, wrep + W0OFF, wrep + B0OFF, p0, o3, wv, lane, zero);
    __syncthreads();
    // s1: fp16 in/out, splat-half2 weights + pk_fma (fp16 accum)
    stage_eo<20, 32, 4, 8, 24, 222, 1500, 2, true,  true,  true,  false>(
        B, A, nullptr, wrep + W1OFF, wrep + B1OFF, p1, o3, wv, lane, zero);
    __syncthreads();
    // s2: fp16 in/out, splat-half2 weights + pk_fma (fp16 accum)
    stage_eo<32, 64, 8, 8, 24, 110,  750, 2, true,  true,  true,  false>(
        A, B, nullptr, wrep + W2OFF, wrep + B2OFF, p2, o3, wv, lane, zero);
    __syncthreads();
    // s3: fp16 in, dot2 weights (fp32 accum), split 2x32 ic across 8 waves
    stage3_split(B, A, hcat + (size_t)n * HCATW,
                 wrep + W3OFF, wrep + B3OFF, o3, wv, lane, zero);
}

// ---------------------------------------------------------------------------
// LAPACK ssyevd (n=3, uplo='L') replica: ssytrd -> ssteqr('I') -> apply Q.
// ---------------------------------------------------------------------------
__device__ __forceinline__ float fsign(float a, float b) {
    return (b >= 0.0f) ? fabsf(a) : -fabsf(a);
}
__device__ __forceinline__ float slapy2(float xx, float yy) {
    float xa = fabsf(xx), ya = fabsf(yy);
    float w = fmaxf(xa, ya), z = fminf(xa, ya);
    if (z == 0.f) return w;
    float t = z / w;
    return w * sqrtf(1.f + t*t);
}
// LAPACK 3.10+ slartg: c >= 0 always, r = sign(f)*hypot
__device__ __forceinline__ void slartg(float f, float g, float& c, float& s, float& r) {
    if (g == 0.f)      { c = 1.f; s = 0.f; r = f; }
    else if (f == 0.f) { c = 0.f; s = (g >= 0.f ? 1.f : -1.f); r = fabsf(g); }
    else {
        float d = sqrtf(f*f + g*g);
        c = fabsf(f) / d;
        r = fsign(d, f);
        s = g / r;
    }
}
__device__ void slaev2(float a, float b, float cc,
                       float& rt1, float& rt2, float& cs1, float& sn1) {
    float sm = a + cc, df = a - cc;
    float adf = fabsf(df);
    float tb = b + b, ab = fabsf(tb);
    float acmx, acmn;
    if (fabsf(a) > fabsf(cc)) { acmx = a; acmn = cc; } else { acmx = cc; acmn = a; }
    float rt;
    if (adf > ab)      { float t = ab/adf; rt = adf*sqrtf(1.f + t*t); }
    else if (adf < ab) { float t = adf/ab; rt = ab*sqrtf(1.f + t*t); }
    else rt = ab * sqrtf(2.f);
    int sgn1;
    if (sm < 0.f)      { rt1 = 0.5f*(sm - rt); sgn1 = -1; rt2 = (acmx/rt1)*acmn - (b/rt1)*b; }
    else if (sm > 0.f) { rt1 = 0.5f*(sm + rt); sgn1 =  1; rt2 = (acmx/rt1)*acmn - (b/rt1)*b; }
    else               { rt1 = 0.5f*rt; rt2 = -0.5f*rt; sgn1 = 1; }
    float cs; int sgn2;
    if (df >= 0.f) { cs = df + rt; sgn2 = 1; } else { cs = df - rt; sgn2 = -1; }
    float acs = fabsf(cs);
    if (acs > ab) {
        float ct = -tb / cs;
        sn1 = 1.f / sqrtf(1.f + ct*ct);
        cs1 = ct * sn1;
    } else {
        if (ab == 0.f) { cs1 = 1.f; sn1 = 0.f; }
        else {
            float tn = -cs / tb;
            cs1 = 1.f / sqrtf(1.f + tn*tn);
            sn1 = tn * cs1;
        }
    }
    if (sgn1 == sgn2) { float tn = cs1; cs1 = -sn1; sn1 = tn; }
}
__device__ __forceinline__ void rot_cols(float z[3][3], int jc, float c, float s) {
    for (int i = 0; i < 3; ++i) {
        float t = z[i][jc+1];
        z[i][jc+1] = c*t - s*z[i][jc];
        z[i][jc]   = s*t + c*z[i][jc];
    }
}

__device__ void ssteqr3(float d[3], float e[2], float z[3][3]) {
    const float eps    = 5.9604645e-8f;
    const float eps2   = eps * eps;
    const float safmin = 1.17549435e-38f;
    const int n = 3;
    for (int i = 0; i < 3; ++i)
        for (int j = 0; j < 3; ++j) z[i][j] = (i == j) ? 1.f : 0.f;
    const int nmaxit = n * 30;
    int jtot = 0;
    float cw[2], sw[2];
    int l1 = 1, l, m, lend, lsv, lendsv;

L10:
    if (l1 > n) goto L160;
    if (l1 > 1) e[l1-2] = 0.f;
    if (l1 <= n-1) {
        for (m = l1; m <= n-1; ++m) {
            float tst = fabsf(e[m-1]);
            if (tst == 0.f) goto L30;
            if (tst <= (sqrtf(fabsf(d[m-1])) * sqrtf(fabsf(d[m]))) * eps) {
                e[m-1] = 0.f;
                goto L30;
            }
        }
    }
    m = n;
L30:
    l = l1; lsv = l; lend = m; lendsv = lend; l1 = m + 1;
    if (lend == l) goto L10;
    if (fabsf(d[lend-1]) < fabsf(d[l-1])) { lend = lsv; l = lendsv; }
    if (lend > l) {
L40:
        if (l != lend) {
            bool found = false;
            for (m = l; m <= lend-1; ++m) {
                float tst = e[m-1]*e[m-1];
                if (tst <= (eps2*fabsf(d[m-1]))*fabsf(d[m]) + safmin) { found = true; break; }
            }
            if (!found) m = lend;
        } else m = lend;
        if (m < lend) e[m-1] = 0.f;
        {
            float p = d[l-1];
            if (m == l) {
                d[l-1] = p;
                l = l + 1;
                if (l <= lend) goto L40;
                goto L140;
            }
            if (m == l+1) {
                float rt1, rt2, c2, s2;
                slaev2(d[l-1], e[l-1], d[l], rt1, rt2, c2, s2);
                rot_cols(z, l-1, c2, s2);
                d[l-1] = rt1; d[l] = rt2; e[l-1] = 0.f;
                l += 2;
                if (l <= lend) goto L40;
                goto L140;
            }
            if (jtot == nmaxit) goto L140;
            jtot++;
            float g = (d[l] - p) / (2.f * e[l-1]);
            float r = slapy2(g, 1.f);
            g = d[m-1] - p + e[l-1] / (g + fsign(r, g));
            float s = 1.f, c = 1.f;
            p = 0.f;
            for (int i = m-1; i >= l; --i) {
                float f = s * e[i-1];
                float b = c * e[i-1];
                slartg(g, f, c, s, r);
                if (i != m-1) e[i] = r;
                g = d[i] - p;
                r = (d[i-1] - g)*s + 2.f*c*b;
                p = s * r;
                d[i] = g + p;
                g = c*r - b;
                cw[i-l] = c; sw[i-l] = -s;
            }
            for (int jj = m-l; jj >= 1; --jj)
                rot_cols(z, l + jj - 2, cw[jj-1], sw[jj-1]);
            d[l-1] = d[l-1] - p;
            e[l-1] = g;
            goto L40;
        }
    } else {
L90:
        if (l != lend) {
            bool found = false;
            for (m = l; m >= lend+1; --m) {
                float tst = e[m-2]*e[m-2];
                if (tst <= (eps2*fabsf(d[m-1]))*fabsf(d[m-2]) + safmin) { found = true; break; }
            }
            if (!found) m = lend;
        } else m = lend;
        if (m > lend) e[m-2] = 0.f;
        {
            float p = d[l-1];
            if (m == l) {
                d[l-1] = p;
                l = l - 1;
                if (l >= lend) goto L90;
                goto L140;
            }
            if (m == l-1) {
                float rt1, rt2, c2, s2;
                slaev2(d[l-2], e[l-2], d[l-1], rt1, rt2, c2, s2);
                rot_cols(z, l-2, c2, s2);
                d[l-2] = rt1; d[l-1] = rt2; e[l-2] = 0.f;
                l -= 2;
                if (l >= lend) goto L90;
                goto L140;
            }
            if (jtot == nmaxit) goto L140;
            jtot++;
            float g = (d[l-2] - p) / (2.f * e[l-2]);
            float r = slapy2(g, 1.f);
            g = d[m-1] - p + e[l-2] / (g + fsign(r, g));
            float s = 1.f, c = 1.f;
            p = 0.f;
            for (int i = m; i <= l-1; ++i) {
                float f = s * e[i-1];
                float b = c * e[i-1];
                slartg(g, f, c, s, r);
                if (i != m) e[i-2] = r;
                g = d[i-1] - p;
                r = (d[i] - g)*s + 2.f*c*b;
                p = s * r;
                d[i-1] = g + p;
                g = c*r - b;
                cw[i-m] = c; sw[i-m] = s;
            }
            for (int jj = 1; jj <= l-m; ++jj)
                rot_cols(z, m + jj - 2, cw[jj-1], sw[jj-1]);
            d[l-1] = d[l-1] - p;
            e[l-2] = g;
            goto L90;
        }
    }
L140:
    if (jtot < nmaxit) goto L10;
L160:
    for (int ii = 2; ii <= n; ++ii) {
        int i = ii - 1, k = i;
        float p = d[i-1];
        for (int j = ii; j <= n; ++j)
            if (d[j-1] < p) { k = j; p = d[j-1]; }
        if (k != i) {
            d[k-1] = d[i-1]; d[i-1] = p;
            for (int r0 = 0; r0 < 3; ++r0) {
                float t = z[r0][i-1]; z[r0][i-1] = z[r0][k-1]; z[r0][k-1] = t;
            }
        }
    }
}

// ---------------------------------------------------------------------------
// cov + eig kernel (x loads vectorized float4)
// ---------------------------------------------------------------------------
__global__ __launch_bounds__(256) void cov_eig_kernel(const float* __restrict__ x,
                                                      float* __restrict__ eigbuf,
                                                      unsigned int* __restrict__ gmax)
{
    __shared__ float part[4][9];
    const int n = blockIdx.x;
    const float* xn = x + (size_t)n * 3 * LIN;
    float v[9] = {0,0,0,0,0,0,0,0,0};
    for (int i = threadIdx.x; i < LIN / 4; i += 256) {
        float4 a = *(const float4*)(xn + 4 * i);
        float4 b = *(const float4*)(xn + LIN + 4 * i);
        float4 c = *(const float4*)(xn + 2 * LIN + 4 * i);
        v[0] += (a.x + a.y) + (a.z + a.w);
        v[1] += (b.x + b.y) + (b.z + b.w);
        v[2] += (c.x + c.y) + (c.z + c.w);
        v[3] = fmaf(a.x,a.x, fmaf(a.y,a.y, fmaf(a.z,a.z, fmaf(a.w,a.w, v[3]))));
        v[4] = fmaf(a.x,b.x, fmaf(a.y,b.y, fmaf(a.z,b.z, fmaf(a.w,b.w, v[4]))));
        v[5] = fmaf(a.x,c.x, fmaf(a.y,c.y, fmaf(a.z,c.z, fmaf(a.w,c.w, v[5]))));
        v[6] = fmaf(b.x,b.x, fmaf(b.y,b.y, fmaf(b.z,b.z, fmaf(b.w,b.w, v[6]))));
        v[7] = fmaf(b.x,c.x, fmaf(b.y,c.y, fmaf(b.z,c.z, fmaf(b.w,c.w, v[7]))));
        v[8] = fmaf(c.x,c.x, fmaf(c.y,c.y, fmaf(c.z,c.z, fmaf(c.w,c.w, v[8]))));
    }
#pragma unroll
    for (int off = 32; off > 0; off >>= 1)
#pragma unroll
        for (int i = 0; i < 9; ++i) v[i] += __shfl_down(v[i], off, 64);
    const int wv = threadIdx.x >> 6, lane = threadIdx.x & 63;
    if (lane == 0)
        for (int i = 0; i < 9; ++i) part[wv][i] = v[i];
    __syncthreads();
    if (threadIdx.x == 0) {
        float t[9];
        for (int i = 0; i < 9; ++i)
            t[i] = part[0][i] + part[1][i] + part[2][i] + part[3][i];
        const float Lf = (float)LIN;
        float m0 = t[0]/Lf, m1 = t[1]/Lf, m2 = t[2]/Lf;
        float c00 = (t[3] - Lf*m0*m0) / (Lf - 1.f);
        float c01 = (t[4] - Lf*m0*m1) / (Lf - 1.f);
        float c02 = (t[5] - Lf*m0*m2) / (Lf - 1.f);
        float c11 = (t[6] - Lf*m1*m1) / (Lf - 1.f);
        float c12 = (t[7] - Lf*m1*m2) / (Lf - 1.f);
        float c22 = (t[8] - Lf*m2*m2) / (Lf - 1.f);

        float dd[3], ee[2], tau, v2;
        {
            float a21 = c01, a31 = c02, a22 = c11, a32 = c12, a33 = c22;
            float xnorm = fabsf(a31);
            if (xnorm == 0.f) {
                tau = 0.f; v2 = 0.f;
                dd[0] = c00; dd[1] = a22; dd[2] = a33;
                ee[0] = a21; ee[1] = a32;
            } else {
                float beta = -fsign(slapy2(a21, xnorm), a21);
                tau = (beta - a21) / beta;
                v2  = a31 / (a21 - beta);
                ee[0] = beta;
                float x1 = tau*(a22 + a32*v2);
                float x2 = tau*(a32 + a33*v2);
                float al = -0.5f*tau*(x1 + x2*v2);
                float w1 = x1 + al;
                float w2 = x2 + al*v2;
                a22 -= 2.f*w1;
                a32 -= (v2*w1 + w2);
                a33 -= 2.f*v2*w2;
                dd[0] = c00; dd[1] = a22; dd[2] = a33;
                ee[1] = a32;
            }
        }
        float zz[3][3];
        ssteqr3(dd, ee, zz);
        if (tau != 0.f) {
            for (int j = 0; j < 3; ++j) {
                float sum = zz[1][j] + v2*zz[2][j];
                zz[1][j] -= tau * sum;
                zz[2][j] -= tau * v2 * sum;
            }
        }

        float* eb = eigbuf + n * 21;
        eb[0] = c00; eb[1] = c01; eb[2] = c02;
        eb[3] = c01; eb[4] = c11; eb[5] = c12;
        eb[6] = c02; eb[7] = c12; eb[8] = c22;
        eb[9] = dd[0]; eb[10] = dd[1]; eb[11] = dd[2];
        for (int c = 0; c < 3; ++c)
            for (int k = 0; k < 3; ++k) eb[12 + c*3 + k] = zz[c][k];

        float vmax = fmaxf(dd[0], fmaxf(dd[1], dd[2]));
        float cmax = 0.f;
        for (int i = 0; i < 9; ++i) cmax = fmaxf(cmax, fabsf(eb[i]));
        atomicMax(&gmax[0], __float_as_uint(vmax));
        atomicMax(&gmax[1], __float_as_uint(cmax));
    }
}

// ---------------------------------------------------------------------------
// feats -> 1x1 conv (wc) + relu, writes hcat[:, 7500:7640]
// ---------------------------------------------------------------------------
__global__ __launch_bounds__(256) void feats_kernel(const float* __restrict__ eigbuf,
                                                    const unsigned int* __restrict__ gmax,
                                                    const float* __restrict__ wc,
                                                    const float* __restrict__ bc,
                                                    float* __restrict__ hcat)
{
    const int n = blockIdx.x;
    const int t = threadIdx.x;
    if (t >= 140) return;
    const int o = t / 7, j = t % 7;
    const float* eb = eigbuf + n * 21;
    const float vmax = __uint_as_float(gmax[0]);
    const float cmax = __uint_as_float(gmax[1]);
    float f0, f1, f2;
    if (j < 3)       { f0 = eb[0*3+j]/cmax; f1 = eb[1*3+j]/cmax; f2 = eb[2*3+j]/cmax; }
    else if (j == 3) { f0 = eb[9]/vmax;     f1 = eb[10]/vmax;    f2 = eb[11]/vmax; }
    else             { int k = j-4; f0 = eb[12+0*3+k]; f1 = eb[12+1*3+k]; f2 = eb[12+2*3+k]; }
    float r = bc[o] + wc[o*3+0]*f0 + wc[o*3+1]*f1 + wc[o*3+2]*f2;
    hcat[(size_t)n*HCATW + 7500 + o*7 + j] = fmaxf(r, 0.f);
}

// ---------------------------------------------------------------------------
// FC0+FC1 fused, 8 samples per block (512 threads), h staged in LDS as fp16,
// wl0 pre-packed fp16 -> v_dot2_f32_f16 with fp32 accumulate.
// ---------------------------------------------------------------------------
__global__ __launch_bounds__(512) void fc01_kernel(const float* __restrict__ hcat,
                                                   const unsigned int* __restrict__ wl0h,
                                                   const float* __restrict__ bl0,
                                                   const float* __restrict__ wl1,
                                                   const float* __restrict__ bl1,
                                                   float* __restrict__ out)
{
    __shared__ __half hl[FCNS * HCATW];    // 122,240 B
    __shared__ float hbuf[FCNS * HID];     //   3,200 B
    const int tid = threadIdx.x;
    const int n0 = blockIdx.x * FCNS;
    // stage hcat fp32 -> fp16 LDS
    for (int i = tid; i < FCNS * (HCATW/4); i += 512) {
        int s  = i / (HCATW/4);
        int k4 = i - s * (HCATW/4);
        float4 v = *(const float4*)(hcat + (size_t)(n0 + s) * HCATW + k4 * 4);
        __half2 h01 = __floats2half2_rn(v.x, v.y);
        __half2 h23 = __floats2half2_rn(v.z, v.w);
        *(__half2*)(hl + s * HCATW + k4 * 4)     = h01;
        *(__half2*)(hl + s * HCATW + k4 * 4 + 2) = h23;
    }
    __syncthreads();
    const int wv = tid >> 6;
    const int lane = tid & 63;
    for (int ot = wv; ot < HID / 4; ot += 8) {      // 25 o-tiles of 4
        float acc[4][FCNS];
#pragma unroll
        for (int oo = 0; oo < 4; ++oo)
#pragma unroll
            for (int s = 0; s < FCNS; ++s) acc[oo][s] = 0.f;
        for (int k = lane * 8; k < HCATW; k += 512) {   // 8 halves per lane
            uint4 hv[FCNS];
#pragma unroll
            for (int s = 0; s < FCNS; ++s)
                hv[s] = *(const uint4*)(hl + s * HCATW + k);
#pragma unroll
            for (int oo = 0; oo < 4; ++oo) {
                const uint4 wp = *(const uint4*)(wl0h + (ot*4+oo) * (HCATW/2) + (k >> 1));
#pragma unroll
                for (int s = 0; s < FCNS; ++s) {
                    float a = acc[oo][s];
                    a = fdot2_f16(hv[s].x, wp.x, a);
                    a = fdot2_f16(hv[s].y, wp.y, a);
                    a = fdot2_f16(hv[s].z, wp.z, a);
                    a = fdot2_f16(hv[s].w, wp.w, a);
                    acc[oo][s] = a;
                }
            }
        }
#pragma unroll
        for (int off = 32; off > 0; off >>= 1)
#pragma unroll
            for (int oo = 0; oo < 4; ++oo)
#pragma unroll
                for (int s = 0; s < FCNS; ++s)
                    acc[oo][s] += __shfl_down(acc[oo][s], off, 64);
        if (lane == 0) {
#pragma unroll
            for (int oo = 0; oo < 4; ++oo) {
                const float b = bl0[ot*4+oo];
#pragma unroll
                for (int s = 0; s < FCNS; ++s)
                    hbuf[s * HID + ot*4+oo] = fmaxf(acc[oo][s] + b, 0.f);
            }
        }
    }
    __syncthreads();
    if (tid < 2 * FCNS) {
        const int s = tid >> 1, r = tid & 1;
        const float* w = wl1 + r * HID;
        float acc = bl1[r];
        for (int k = 0; k < HID; ++k) acc = fmaf(hbuf[s * HID + k], w[k], acc);
        out[r * NBATCH + n0 + s] = acc;
    }
}

// ---------------------------------------------------------------------------
// launch
// ---------------------------------------------------------------------------
extern "C" void kernel_launch(void* const* d_in, const int* in_sizes, int n_in,
                              void* d_out, int out_size, void* d_ws, size_t ws_size,
                              hipStream_t stream)
{
    const float* x   = (const float*)d_in[0];
    const float* w0  = (const float*)d_in[1];
    const float* b0  = (const float*)d_in[2];
    const float* w1  = (const float*)d_in[3];
    const float* b1  = (const float*)d_in[4];
    const float* w2  = (const float*)d_in[5];
    const float* b2  = (const float*)d_in[6];
    const float* w3  = (const float*)d_in[7];
    const float* b3  = (const float*)d_in[8];
    const float* wc  = (const float*)d_in[9];
    const float* bc  = (const float*)d_in[10];
    const float* wl0 = (const float*)d_in[11];
    const float* bl0 = (const float*)d_in[12];
    const float* wl1 = (const float*)d_in[13];
    const float* bl1 = (const float*)d_in[14];
    float* out = (float*)d_out;

    // workspace layout (floats)
    const size_t HCAT_N = (size_t)NBATCH * HCATW;        // 7,823,360
    const size_t EIG_N  = (size_t)NBATCH * 21;
    const size_t need_bytes = (HCAT_N + EIG_N + 4 + WREPSZ + WL0HSZ) * 4 + 16;
    if (ws_size < need_bytes) return;

    float* ws     = (float*)d_ws;
    float* hcat   = ws;
    float* eigbuf = hcat + HCAT_N;
    unsigned int* gmax = (unsigned int*)(eigbuf + EIG_N);
    float* wrep   = (float*)(gmax + 4);
    unsigned int* wl0h = (unsigned int*)(wrep + WREPSZ);

    hipMemsetAsync(gmax, 0, 2 * sizeof(unsigned int), stream);

    prep_kernel<<<(WL0HSZ + 255) / 256, 256, 0, stream>>>(
        w0, b0, w1, b1, w2, b2, w3, b3, wl0, wrep, wl0h);
    conv_chain_eo<<<NBATCH * NCHK, 512, 0, stream>>>(x, wrep, hcat);
    cov_eig_kernel<<<NBATCH, 256, 0, stream>>>(x, eigbuf, gmax);
    feats_kernel<<<NBATCH, 256, 0, stream>>>(eigbuf, gmax, wc, bc, hcat);
    fc01_kernel<<<NBATCH / FCNS, 512, 0, stream>>>(hcat, wl0h, bl0, wl1, bl1, out);
}

// Round 9
// 605.779 us; speedup vs baseline: 1.3358x; 1.0071x over previous
//
#include <hip/hip_runtime.h>
#include <hip/hip_fp16.h>
#include <math.h>

// ---------------------------------------------------------------------------
// Problem constants
// ---------------------------------------------------------------------------
#define NBATCH 1024
#define LIN    6000
#define HCATW  7640       // 20*375 + 20*7
#define HID    100

// conv-chain chunking: T=54 final(375-res) positions per block, 7 chunks.
//   JOUT chain = 8T+14, 4T+6, 2T+2, T = 446, 222, 110, 54
// R13: s1/s2 pk_fma_f16 -> 461us, VALUBusy 92%. DS-audit: ~12.4K DS-cyc vs
//   ~16K VALU-cyc per CU -> approaching VALU/DS co-saturation (explains the
//   <50% realization of static instruction cuts).
// R14: finish PK16 conversion: s0 (x staged fp16-interleaved; also halves
//   x ds_reads) and s3 (fp16 accum per 32-ic half, fp32 combine). All four
//   stages now splat-half2 weights + v_pk_fma_f16.
#define TCH   54
#define NCHK  7

#define ASZ 3552            // max(x-buf fp16 3*447dw=1341, s1-out 3552, s3 part 1280)
#define BSZ 4460            // max(s0-out fp16 20*223dw=4460, s2-out fp16 64*55dw=3520)

// repacked-weight offsets (dwords) inside wrep — all splat-half2 PK16:
// per (ocg,ic): WSTR dwords, dword q (q<OPG*3) = splat-half2 w[oc=ocg*OPG+q/3][ic][q%3]
#define W0OFF 0             // 4*3*16   = 192
#define W1OFF 192           // 4*20*24  = 1920
#define W2OFF 2112          // 8*32*24  = 6144
#define W3OFF 8256          // 4*64*16  = 4096
#define B0OFF 12352
#define B1OFF 12372
#define B2OFF 12404
#define B3OFF 12468
#define WREPSZ 12496

#define WL0HSZ (HID * (HCATW/2))   // 382,000 dwords of packed fp16 wl0

// fc01: samples per block
#define FCNS 8

typedef _Float16 v2h __attribute__((ext_vector_type(2)));

__device__ __forceinline__ float fdot2_f16(unsigned int a, unsigned int b, float c) {
#if __has_builtin(__builtin_amdgcn_fdot2)
    v2h ah, bh;
    __builtin_memcpy(&ah, &a, 4);
    __builtin_memcpy(&bh, &b, 4);
    return __builtin_amdgcn_fdot2(ah, bh, c, false);
#else
    float d;
    asm("v_dot2_f32_f16 %0, %1, %2, %3" : "=v"(d) : "v"(a), "v"(b), "v"(c));
    return d;
#endif
}

__device__ __forceinline__ __half2 u2h2(unsigned int u) {
    __half2 h; __builtin_memcpy(&h, &u, 4); return h;
}

// ---------------------------------------------------------------------------
// Weight repack: generalized splat-half2 pack.
// per (ocg,ic): WSTR dwords; dword q = splat(w[ocg*OPG + q/3][ic][q%3]) if
// q/3 < OPG else 0.
// ---------------------------------------------------------------------------
__device__ __forceinline__ void pack_pk16g(int idx, int OC, int IC, int OCG,
                                           int OPG, int WSTR,
                                           const float* __restrict__ w,
                                           unsigned int* __restrict__ dst)
{
    if (idx >= OCG * IC * WSTR) return;
    int ocg = idx / (IC * WSTR);
    int r   = idx - ocg * (IC * WSTR);
    int ic  = r / WSTR, q = r - ic * WSTR;
    int o   = q / 3, k = q - o * 3;
    int oc  = ocg * OPG + o;
    unsigned int v = 0;
    if (o < OPG && oc < OC) {
        float wv = w[(oc * IC + ic) * 3 + k];
        unsigned int h = __half_as_ushort(__float2half(wv));
        v = h | (h << 16);
    }
    dst[idx] = v;
}

// combined: conv-weight repack + wl0 fp16 pack (one launch)
__global__ __launch_bounds__(256) void prep_kernel(
    const float* __restrict__ w0, const float* __restrict__ b0,
    const float* __restrict__ w1, const float* __restrict__ b1,
    const float* __restrict__ w2, const float* __restrict__ b2,
    const float* __restrict__ w3, const float* __restrict__ b3,
    const float* __restrict__ wl0,
    float* __restrict__ wrep, unsigned int* __restrict__ wl0h)
{
    int idx = blockIdx.x * 256 + threadIdx.x;
    if (idx < WL0HSZ) {
        float a = wl0[idx * 2], b = wl0[idx * 2 + 1];
        unsigned int lo = __half_as_ushort(__float2half(a));
        unsigned int hi = __half_as_ushort(__float2half(b));
        wl0h[idx] = lo | (hi << 16);
    }
    if (idx < 8192) {
        unsigned int* wu = (unsigned int*)wrep;
        pack_pk16g(idx, 20,  3, 4, 5, 16, w0, wu + W0OFF);
        pack_pk16g(idx, 32, 20, 4, 8, 24, w1, wu + W1OFF);
        pack_pk16g(idx, 64, 32, 8, 8, 24, w2, wu + W2OFF);
        pack_pk16g(idx, 20, 64, 4, 5, 16, w3, wu + W3OFF);
        if (idx < 20)            wrep[B0OFF + idx] = b0[idx];
        else if (idx < 52)  { int i = idx - 20;  wrep[B1OFF + i] = b1[i]; }
        else if (idx < 116) { int i = idx - 52;  wrep[B2OFF + i] = b2[i]; }
        else if (idx < 136) { int i = idx - 116; wrep[B3OFF + i] = b3[i]; }
    }
}

// ---------------------------------------------------------------------------
// One conv(K=3,SAME)+ReLU+pool2 stage on LDS buffers (all-PK16 now).
// 8 waves per block (512 threads), wave-strided tasks of JBLK*64 outputs.
// fp16 buffers: interleaved shorts, plane stride PIN dwords; dword p =
//   (pooled[2p], pooled[2p+1]); one ds_read2_b32 at dword jc yields
//   (e0,o0,e1,o1).
// PK16 math: splat-half2 weights; per o three v_pk_fma_f16 on the packed
//   (ae,ao) fp16 accumulator:
//     acc += (e0,o0)*(w0,w0); acc += (o0,e1)*(w1,w1); acc += (e1,o1)*(w2,w2)
// ---------------------------------------------------------------------------
template<int IC, int OC, int OCG, int OPG, int WSTR, int JOUT, int LG, int JBLK,
         bool FINAL>
__device__ __forceinline__ void stage_eo(const float* __restrict__ in,
                                         float* __restrict__ out,
                                         float* __restrict__ outg,
                                         const float* __restrict__ wrep,
                                         const float* __restrict__ brep,
                                         int pbase, int o3, int wv, int lane,
                                         int zero)
{
    constexpr int PIN  = JOUT + 1;
    constexpr int NJT  = (JOUT + 64 * JBLK - 1) / (64 * JBLK);
    for (int task = wv; task < OCG * NJT; task += 8) {
        const int ocg = task / NJT;                 // wave-uniform (wv uniform)
        const int jt  = task - ocg * NJT;
        const int j0  = jt * (64 * JBLK) + lane;
        const float* bp = brep + ocg * OPG;
        __half2 ap[JBLK][OPG];
#pragma unroll
        for (int t = 0; t < JBLK; ++t)
#pragma unroll
            for (int o = 0; o < OPG; ++o) {
                __half hb = __float2half(bp[o]);
                ap[t][o] = __halves2half2(hb, hb);
            }
        const float* wbase = wrep + ocg * (IC * WSTR) + zero;  // stays VMEM
#pragma unroll 1
        for (int ic = 0; ic < IC; ++ic) {
            const float* wp = wbase + ic * WSTR;
            float wr[WSTR];
#pragma unroll
            for (int q = 0; q < WSTR / 4; ++q)
                *(float4*)&wr[q * 4] = *(const float4*)(wp + q * 4);
#pragma unroll
            for (int t = 0; t < JBLK; ++t) {
                const int jj = j0 + t * 64;
                const int jc = (jj < JOUT) ? jj : (JOUT - 1);
                const float* ipw = in + ic * PIN;
                uint2 pw;
                __builtin_memcpy(&pw, ipw + jc, 8);   // ds_read2_b32
                const unsigned int crossu = (pw.x >> 16) | (pw.y << 16);
#pragma unroll
                for (int o = 0; o < OPG; ++o) {
                    __half2 a = ap[t][o];
                    a = __hfma2(u2h2(pw.x),   u2h2(__float_as_uint(wr[o*3+0])), a);
                    a = __hfma2(u2h2(crossu), u2h2(__float_as_uint(wr[o*3+1])), a);
                    a = __hfma2(u2h2(pw.y),   u2h2(__float_as_uint(wr[o*3+2])), a);
                    ap[t][o] = a;
                }
            }
        }

#pragma unroll
        for (int t = 0; t < JBLK; ++t) {
            const int jj = j0 + t * 64;
            if constexpr (FINAL) {
                const int gj = o3 + jj;
                if (gj < 375 && jj < JOUT) {
#pragma unroll
                    for (int o = 0; o < OPG; ++o) {
                        float ee = __low2float(ap[t][o]);
                        float oo = __high2float(ap[t][o]);
                        outg[(ocg*OPG+o) * 375 + gj] = fmaxf(fmaxf(ee, oo), 0.f);
                    }
                }
            } else {
                const int g = pbase + jj;
                const bool val = (jj < JOUT) && (g >= 0) && (g < LG);
                if (jj < JOUT) {
                    __half* dh = (__half*)out;
#pragma unroll
                    for (int o = 0; o < OPG; ++o) {
                        float ee = __low2float(ap[t][o]);
                        float oo = __high2float(ap[t][o]);
                        float v = val ? fmaxf(fmaxf(ee, oo), 0.f) : 0.f;
                        dh[(ocg*OPG+o) * JOUT + jj] = __float2half(v);
                    }
                }
            }
        }
    }
}

// ---------------------------------------------------------------------------
// Final stage (s3) split across all 8 waves: wave = (ocg 0..3) x (ic-half).
// fp16 interleaved input (plane stride 55 dwords), PK16 math (fp16 accum
// per 32-ic half), fp32 combine. Upper-half waves publish half2 partials
// through LDS `part` (buffer A), one barrier, lower-half waves combine +
// relu-pool + store.
// ---------------------------------------------------------------------------
__device__ __forceinline__ void stage3_split(const float* __restrict__ in,
                                             float* __restrict__ part,
                                             float* __restrict__ outg,
                                             const float* __restrict__ wrep,
                                             const float* __restrict__ brep,
                                             int o3, int wv, int lane, int zero)
{
    constexpr int JOUT = 54, PIND = 55, OPG = 5, WSTR = 16;
    const int ocg = wv & 3, ih = wv >> 2;
    const int j  = lane;
    const int jc = (j < JOUT) ? j : (JOUT - 1);
    const float* bp = brep + ocg * OPG;
    __half2 ap[OPG];
#pragma unroll
    for (int o = 0; o < OPG; ++o) {
        __half hb = __float2half(ih ? 0.f : bp[o]);
        ap[o] = __halves2half2(hb, hb);
    }
    const float* wbase = wrep + (ocg * 64 + ih * 32) * WSTR + zero;
#pragma unroll 2
    for (int ic = 0; ic < 32; ++ic) {
        const float* ipw = in + (ih * 32 + ic) * PIND;
        uint2 pw;
        __builtin_memcpy(&pw, ipw + jc, 8);           // ds_read2_b32
        const unsigned int crossu = (pw.x >> 16) | (pw.y << 16);
        const float* wp = wbase + ic * WSTR;
        float wr[WSTR];
#pragma unroll
        for (int q = 0; q < WSTR / 4; ++q)
            *(float4*)&wr[q * 4] = *(const float4*)(wp + q * 4);
#pragma unroll
        for (int o = 0; o < OPG; ++o) {
            __half2 a = ap[o];
            a = __hfma2(u2h2(pw.x),   u2h2(__float_as_uint(wr[o*3+0])), a);
            a = __hfma2(u2h2(crossu), u2h2(__float_as_uint(wr[o*3+1])), a);
            a = __hfma2(u2h2(pw.y),   u2h2(__float_as_uint(wr[o*3+2])), a);
            ap[o] = a;
        }
    }
    unsigned int* pu = (unsigned int*)part;
    if (ih == 1) {
#pragma unroll
        for (int o = 0; o < OPG; ++o) {
            unsigned int u; __builtin_memcpy(&u, &ap[o], 4);
            pu[(ocg * OPG + o) * 64 + lane] = u;
        }
    }
    __syncthreads();
    if (ih == 0) {
        const int gj = o3 + j;
        if (gj < 375 && j < JOUT) {
#pragma unroll
            for (int o = 0; o < OPG; ++o) {
                __half2 p = u2h2(pu[(ocg * OPG + o) * 64 + lane]);
                float ee = __low2float(ap[o])  + __low2float(p);
                float oo = __high2float(ap[o]) + __high2float(p);
                outg[(ocg * OPG + o) * 375 + gj] = fmaxf(fmaxf(ee, oo), 0.f);
            }
        }
    }
}

// LDS (3552+4460)*4 = 32,048 B -> 4 blocks/CU (wave-capped); 8 waves/EU.
__global__ __launch_bounds__(512, 8) void conv_chain_eo(
    const float* __restrict__ x,
    const float* __restrict__ wrep,
    float* __restrict__ hcat)
{
    __shared__ float A[ASZ];
    __shared__ float B[BSZ];

    const int tid  = threadIdx.x;
    const int wv   = __builtin_amdgcn_readfirstlane(tid >> 6);
    const int lane = tid & 63;
    // opaque zero: compiler can't prove uniformity -> weight loads stay VMEM
    const int zero = __builtin_amdgcn_ds_bpermute(0, 0);
    const int n     = blockIdx.x / NCHK;
    const int chunk = blockIdx.x % NCHK;
    const int o3 = chunk * TCH;
    const int p2 = 2*o3 - 1, p1 = 4*o3 - 3, p0 = 8*o3 - 7, xs = 16*o3 - 15;

    // stage x -> A as fp16-interleaved dwords (3 ch, 447 dw/plane):
    // dword p of plane c = (x[xs+2p], x[xs+2p+1]) as half2
    const float* xn = x + (size_t)n * 3 * LIN;
    unsigned int* Au = (unsigned int*)A;
    for (int idx = tid; idx < 3 * 447; idx += 512) {
        int c = idx / 447, p = idx - c * 447;
        int g0 = xs + 2 * p, g1 = g0 + 1;
        float v0 = (g0 >= 0 && g0 < LIN) ? xn[c * LIN + g0] : 0.f;
        float v1 = (g1 >= 0 && g1 < LIN) ? xn[c * LIN + g1] : 0.f;
        __half2 h = __floats2half2_rn(v0, v1);
        unsigned int u; __builtin_memcpy(&u, &h, 4);
        Au[c * 447 + p] = u;
    }
    __syncthreads();
    // s0: fp16 in (x), fp16 out
    stage_eo< 3, 20, 4, 5, 16, 446, 3000, 2, false>(
        A, B, nullptr, wrep + W0OFF, wrep + B0OFF, p0, o3, wv, lane, zero);
    __syncthreads();
    // s1
    stage_eo<20, 32, 4, 8, 24, 222, 1500, 2, false>(
        B, A, nullptr, wrep + W1OFF, wrep + B1OFF, p1, o3, wv, lane, zero);
    __syncthreads();
    // s2
    stage_eo<32, 64, 8, 8, 24, 110,  750, 2, false>(
        A, B, nullptr, wrep + W2OFF, wrep + B2OFF, p2, o3, wv, lane, zero);
    __syncthreads();
    // s3: split 2x32 ic across 8 waves, half2 partials via A
    stage3_split(B, A, hcat + (size_t)n * HCATW,
                 wrep + W3OFF, wrep + B3OFF, o3, wv, lane, zero);
}

// ---------------------------------------------------------------------------
// LAPACK ssyevd (n=3, uplo='L') replica: ssytrd -> ssteqr('I') -> apply Q.
// ---------------------------------------------------------------------------
__device__ __forceinline__ float fsign(float a, float b) {
    return (b >= 0.0f) ? fabsf(a) : -fabsf(a);
}
__device__ __forceinline__ float slapy2(float xx, float yy) {
    float xa = fabsf(xx), ya = fabsf(yy);
    float w = fmaxf(xa, ya), z = fminf(xa, ya);
    if (z == 0.f) return w;
    float t = z / w;
    return w * sqrtf(1.f + t*t);
}
// LAPACK 3.10+ slartg: c >= 0 always, r = sign(f)*hypot
__device__ __forceinline__ void slartg(float f, float g, float& c, float& s, float& r) {
    if (g == 0.f)      { c = 1.f; s = 0.f; r = f; }
    else if (f == 0.f) { c = 0.f; s = (g >= 0.f ? 1.f : -1.f); r = fabsf(g); }
    else {
        float d = sqrtf(f*f + g*g);
        c = fabsf(f) / d;
        r = fsign(d, f);
        s = g / r;
    }
}
__device__ void slaev2(float a, float b, float cc,
                       float& rt1, float& rt2, float& cs1, float& sn1) {
    float sm = a + cc, df = a - cc;
    float adf = fabsf(df);
    float tb = b + b, ab = fabsf(tb);
    float acmx, acmn;
    if (fabsf(a) > fabsf(cc)) { acmx = a; acmn = cc; } else { acmx = cc; acmn = a; }
    float rt;
    if (adf > ab)      { float t = ab/adf; rt = adf*sqrtf(1.f + t*t); }
    else if (adf < ab) { float t = adf/ab; rt = ab*sqrtf(1.f + t*t); }
    else rt = ab * sqrtf(2.f);
    int sgn1;
    if (sm < 0.f)      { rt1 = 0.5f*(sm - rt); sgn1 = -1; rt2 = (acmx/rt1)*acmn - (b/rt1)*b; }
    else if (sm > 0.f) { rt1 = 0.5f*(sm + rt); sgn1 =  1; rt2 = (acmx/rt1)*acmn - (b/rt1)*b; }
    else               { rt1 = 0.5f*rt; rt2 = -0.5f*rt; sgn1 = 1; }
    float cs; int sgn2;
    if (df >= 0.f) { cs = df + rt; sgn2 = 1; } else { cs = df - rt; sgn2 = -1; }
    float acs = fabsf(cs);
    if (acs > ab) {
        float ct = -tb / cs;
        sn1 = 1.f / sqrtf(1.f + ct*ct);
        cs1 = ct * sn1;
    } else {
        if (ab == 0.f) { cs1 = 1.f; sn1 = 0.f; }
        else {
            float tn = -cs / tb;
            cs1 = 1.f / sqrtf(1.f + tn*tn);
            sn1 = tn * cs1;
        }
    }
    if (sgn1 == sgn2) { float tn = cs1; cs1 = -sn1; sn1 = tn; }
}
__device__ __forceinline__ void rot_cols(float z[3][3], int jc, float c, float s) {
    for (int i = 0; i < 3; ++i) {
        float t = z[i][jc+1];
        z[i][jc+1] = c*t - s*z[i][jc];
        z[i][jc]   = s*t + c*z[i][jc];
    }
}

__device__ void ssteqr3(float d[3], float e[2], float z[3][3]) {
    const float eps    = 5.9604645e-8f;
    const float eps2   = eps * eps;
    const float safmin = 1.17549435e-38f;
    const int n = 3;
    for (int i = 0; i < 3; ++i)
        for (int j = 0; j < 3; ++j) z[i][j] = (i == j) ? 1.f : 0.f;
    const int nmaxit = n * 30;
    int jtot = 0;
    float cw[2], sw[2];
    int l1 = 1, l, m, lend, lsv, lendsv;

L10:
    if (l1 > n) goto L160;
    if (l1 > 1) e[l1-2] = 0.f;
    if (l1 <= n-1) {
        for (m = l1; m <= n-1; ++m) {
            float tst = fabsf(e[m-1]);
            if (tst == 0.f) goto L30;
            if (tst <= (sqrtf(fabsf(d[m-1])) * sqrtf(fabsf(d[m]))) * eps) {
                e[m-1] = 0.f;
                goto L30;
            }
        }
    }
    m = n;
L30:
    l = l1; lsv = l; lend = m; lendsv = lend; l1 = m + 1;
    if (lend == l) goto L10;
    if (fabsf(d[lend-1]) < fabsf(d[l-1])) { lend = lsv; l = lendsv; }
    if (lend > l) {
L40:
        if (l != lend) {
            bool found = false;
            for (m = l; m <= lend-1; ++m) {
                float tst = e[m-1]*e[m-1];
                if (tst <= (eps2*fabsf(d[m-1]))*fabsf(d[m]) + safmin) { found = true; break; }
            }
            if (!found) m = lend;
        } else m = lend;
        if (m < lend) e[m-1] = 0.f;
        {
            float p = d[l-1];
            if (m == l) {
                d[l-1] = p;
                l = l + 1;
                if (l <= lend) goto L40;
                goto L140;
            }
            if (m == l+1) {
                float rt1, rt2, c2, s2;
                slaev2(d[l-1], e[l-1], d[l], rt1, rt2, c2, s2);
                rot_cols(z, l-1, c2, s2);
                d[l-1] = rt1; d[l] = rt2; e[l-1] = 0.f;
                l += 2;
                if (l <= lend) goto L40;
                goto L140;
            }
            if (jtot == nmaxit) goto L140;
            jtot++;
            float g = (d[l] - p) / (2.f * e[l-1]);
            float r = slapy2(g, 1.f);
            g = d[m-1] - p + e[l-1] / (g + fsign(r, g));
            float s = 1.f, c = 1.f;
            p = 0.f;
            for (int i = m-1; i >= l; --i) {
                float f = s * e[i-1];
                float b = c * e[i-1];
                slartg(g, f, c, s, r);
                if (i != m-1) e[i] = r;
                g = d[i] - p;
                r = (d[i-1] - g)*s + 2.f*c*b;
                p = s * r;
                d[i] = g + p;
                g = c*r - b;
                cw[i-l] = c; sw[i-l] = -s;
            }
            for (int jj = m-l; jj >= 1; --jj)
                rot_cols(z, l + jj - 2, cw[jj-1], sw[jj-1]);
            d[l-1] = d[l-1] - p;
            e[l-1] = g;
            goto L40;
        }
    } else {
L90:
        if (l != lend) {
            bool found = false;
            for (m = l; m >= lend+1; --m) {
                float tst = e[m-2]*e[m-2];
                if (tst <= (eps2*fabsf(d[m-1]))*fabsf(d[m-2]) + safmin) { found = true; break; }
            }
            if (!found) m = lend;
        } else m = lend;
        if (m > lend) e[m-2] = 0.f;
        {
            float p = d[l-1];
            if (m == l) {
                d[l-1] = p;
                l = l - 1;
                if (l >= lend) goto L90;
                goto L140;
            }
            if (m == l-1) {
                float rt1, rt2, c2, s2;
                slaev2(d[l-2], e[l-2], d[l-1], rt1, rt2, c2, s2);
                rot_cols(z, l-2, c2, s2);
                d[l-2] = rt1; d[l-1] = rt2; e[l-2] = 0.f;
                l -= 2;
                if (l >= lend) goto L90;
                goto L140;
            }
            if (jtot == nmaxit) goto L140;
            jtot++;
            float g = (d[l-2] - p) / (2.f * e[l-2]);
            float r = slapy2(g, 1.f);
            g = d[m-1] - p + e[l-2] / (g + fsign(r, g));
            float s = 1.f, c = 1.f;
            p = 0.f;
            for (int i = m; i <= l-1; ++i) {
                float f = s * e[i-1];
                float b = c * e[i-1];
                slartg(g, f, c, s, r);
                if (i != m) e[i-2] = r;
                g = d[i-1] - p;
                r = (d[i] - g)*s + 2.f*c*b;
                p = s * r;
                d[i-1] = g + p;
                g = c*r - b;
                cw[i-m] = c; sw[i-m] = s;
            }
            for (int jj = 1; jj <= l-m; ++jj)
                rot_cols(z, m + jj - 2, cw[jj-1], sw[jj-1]);
            d[l-1] = d[l-1] - p;
            e[l-2] = g;
            goto L90;
        }
    }
L140:
    if (jtot < nmaxit) goto L10;
L160:
    for (int ii = 2; ii <= n; ++ii) {
        int i = ii - 1, k = i;
        float p = d[i-1];
        for (int j = ii; j <= n; ++j)
            if (d[j-1] < p) { k = j; p = d[j-1]; }
        if (k != i) {
            d[k-1] = d[i-1]; d[i-1] = p;
            for (int r0 = 0; r0 < 3; ++r0) {
                float t = z[r0][i-1]; z[r0][i-1] = z[r0][k-1]; z[r0][k-1] = t;
            }
        }
    }
}

// ---------------------------------------------------------------------------
// cov + eig kernel (x loads vectorized float4)
// ---------------------------------------------------------------------------
__global__ __launch_bounds__(256) void cov_eig_kernel(const float* __restrict__ x,
                                                      float* __restrict__ eigbuf,
                                                      unsigned int* __restrict__ gmax)
{
    __shared__ float part[4][9];
    const int n = blockIdx.x;
    const float* xn = x + (size_t)n * 3 * LIN;
    float v[9] = {0,0,0,0,0,0,0,0,0};
    for (int i = threadIdx.x; i < LIN / 4; i += 256) {
        float4 a = *(const float4*)(xn + 4 * i);
        float4 b = *(const float4*)(xn + LIN + 4 * i);
        float4 c = *(const float4*)(xn + 2 * LIN + 4 * i);
        v[0] += (a.x + a.y) + (a.z + a.w);
        v[1] += (b.x + b.y) + (b.z + b.w);
        v[2] += (c.x + c.y) + (c.z + c.w);
        v[3] = fmaf(a.x,a.x, fmaf(a.y,a.y, fmaf(a.z,a.z, fmaf(a.w,a.w, v[3]))));
        v[4] = fmaf(a.x,b.x, fmaf(a.y,b.y, fmaf(a.z,b.z, fmaf(a.w,b.w, v[4]))));
        v[5] = fmaf(a.x,c.x, fmaf(a.y,c.y, fmaf(a.z,c.z, fmaf(a.w,c.w, v[5]))));
        v[6] = fmaf(b.x,b.x, fmaf(b.y,b.y, fmaf(b.z,b.z, fmaf(b.w,b.w, v[6]))));
        v[7] = fmaf(b.x,c.x, fmaf(b.y,c.y, fmaf(b.z,c.z, fmaf(b.w,c.w, v[7]))));
        v[8] = fmaf(c.x,c.x, fmaf(c.y,c.y, fmaf(c.z,c.z, fmaf(c.w,c.w, v[8]))));
    }
#pragma unroll
    for (int off = 32; off > 0; off >>= 1)
#pragma unroll
        for (int i = 0; i < 9; ++i) v[i] += __shfl_down(v[i], off, 64);
    const int wv = threadIdx.x >> 6, lane = threadIdx.x & 63;
    if (lane == 0)
        for (int i = 0; i < 9; ++i) part[wv][i] = v[i];
    __syncthreads();
    if (threadIdx.x == 0) {
        float t[9];
        for (int i = 0; i < 9; ++i)
            t[i] = part[0][i] + part[1][i] + part[2][i] + part[3][i];
        const float Lf = (float)LIN;
        float m0 = t[0]/Lf, m1 = t[1]/Lf, m2 = t[2]/Lf;
        float c00 = (t[3] - Lf*m0*m0) / (Lf - 1.f);
        float c01 = (t[4] - Lf*m0*m1) / (Lf - 1.f);
        float c02 = (t[5] - Lf*m0*m2) / (Lf - 1.f);
        float c11 = (t[6] - Lf*m1*m1) / (Lf - 1.f);
        float c12 = (t[7] - Lf*m1*m2) / (Lf - 1.f);
        float c22 = (t[8] - Lf*m2*m2) / (Lf - 1.f);

        float dd[3], ee[2], tau, v2;
        {
            float a21 = c01, a31 = c02, a22 = c11, a32 = c12, a33 = c22;
            float xnorm = fabsf(a31);
            if (xnorm == 0.f) {
                tau = 0.f; v2 = 0.f;
                dd[0] = c00; dd[1] = a22; dd[2] = a33;
                ee[0] = a21; ee[1] = a32;
            } else {
                float beta = -fsign(slapy2(a21, xnorm), a21);
                tau = (beta - a21) / beta;
                v2  = a31 / (a21 - beta);
                ee[0] = beta;
                float x1 = tau*(a22 + a32*v2);
                float x2 = tau*(a32 + a33*v2);
                float al = -0.5f*tau*(x1 + x2*v2);
                float w1 = x1 + al;
                float w2 = x2 + al*v2;
                a22 -= 2.f*w1;
                a32 -= (v2*w1 + w2);
                a33 -= 2.f*v2*w2;
                dd[0] = c00; dd[1] = a22; dd[2] = a33;
                ee[1] = a32;
            }
        }
        float zz[3][3];
        ssteqr3(dd, ee, zz);
        if (tau != 0.f) {
            for (int j = 0; j < 3; ++j) {
                float sum = zz[1][j] + v2*zz[2][j];
                zz[1][j] -= tau * sum;
                zz[2][j] -= tau * v2 * sum;
            }
        }

        float* eb = eigbuf + n * 21;
        eb[0] = c00; eb[1] = c01; eb[2] = c02;
        eb[3] = c01; eb[4] = c11; eb[5] = c12;
        eb[6] = c02; eb[7] = c12; eb[8] = c22;
        eb[9] = dd[0]; eb[10] = dd[1]; eb[11] = dd[2];
        for (int c = 0; c < 3; ++c)
            for (int k = 0; k < 3; ++k) eb[12 + c*3 + k] = zz[c][k];

        float vmax = fmaxf(dd[0], fmaxf(dd[1], dd[2]));
        float cmax = 0.f;
        for (int i = 0; i < 9; ++i) cmax = fmaxf(cmax, fabsf(eb[i]));
        atomicMax(&gmax[0], __float_as_uint(vmax));
        atomicMax(&gmax[1], __float_as_uint(cmax));
    }
}

// ---------------------------------------------------------------------------
// feats -> 1x1 conv (wc) + relu, writes hcat[:, 7500:7640]
// ---------------------------------------------------------------------------
__global__ __launch_bounds__(256) void feats_kernel(const float* __restrict__ eigbuf,
                                                    const unsigned int* __restrict__ gmax,
                                                    const float* __restrict__ wc,
                                                    const float* __restrict__ bc,
                                                    float* __restrict__ hcat)
{
    const int n = blockIdx.x;
    const int t = threadIdx.x;
    if (t >= 140) return;
    const int o = t / 7, j = t % 7;
    const float* eb = eigbuf + n * 21;
    const float vmax = __uint_as_float(gmax[0]);
    const float cmax = __uint_as_float(gmax[1]);
    float f0, f1, f2;
    if (j < 3)       { f0 = eb[0*3+j]/cmax; f1 = eb[1*3+j]/cmax; f2 = eb[2*3+j]/cmax; }
    else if (j == 3) { f0 = eb[9]/vmax;     f1 = eb[10]/vmax;    f2 = eb[11]/vmax; }
    else             { int k = j-4; f0 = eb[12+0*3+k]; f1 = eb[12+1*3+k]; f2 = eb[12+2*3+k]; }
    float r = bc[o] + wc[o*3+0]*f0 + wc[o*3+1]*f1 + wc[o*3+2]*f2;
    hcat[(size_t)n*HCATW + 7500 + o*7 + j] = fmaxf(r, 0.f);
}

// ---------------------------------------------------------------------------
// FC0+FC1 fused, 8 samples per block (512 threads), h staged in LDS as fp16,
// wl0 pre-packed fp16 -> v_dot2_f32_f16 with fp32 accumulate.
// ---------------------------------------------------------------------------
__global__ __launch_bounds__(512) void fc01_kernel(const float* __restrict__ hcat,
                                                   const unsigned int* __restrict__ wl0h,
                                                   const float* __restrict__ bl0,
                                                   const float* __restrict__ wl1,
                                                   const float* __restrict__ bl1,
                                                   float* __restrict__ out)
{
    __shared__ __half hl[FCNS * HCATW];    // 122,240 B
    __shared__ float hbuf[FCNS * HID];     //   3,200 B
    const int tid = threadIdx.x;
    const int n0 = blockIdx.x * FCNS;
    // stage hcat fp32 -> fp16 LDS
    for (int i = tid; i < FCNS * (HCATW/4); i += 512) {
        int s  = i / (HCATW/4);
        int k4 = i - s * (HCATW/4);
        float4 v = *(const float4*)(hcat + (size_t)(n0 + s) * HCATW + k4 * 4);
        __half2 h01 = __floats2half2_rn(v.x, v.y);
        __half2 h23 = __floats2half2_rn(v.z, v.w);
        *(__half2*)(hl + s * HCATW + k4 * 4)     = h01;
        *(__half2*)(hl + s * HCATW + k4 * 4 + 2) = h23;
    }
    __syncthreads();
    const int wv = tid >> 6;
    const int lane = tid & 63;
    for (int ot = wv; ot < HID / 4; ot += 8) {      // 25 o-tiles of 4
        float acc[4][FCNS];
#pragma unroll
        for (int oo = 0; oo < 4; ++oo)
#pragma unroll
            for (int s = 0; s < FCNS; ++s) acc[oo][s] = 0.f;
        for (int k = lane * 8; k < HCATW; k += 512) {   // 8 halves per lane
            uint4 hv[FCNS];
#pragma unroll
            for (int s = 0; s < FCNS; ++s)
                hv[s] = *(const uint4*)(hl + s * HCATW + k);
#pragma unroll
            for (int oo = 0; oo < 4; ++oo) {
                const uint4 wp = *(const uint4*)(wl0h + (ot*4+oo) * (HCATW/2) + (k >> 1));
#pragma unroll
                for (int s = 0; s < FCNS; ++s) {
                    float a = acc[oo][s];
                    a = fdot2_f16(hv[s].x, wp.x, a);
                    a = fdot2_f16(hv[s].y, wp.y, a);
                    a = fdot2_f16(hv[s].z, wp.z, a);
                    a = fdot2_f16(hv[s].w, wp.w, a);
                    acc[oo][s] = a;
                }
            }
        }
#pragma unroll
        for (int off = 32; off > 0; off >>= 1)
#pragma unroll
            for (int oo = 0; oo < 4; ++oo)
#pragma unroll
                for (int s = 0; s < FCNS; ++s)
                    acc[oo][s] += __shfl_down(acc[oo][s], off, 64);
        if (lane == 0) {
#pragma unroll
            for (int oo = 0; oo < 4; ++oo) {
                const float b = bl0[ot*4+oo];
#pragma unroll
                for (int s = 0; s < FCNS; ++s)
                    hbuf[s * HID + ot*4+oo] = fmaxf(acc[oo][s] + b, 0.f);
            }
        }
    }
    __syncthreads();
    if (tid < 2 * FCNS) {
        const int s = tid >> 1, r = tid & 1;
        const float* w = wl1 + r * HID;
        float acc = bl1[r];
        for (int k = 0; k < HID; ++k) acc = fmaf(hbuf[s * HID + k], w[k], acc);
        out[r * NBATCH + n0 + s] = acc;
    }
}

// ---------------------------------------------------------------------------
// launch
// ---------------------------------------------------------------------------
extern "C" void kernel_launch(void* const* d_in, const int* in_sizes, int n_in,
                              void* d_out, int out_size, void* d_ws, size_t ws_size,
                              hipStream_t stream)
{
    const float* x   = (const float*)d_in[0];
    const float* w0  = (const float*)d_in[1];
    const float* b0  = (const float*)d_in[2];
    const float* w1  = (const float*)d_in[3];
    const float* b1  = (const float*)d_in[4];
    const float* w2  = (const float*)d_in[5];
    const float* b2  = (const float*)d_in[6];
    const float* w3  = (const float*)d_in[7];
    const float* b3  = (const float*)d_in[8];
    const float* wc  = (const float*)d_in[9];
    const float* bc  = (const float*)d_in[10];
    const float* wl0 = (const float*)d_in[11];
    const float* bl0 = (const float*)d_in[12];
    const float* wl1 = (const float*)d_in[13];
    const float* bl1 = (const float*)d_in[14];
    float* out = (float*)d_out;

    // workspace layout (floats)
    const size_t HCAT_N = (size_t)NBATCH * HCATW;        // 7,823,360
    const size_t EIG_N  = (size_t)NBATCH * 21;
    const size_t need_bytes = (HCAT_N + EIG_N + 4 + WREPSZ + WL0HSZ) * 4 + 16;
    if (ws_size < need_bytes) return;

    float* ws     = (float*)d_ws;
    float* hcat   = ws;
    float* eigbuf = hcat + HCAT_N;
    unsigned int* gmax = (unsigned int*)(eigbuf + EIG_N);
    float* wrep   = (float*)(gmax + 4);
    unsigned int* wl0h = (unsigned int*)(wrep + WREPSZ);

    hipMemsetAsync(gmax, 0, 2 * sizeof(unsigned int), stream);

    prep_kernel<<<(WL0HSZ + 255) / 256, 256, 0, stream>>>(
        w0, b0, w1, b1, w2, b2, w3, b3, wl0, wrep, wl0h);
    conv_chain_eo<<<NBATCH * NCHK, 512, 0, stream>>>(x, wrep, hcat);
    cov_eig_kernel<<<NBATCH, 256, 0, stream>>>(x, eigbuf, gmax);
    feats_kernel<<<NBATCH, 256, 0, stream>>>(eigbuf, gmax, wc, bc, hcat);
    fc01_kernel<<<NBATCH / FCNS, 512, 0, stream>>>(hcat, wl0h, bl0, wl1, bl1, out);
}

// Round 12
// 595.435 us; speedup vs baseline: 1.3590x; 1.0174x over previous
//
#include <hip/hip_runtime.h>
#include <hip/hip_fp16.h>
#include <math.h>

// ---------------------------------------------------------------------------
// Problem constants
// ---------------------------------------------------------------------------
#define NBATCH 1024
#define LIN    6000
#define HCATW  7640       // 20*375 + 20*7
#define HID    100

// conv-chain chunking: T=54 final(375-res) positions per block, 7 chunks.
//   JOUT chain = 8T+14, 4T+6, 2T+2, T = 446, 222, 110, 54
// R14: all-PK16 conv -> 449us, VALUBusy 92%, occ 88%, bank-conflicts 0.
// R15: split-K fc0 (256 blocks, 61KB LDS, partials to global) + tiny fc1;
//   hcat fp16 end-to-end. Conv kernel untouched.
// (R15c: second identical resubmit — R10/R11 were container-acquisition
//  failures with no compile/run evidence; source audited clean.)
#define TCH   54
#define NCHK  7

#define ASZ 3552            // max(x-buf fp16 3*447dw=1341, s1-out 3552, s3 part 1280)
#define BSZ 4460            // max(s0-out fp16 20*223dw=4460, s2-out fp16 64*55dw=3520)

// repacked-weight offsets (dwords) inside wrep — all splat-half2 PK16:
// per (ocg,ic): WSTR dwords, dword q (q<OPG*3) = splat-half2 w[oc=ocg*OPG+q/3][ic][q%3]
#define W0OFF 0             // 4*3*16   = 192
#define W1OFF 192           // 4*20*24  = 1920
#define W2OFF 2112          // 8*32*24  = 6144
#define W3OFF 8256          // 4*64*16  = 4096
#define B0OFF 12352
#define B1OFF 12372
#define B2OFF 12404
#define B3OFF 12468
#define WREPSZ 12496

#define WL0HSZ (HID * (HCATW/2))   // 382,000 dwords of packed fp16 wl0

// fc0: samples per block-group, split-K at 3824 (both halves mult of 8)
#define FCNS 8
#define KSPL 3824

typedef _Float16 v2h __attribute__((ext_vector_type(2)));

__device__ __forceinline__ float fdot2_f16(unsigned int a, unsigned int b, float c) {
#if __has_builtin(__builtin_amdgcn_fdot2)
    v2h ah, bh;
    __builtin_memcpy(&ah, &a, 4);
    __builtin_memcpy(&bh, &b, 4);
    return __builtin_amdgcn_fdot2(ah, bh, c, false);
#else
    float d;
    asm("v_dot2_f32_f16 %0, %1, %2, %3" : "=v"(d) : "v"(a), "v"(b), "v"(c));
    return d;
#endif
}

__device__ __forceinline__ __half2 u2h2(unsigned int u) {
    __half2 h; __builtin_memcpy(&h, &u, 4); return h;
}

// ---------------------------------------------------------------------------
// Weight repack: generalized splat-half2 pack.
// ---------------------------------------------------------------------------
__device__ __forceinline__ void pack_pk16g(int idx, int OC, int IC, int OCG,
                                           int OPG, int WSTR,
                                           const float* __restrict__ w,
                                           unsigned int* __restrict__ dst)
{
    if (idx >= OCG * IC * WSTR) return;
    int ocg = idx / (IC * WSTR);
    int r   = idx - ocg * (IC * WSTR);
    int ic  = r / WSTR, q = r - ic * WSTR;
    int o   = q / 3, k = q - o * 3;
    int oc  = ocg * OPG + o;
    unsigned int v = 0;
    if (o < OPG && oc < OC) {
        float wv = w[(oc * IC + ic) * 3 + k];
        unsigned int h = __half_as_ushort(__float2half(wv));
        v = h | (h << 16);
    }
    dst[idx] = v;
}

// combined: conv-weight repack + wl0 fp16 pack (one launch)
__global__ __launch_bounds__(256) void prep_kernel(
    const float* __restrict__ w0, const float* __restrict__ b0,
    const float* __restrict__ w1, const float* __restrict__ b1,
    const float* __restrict__ w2, const float* __restrict__ b2,
    const float* __restrict__ w3, const float* __restrict__ b3,
    const float* __restrict__ wl0,
    float* __restrict__ wrep, unsigned int* __restrict__ wl0h)
{
    int idx = blockIdx.x * 256 + threadIdx.x;
    if (idx < WL0HSZ) {
        float a = wl0[idx * 2], b = wl0[idx * 2 + 1];
        unsigned int lo = __half_as_ushort(__float2half(a));
        unsigned int hi = __half_as_ushort(__float2half(b));
        wl0h[idx] = lo | (hi << 16);
    }
    if (idx < 8192) {
        unsigned int* wu = (unsigned int*)wrep;
        pack_pk16g(idx, 20,  3, 4, 5, 16, w0, wu + W0OFF);
        pack_pk16g(idx, 32, 20, 4, 8, 24, w1, wu + W1OFF);
        pack_pk16g(idx, 64, 32, 8, 8, 24, w2, wu + W2OFF);
        pack_pk16g(idx, 20, 64, 4, 5, 16, w3, wu + W3OFF);
        if (idx < 20)            wrep[B0OFF + idx] = b0[idx];
        else if (idx < 52)  { int i = idx - 20;  wrep[B1OFF + i] = b1[i]; }
        else if (idx < 116) { int i = idx - 52;  wrep[B2OFF + i] = b2[i]; }
        else if (idx < 136) { int i = idx - 116; wrep[B3OFF + i] = b3[i]; }
    }
}

// ---------------------------------------------------------------------------
// One conv(K=3,SAME)+ReLU+pool2 stage on LDS buffers (all-PK16).
// 8 waves per block (512 threads), wave-strided tasks of JBLK*64 outputs.
// fp16 buffers: interleaved shorts, plane stride PIN dwords; dword p =
//   (pooled[2p], pooled[2p+1]); one ds_read2_b32 at dword jc yields
//   (e0,o0,e1,o1).
// PK16 math: splat-half2 weights; per o three v_pk_fma_f16 on the packed
//   (ae,ao) fp16 accumulator.
// ---------------------------------------------------------------------------
template<int IC, int OC, int OCG, int OPG, int WSTR, int JOUT, int LG, int JBLK,
         bool FINAL>
__device__ __forceinline__ void stage_eo(const float* __restrict__ in,
                                         float* __restrict__ out,
                                         __half* __restrict__ outg,
                                         const float* __restrict__ wrep,
                                         const float* __restrict__ brep,
                                         int pbase, int o3, int wv, int lane,
                                         int zero)
{
    constexpr int PIN  = JOUT + 1;
    constexpr int NJT  = (JOUT + 64 * JBLK - 1) / (64 * JBLK);
    for (int task = wv; task < OCG * NJT; task += 8) {
        const int ocg = task / NJT;                 // wave-uniform (wv uniform)
        const int jt  = task - ocg * NJT;
        const int j0  = jt * (64 * JBLK) + lane;
        const float* bp = brep + ocg * OPG;
        __half2 ap[JBLK][OPG];
#pragma unroll
        for (int t = 0; t < JBLK; ++t)
#pragma unroll
            for (int o = 0; o < OPG; ++o) {
                __half hb = __float2half(bp[o]);
                ap[t][o] = __halves2half2(hb, hb);
            }
        const float* wbase = wrep + ocg * (IC * WSTR) + zero;  // stays VMEM
#pragma unroll 1
        for (int ic = 0; ic < IC; ++ic) {
            const float* wp = wbase + ic * WSTR;
            float wr[WSTR];
#pragma unroll
            for (int q = 0; q < WSTR / 4; ++q)
                *(float4*)&wr[q * 4] = *(const float4*)(wp + q * 4);
#pragma unroll
            for (int t = 0; t < JBLK; ++t) {
                const int jj = j0 + t * 64;
                const int jc = (jj < JOUT) ? jj : (JOUT - 1);
                const float* ipw = in + ic * PIN;
                uint2 pw;
                __builtin_memcpy(&pw, ipw + jc, 8);   // ds_read2_b32
                const unsigned int crossu = (pw.x >> 16) | (pw.y << 16);
#pragma unroll
                for (int o = 0; o < OPG; ++o) {
                    __half2 a = ap[t][o];
                    a = __hfma2(u2h2(pw.x),   u2h2(__float_as_uint(wr[o*3+0])), a);
                    a = __hfma2(u2h2(crossu), u2h2(__float_as_uint(wr[o*3+1])), a);
                    a = __hfma2(u2h2(pw.y),   u2h2(__float_as_uint(wr[o*3+2])), a);
                    ap[t][o] = a;
                }
            }
        }

#pragma unroll
        for (int t = 0; t < JBLK; ++t) {
            const int jj = j0 + t * 64;
            if constexpr (FINAL) {
                const int gj = o3 + jj;
                if (gj < 375 && jj < JOUT) {
#pragma unroll
                    for (int o = 0; o < OPG; ++o) {
                        float ee = __low2float(ap[t][o]);
                        float oo = __high2float(ap[t][o]);
                        outg[(ocg*OPG+o) * 375 + gj] =
                            __float2half(fmaxf(fmaxf(ee, oo), 0.f));
                    }
                }
            } else {
                const int g = pbase + jj;
                const bool val = (jj < JOUT) && (g >= 0) && (g < LG);
                if (jj < JOUT) {
                    __half* dh = (__half*)out;
#pragma unroll
                    for (int o = 0; o < OPG; ++o) {
                        float ee = __low2float(ap[t][o]);
                        float oo = __high2float(ap[t][o]);
                        float v = val ? fmaxf(fmaxf(ee, oo), 0.f) : 0.f;
                        dh[(ocg*OPG+o) * JOUT + jj] = __float2half(v);
                    }
                }
            }
        }
    }
}

// ---------------------------------------------------------------------------
// Final stage (s3) split across all 8 waves: wave = (ocg 0..3) x (ic-half).
// fp16 interleaved input, PK16 math (fp16 accum per 32-ic half), fp32
// combine; half2 partials via LDS A; fp16 store to hcat.
// ---------------------------------------------------------------------------
__device__ __forceinline__ void stage3_split(const float* __restrict__ in,
                                             float* __restrict__ part,
                                             __half* __restrict__ outg,
                                             const float* __restrict__ wrep,
                                             const float* __restrict__ brep,
                                             int o3, int wv, int lane, int zero)
{
    constexpr int JOUT = 54, PIND = 55, OPG = 5, WSTR = 16;
    const int ocg = wv & 3, ih = wv >> 2;
    const int j  = lane;
    const int jc = (j < JOUT) ? j : (JOUT - 1);
    const float* bp = brep + ocg * OPG;
    __half2 ap[OPG];
#pragma unroll
    for (int o = 0; o < OPG; ++o) {
        __half hb = __float2half(ih ? 0.f : bp[o]);
        ap[o] = __halves2half2(hb, hb);
    }
    const float* wbase = wrep + (ocg * 64 + ih * 32) * WSTR + zero;
#pragma unroll 2
    for (int ic = 0; ic < 32; ++ic) {
        const float* ipw = in + (ih * 32 + ic) * PIND;
        uint2 pw;
        __builtin_memcpy(&pw, ipw + jc, 8);           // ds_read2_b32
        const unsigned int crossu = (pw.x >> 16) | (pw.y << 16);
        const float* wp = wbase + ic * WSTR;
        float wr[WSTR];
#pragma unroll
        for (int q = 0; q < WSTR / 4; ++q)
            *(float4*)&wr[q * 4] = *(const float4*)(wp + q * 4);
#pragma unroll
        for (int o = 0; o < OPG; ++o) {
            __half2 a = ap[o];
            a = __hfma2(u2h2(pw.x),   u2h2(__float_as_uint(wr[o*3+0])), a);
            a = __hfma2(u2h2(crossu), u2h2(__float_as_uint(wr[o*3+1])), a);
            a = __hfma2(u2h2(pw.y),   u2h2(__float_as_uint(wr[o*3+2])), a);
            ap[o] = a;
        }
    }
    unsigned int* pu = (unsigned int*)part;
    if (ih == 1) {
#pragma unroll
        for (int o = 0; o < OPG; ++o) {
            unsigned int u; __builtin_memcpy(&u, &ap[o], 4);
            pu[(ocg * OPG + o) * 64 + lane] = u;
        }
    }
    __syncthreads();
    if (ih == 0) {
        const int gj = o3 + j;
        if (gj < 375 && j < JOUT) {
#pragma unroll
            for (int o = 0; o < OPG; ++o) {
                __half2 p = u2h2(pu[(ocg * OPG + o) * 64 + lane]);
                float ee = __low2float(ap[o])  + __low2float(p);
                float oo = __high2float(ap[o]) + __high2float(p);
                outg[(ocg * OPG + o) * 375 + gj] =
                    __float2half(fmaxf(fmaxf(ee, oo), 0.f));
            }
        }
    }
}

// LDS (3552+4460)*4 = 32,048 B -> 4 blocks/CU (wave-capped); 8 waves/EU.
__global__ __launch_bounds__(512, 8) void conv_chain_eo(
    const float* __restrict__ x,
    const float* __restrict__ wrep,
    __half* __restrict__ hcat)
{
    __shared__ float A[ASZ];
    __shared__ float B[BSZ];

    const int tid  = threadIdx.x;
    const int wv   = __builtin_amdgcn_readfirstlane(tid >> 6);
    const int lane = tid & 63;
    // opaque zero: compiler can't prove uniformity -> weight loads stay VMEM
    const int zero = __builtin_amdgcn_ds_bpermute(0, 0);
    const int n     = blockIdx.x / NCHK;
    const int chunk = blockIdx.x % NCHK;
    const int o3 = chunk * TCH;
    const int p2 = 2*o3 - 1, p1 = 4*o3 - 3, p0 = 8*o3 - 7, xs = 16*o3 - 15;

    // stage x -> A as fp16-interleaved dwords (3 ch, 447 dw/plane)
    const float* xn = x + (size_t)n * 3 * LIN;
    unsigned int* Au = (unsigned int*)A;
    for (int idx = tid; idx < 3 * 447; idx += 512) {
        int c = idx / 447, p = idx - c * 447;
        int g0 = xs + 2 * p, g1 = g0 + 1;
        float v0 = (g0 >= 0 && g0 < LIN) ? xn[c * LIN + g0] : 0.f;
        float v1 = (g1 >= 0 && g1 < LIN) ? xn[c * LIN + g1] : 0.f;
        __half2 h = __floats2half2_rn(v0, v1);
        unsigned int u; __builtin_memcpy(&u, &h, 4);
        Au[c * 447 + p] = u;
    }
    __syncthreads();
    // s0: fp16 in (x), fp16 out
    stage_eo< 3, 20, 4, 5, 16, 446, 3000, 2, false>(
        A, B, nullptr, wrep + W0OFF, wrep + B0OFF, p0, o3, wv, lane, zero);
    __syncthreads();
    // s1
    stage_eo<20, 32, 4, 8, 24, 222, 1500, 2, false>(
        B, A, nullptr, wrep + W1OFF, wrep + B1OFF, p1, o3, wv, lane, zero);
    __syncthreads();
    // s2
    stage_eo<32, 64, 8, 8, 24, 110,  750, 2, false>(
        A, B, nullptr, wrep + W2OFF, wrep + B2OFF, p2, o3, wv, lane, zero);
    __syncthreads();
    // s3: split 2x32 ic across 8 waves, half2 partials via A, fp16 store
    stage3_split(B, A, hcat + (size_t)n * HCATW,
                 wrep + W3OFF, wrep + B3OFF, o3, wv, lane, zero);
}

// ---------------------------------------------------------------------------
// LAPACK ssyevd (n=3, uplo='L') replica: ssytrd -> ssteqr('I') -> apply Q.
// ---------------------------------------------------------------------------
__device__ __forceinline__ float fsign(float a, float b) {
    return (b >= 0.0f) ? fabsf(a) : -fabsf(a);
}
__device__ __forceinline__ float slapy2(float xx, float yy) {
    float xa = fabsf(xx), ya = fabsf(yy);
    float w = fmaxf(xa, ya), z = fminf(xa, ya);
    if (z == 0.f) return w;
    float t = z / w;
    return w * sqrtf(1.f + t*t);
}
// LAPACK 3.10+ slartg: c >= 0 always, r = sign(f)*hypot
__device__ __forceinline__ void slartg(float f, float g, float& c, float& s, float& r) {
    if (g == 0.f)      { c = 1.f; s = 0.f; r = f; }
    else if (f == 0.f) { c = 0.f; s = (g >= 0.f ? 1.f : -1.f); r = fabsf(g); }
    else {
        float d = sqrtf(f*f + g*g);
        c = fabsf(f) / d;
        r = fsign(d, f);
        s = g / r;
    }
}
__device__ void slaev2(float a, float b, float cc,
                       float& rt1, float& rt2, float& cs1, float& sn1) {
    float sm = a + cc, df = a - cc;
    float adf = fabsf(df);
    float tb = b + b, ab = fabsf(tb);
    float acmx, acmn;
    if (fabsf(a) > fabsf(cc)) { acmx = a; acmn = cc; } else { acmx = cc; acmn = a; }
    float rt;
    if (adf > ab)      { float t = ab/adf; rt = adf*sqrtf(1.f + t*t); }
    else if (adf < ab) { float t = adf/ab; rt = ab*sqrtf(1.f + t*t); }
    else rt = ab * sqrtf(2.f);
    int sgn1;
    if (sm < 0.f)      { rt1 = 0.5f*(sm - rt); sgn1 = -1; rt2 = (acmx/rt1)*acmn - (b/rt1)*b; }
    else if (sm > 0.f) { rt1 = 0.5f*(sm + rt); sgn1 =  1; rt2 = (acmx/rt1)*acmn - (b/rt1)*b; }
    else               { rt1 = 0.5f*rt; rt2 = -0.5f*rt; sgn1 = 1; }
    float cs; int sgn2;
    if (df >= 0.f) { cs = df + rt; sgn2 = 1; } else { cs = df - rt; sgn2 = -1; }
    float acs = fabsf(cs);
    if (acs > ab) {
        float ct = -tb / cs;
        sn1 = 1.f / sqrtf(1.f + ct*ct);
        cs1 = ct * sn1;
    } else {
        if (ab == 0.f) { cs1 = 1.f; sn1 = 0.f; }
        else {
            float tn = -cs / tb;
            cs1 = 1.f / sqrtf(1.f + tn*tn);
            sn1 = tn * cs1;
        }
    }
    if (sgn1 == sgn2) { float tn = cs1; cs1 = -sn1; sn1 = tn; }
}
__device__ __forceinline__ void rot_cols(float z[3][3], int jc, float c, float s) {
    for (int i = 0; i < 3; ++i) {
        float t = z[i][jc+1];
        z[i][jc+1] = c*t - s*z[i][jc];
        z[i][jc]   = s*t + c*z[i][jc];
    }
}

__device__ void ssteqr3(float d[3], float e[2], float z[3][3]) {
    const float eps    = 5.9604645e-8f;
    const float eps2   = eps * eps;
    const float safmin = 1.17549435e-38f;
    const int n = 3;
    for (int i = 0; i < 3; ++i)
        for (int j = 0; j < 3; ++j) z[i][j] = (i == j) ? 1.f : 0.f;
    const int nmaxit = n * 30;
    int jtot = 0;
    float cw[2], sw[2];
    int l1 = 1, l, m, lend, lsv, lendsv;

L10:
    if (l1 > n) goto L160;
    if (l1 > 1) e[l1-2] = 0.f;
    if (l1 <= n-1) {
        for (m = l1; m <= n-1; ++m) {
            float tst = fabsf(e[m-1]);
            if (tst == 0.f) goto L30;
            if (tst <= (sqrtf(fabsf(d[m-1])) * sqrtf(fabsf(d[m]))) * eps) {
                e[m-1] = 0.f;
                goto L30;
            }
        }
    }
    m = n;
L30:
    l = l1; lsv = l; lend = m; lendsv = lend; l1 = m + 1;
    if (lend == l) goto L10;
    if (fabsf(d[lend-1]) < fabsf(d[l-1])) { lend = lsv; l = lendsv; }
    if (lend > l) {
L40:
        if (l != lend) {
            bool found = false;
            for (m = l; m <= lend-1; ++m) {
                float tst = e[m-1]*e[m-1];
                if (tst <= (eps2*fabsf(d[m-1]))*fabsf(d[m]) + safmin) { found = true; break; }
            }
            if (!found) m = lend;
        } else m = lend;
        if (m < lend) e[m-1] = 0.f;
        {
            float p = d[l-1];
            if (m == l) {
                d[l-1] = p;
                l = l + 1;
                if (l <= lend) goto L40;
                goto L140;
            }
            if (m == l+1) {
                float rt1, rt2, c2, s2;
                slaev2(d[l-1], e[l-1], d[l], rt1, rt2, c2, s2);
                rot_cols(z, l-1, c2, s2);
                d[l-1] = rt1; d[l] = rt2; e[l-1] = 0.f;
                l += 2;
                if (l <= lend) goto L40;
                goto L140;
            }
            if (jtot == nmaxit) goto L140;
            jtot++;
            float g = (d[l] - p) / (2.f * e[l-1]);
            float r = slapy2(g, 1.f);
            g = d[m-1] - p + e[l-1] / (g + fsign(r, g));
            float s = 1.f, c = 1.f;
            p = 0.f;
            for (int i = m-1; i >= l; --i) {
                float f = s * e[i-1];
                float b = c * e[i-1];
                slartg(g, f, c, s, r);
                if (i != m-1) e[i] = r;
                g = d[i] - p;
                r = (d[i-1] - g)*s + 2.f*c*b;
                p = s * r;
                d[i] = g + p;
                g = c*r - b;
                cw[i-l] = c; sw[i-l] = -s;
            }
            for (int jj = m-l; jj >= 1; --jj)
                rot_cols(z, l + jj - 2, cw[jj-1], sw[jj-1]);
            d[l-1] = d[l-1] - p;
            e[l-1] = g;
            goto L40;
        }
    } else {
L90:
        if (l != lend) {
            bool found = false;
            for (m = l; m >= lend+1; --m) {
                float tst = e[m-2]*e[m-2];
                if (tst <= (eps2*fabsf(d[m-1]))*fabsf(d[m-2]) + safmin) { found = true; break; }
            }
            if (!found) m = lend;
        } else m = lend;
        if (m > lend) e[m-2] = 0.f;
        {
            float p = d[l-1];
            if (m == l) {
                d[l-1] = p;
                l = l - 1;
                if (l >= lend) goto L90;
                goto L140;
            }
            if (m == l-1) {
                float rt1, rt2, c2, s2;
                slaev2(d[l-2], e[l-2], d[l-1], rt1, rt2, c2, s2);
                rot_cols(z, l-2, c2, s2);
                d[l-2] = rt1; d[l-1] = rt2; e[l-2] = 0.f;
                l -= 2;
                if (l >= lend) goto L90;
                goto L140;
            }
            if (jtot == nmaxit) goto L140;
            jtot++;
            float g = (d[l-2] - p) / (2.f * e[l-2]);
            float r = slapy2(g, 1.f);
            g = d[m-1] - p + e[l-2] / (g + fsign(r, g));
            float s = 1.f, c = 1.f;
            p = 0.f;
            for (int i = m; i <= l-1; ++i) {
                float f = s * e[i-1];
                float b = c * e[i-1];
                slartg(g, f, c, s, r);
                if (i != m) e[i-2] = r;
                g = d[i-1] - p;
                r = (d[i] - g)*s + 2.f*c*b;
                p = s * r;
                d[i-1] = g + p;
                g = c*r - b;
                cw[i-m] = c; sw[i-m] = s;
            }
            for (int jj = 1; jj <= l-m; ++jj)
                rot_cols(z, m + jj - 2, cw[jj-1], sw[jj-1]);
            d[l-1] = d[l-1] - p;
            e[l-2] = g;
            goto L90;
        }
    }
L140:
    if (jtot < nmaxit) goto L10;
L160:
    for (int ii = 2; ii <= n; ++ii) {
        int i = ii - 1, k = i;
        float p = d[i-1];
        for (int j = ii; j <= n; ++j)
            if (d[j-1] < p) { k = j; p = d[j-1]; }
        if (k != i) {
            d[k-1] = d[i-1]; d[i-1] = p;
            for (int r0 = 0; r0 < 3; ++r0) {
                float t = z[r0][i-1]; z[r0][i-1] = z[r0][k-1]; z[r0][k-1] = t;
            }
        }
    }
}

// ---------------------------------------------------------------------------
// cov + eig kernel (x loads vectorized float4)
// ---------------------------------------------------------------------------
__global__ __launch_bounds__(256) void cov_eig_kernel(const float* __restrict__ x,
                                                      float* __restrict__ eigbuf,
                                                      unsigned int* __restrict__ gmax)
{
    __shared__ float part[4][9];
    const int n = blockIdx.x;
    const float* xn = x + (size_t)n * 3 * LIN;
    float v[9] = {0,0,0,0,0,0,0,0,0};
    for (int i = threadIdx.x; i < LIN / 4; i += 256) {
        float4 a = *(const float4*)(xn + 4 * i);
        float4 b = *(const float4*)(xn + LIN + 4 * i);
        float4 c = *(const float4*)(xn + 2 * LIN + 4 * i);
        v[0] += (a.x + a.y) + (a.z + a.w);
        v[1] += (b.x + b.y) + (b.z + b.w);
        v[2] += (c.x + c.y) + (c.z + c.w);
        v[3] = fmaf(a.x,a.x, fmaf(a.y,a.y, fmaf(a.z,a.z, fmaf(a.w,a.w, v[3]))));
        v[4] = fmaf(a.x,b.x, fmaf(a.y,b.y, fmaf(a.z,b.z, fmaf(a.w,b.w, v[4]))));
        v[5] = fmaf(a.x,c.x, fmaf(a.y,c.y, fmaf(a.z,c.z, fmaf(a.w,c.w, v[5]))));
        v[6] = fmaf(b.x,b.x, fmaf(b.y,b.y, fmaf(b.z,b.z, fmaf(b.w,b.w, v[6]))));
        v[7] = fmaf(b.x,c.x, fmaf(b.y,c.y, fmaf(b.z,c.z, fmaf(b.w,c.w, v[7]))));
        v[8] = fmaf(c.x,c.x, fmaf(c.y,c.y, fmaf(c.z,c.z, fmaf(c.w,c.w, v[8]))));
    }
#pragma unroll
    for (int off = 32; off > 0; off >>= 1)
#pragma unroll
        for (int i = 0; i < 9; ++i) v[i] += __shfl_down(v[i], off, 64);
    const int wv = threadIdx.x >> 6, lane = threadIdx.x & 63;
    if (lane == 0)
        for (int i = 0; i < 9; ++i) part[wv][i] = v[i];
    __syncthreads();
    if (threadIdx.x == 0) {
        float t[9];
        for (int i = 0; i < 9; ++i)
            t[i] = part[0][i] + part[1][i] + part[2][i] + part[3][i];
        const float Lf = (float)LIN;
        float m0 = t[0]/Lf, m1 = t[1]/Lf, m2 = t[2]/Lf;
        float c00 = (t[3] - Lf*m0*m0) / (Lf - 1.f);
        float c01 = (t[4] - Lf*m0*m1) / (Lf - 1.f);
        float c02 = (t[5] - Lf*m0*m2) / (Lf - 1.f);
        float c11 = (t[6] - Lf*m1*m1) / (Lf - 1.f);
        float c12 = (t[7] - Lf*m1*m2) / (Lf - 1.f);
        float c22 = (t[8] - Lf*m2*m2) / (Lf - 1.f);

        float dd[3], ee[2], tau, v2;
        {
            float a21 = c01, a31 = c02, a22 = c11, a32 = c12, a33 = c22;
            float xnorm = fabsf(a31);
            if (xnorm == 0.f) {
                tau = 0.f; v2 = 0.f;
                dd[0] = c00; dd[1] = a22; dd[2] = a33;
                ee[0] = a21; ee[1] = a32;
            } else {
                float beta = -fsign(slapy2(a21, xnorm), a21);
                tau = (beta - a21) / beta;
                v2  = a31 / (a21 - beta);
                ee[0] = beta;
                float x1 = tau*(a22 + a32*v2);
                float x2 = tau*(a32 + a33*v2);
                float al = -0.5f*tau*(x1 + x2*v2);
                float w1 = x1 + al;
                float w2 = x2 + al*v2;
                a22 -= 2.f*w1;
                a32 -= (v2*w1 + w2);
                a33 -= 2.f*v2*w2;
                dd[0] = c00; dd[1] = a22; dd[2] = a33;
                ee[1] = a32;
            }
        }
        float zz[3][3];
        ssteqr3(dd, ee, zz);
        if (tau != 0.f) {
            for (int j = 0; j < 3; ++j) {
                float sum = zz[1][j] + v2*zz[2][j];
                zz[1][j] -= tau * sum;
                zz[2][j] -= tau * v2 * sum;
            }
        }

        float* eb = eigbuf + n * 21;
        eb[0] = c00; eb[1] = c01; eb[2] = c02;
        eb[3] = c01; eb[4] = c11; eb[5] = c12;
        eb[6] = c02; eb[7] = c12; eb[8] = c22;
        eb[9] = dd[0]; eb[10] = dd[1]; eb[11] = dd[2];
        for (int c = 0; c < 3; ++c)
            for (int k = 0; k < 3; ++k) eb[12 + c*3 + k] = zz[c][k];

        float vmax = fmaxf(dd[0], fmaxf(dd[1], dd[2]));
        float cmax = 0.f;
        for (int i = 0; i < 9; ++i) cmax = fmaxf(cmax, fabsf(eb[i]));
        atomicMax(&gmax[0], __float_as_uint(vmax));
        atomicMax(&gmax[1], __float_as_uint(cmax));
    }
}

// ---------------------------------------------------------------------------
// feats -> 1x1 conv (wc) + relu, writes hcat[:, 7500:7640] (fp16)
// ---------------------------------------------------------------------------
__global__ __launch_bounds__(256) void feats_kernel(const float* __restrict__ eigbuf,
                                                    const unsigned int* __restrict__ gmax,
                                                    const float* __restrict__ wc,
                                                    const float* __restrict__ bc,
                                                    __half* __restrict__ hcat)
{
    const int n = blockIdx.x;
    const int t = threadIdx.x;
    if (t >= 140) return;
    const int o = t / 7, j = t % 7;
    const float* eb = eigbuf + n * 21;
    const float vmax = __uint_as_float(gmax[0]);
    const float cmax = __uint_as_float(gmax[1]);
    float f0, f1, f2;
    if (j < 3)       { f0 = eb[0*3+j]/cmax; f1 = eb[1*3+j]/cmax; f2 = eb[2*3+j]/cmax; }
    else if (j == 3) { f0 = eb[9]/vmax;     f1 = eb[10]/vmax;    f2 = eb[11]/vmax; }
    else             { int k = j-4; f0 = eb[12+0*3+k]; f1 = eb[12+1*3+k]; f2 = eb[12+2*3+k]; }
    float r = bc[o] + wc[o*3+0]*f0 + wc[o*3+1]*f1 + wc[o*3+2]*f2;
    hcat[(size_t)n*HCATW + 7500 + o*7 + j] = __float2half(fmaxf(r, 0.f));
}

// ---------------------------------------------------------------------------
// FC0 split-K: 256 blocks = (128 sample-groups) x (2 k-halves @ KSPL=3824).
// Each block stages its k-half of 8 samples' fp16 h (61KB LDS), computes
// raw partial dot products (no bias/relu), writes to hpart[kh][n][o].
// All 256 CUs active; wl0h HBM traffic unchanged (196MB).
// ---------------------------------------------------------------------------
__global__ __launch_bounds__(512) void fc0_kernel(const __half* __restrict__ hcat,
                                                  const unsigned int* __restrict__ wl0h,
                                                  float* __restrict__ hpart)
{
    __shared__ __half hl[FCNS * KSPL];     // 61,184 B
    const int tid = threadIdx.x;
    const int g  = blockIdx.x >> 1;
    const int kh = blockIdx.x & 1;
    const int k0   = kh ? KSPL : 0;
    const int KLEN = kh ? (HCATW - KSPL) : KSPL;   // 3816 or 3824 (both %8==0)
    const int n0 = g * FCNS;
    for (int i = tid; i < FCNS * (KLEN / 8); i += 512) {
        int s  = i / (KLEN / 8);
        int k8 = i - s * (KLEN / 8);
        *(uint4*)(hl + s * KLEN + k8 * 8) =
            *(const uint4*)(hcat + (size_t)(n0 + s) * HCATW + k0 + k8 * 8);
    }
    __syncthreads();
    const int wv = tid >> 6;
    const int lane = tid & 63;
    for (int ot = wv; ot < HID / 4; ot += 8) {      // 25 o-tiles of 4
        float acc[4][FCNS];
#pragma unroll
        for (int oo = 0; oo < 4; ++oo)
#pragma unroll
            for (int s = 0; s < FCNS; ++s) acc[oo][s] = 0.f;
        for (int k = lane * 8; k < KLEN; k += 512) {   // 8 halves per lane
            uint4 hv[FCNS];
#pragma unroll
            for (int s = 0; s < FCNS; ++s)
                hv[s] = *(const uint4*)(hl + s * KLEN + k);
#pragma unroll
            for (int oo = 0; oo < 4; ++oo) {
                const uint4 wp = *(const uint4*)(wl0h + (ot*4+oo) * (HCATW/2)
                                                 + ((k0 + k) >> 1));
#pragma unroll
                for (int s = 0; s < FCNS; ++s) {
                    float a = acc[oo][s];
                    a = fdot2_f16(hv[s].x, wp.x, a);
                    a = fdot2_f16(hv[s].y, wp.y, a);
                    a = fdot2_f16(hv[s].z, wp.z, a);
                    a = fdot2_f16(hv[s].w, wp.w, a);
                    acc[oo][s] = a;
                }
            }
        }
#pragma unroll
        for (int off = 32; off > 0; off >>= 1)
#pragma unroll
            for (int oo = 0; oo < 4; ++oo)
#pragma unroll
                for (int s = 0; s < FCNS; ++s)
                    acc[oo][s] += __shfl_down(acc[oo][s], off, 64);
        if (lane == 0) {
#pragma unroll
            for (int oo = 0; oo < 4; ++oo)
#pragma unroll
                for (int s = 0; s < FCNS; ++s)
                    hpart[((size_t)kh * NBATCH + n0 + s) * HID + ot*4+oo] =
                        acc[oo][s];
        }
    }
}

// ---------------------------------------------------------------------------
// FC1: combine the two k-half partials + bias + relu, then final 100->2 dot.
// ---------------------------------------------------------------------------
__global__ __launch_bounds__(256) void fc1_kernel(const float* __restrict__ hpart,
                                                  const float* __restrict__ bl0,
                                                  const float* __restrict__ wl1,
                                                  const float* __restrict__ bl1,
                                                  float* __restrict__ out)
{
    int idx = blockIdx.x * 256 + threadIdx.x;
    if (idx >= 2 * NBATCH) return;
    const int s = idx >> 1, r = idx & 1;
    const float* p0 = hpart + (size_t)s * HID;
    const float* p1 = hpart + ((size_t)NBATCH + s) * HID;
    const float* w = wl1 + r * HID;
    float acc = bl1[r];
    for (int k = 0; k < HID; ++k) {
        float h = fmaxf(p0[k] + p1[k] + bl0[k], 0.f);
        acc = fmaf(h, w[k], acc);
    }
    out[r * NBATCH + s] = acc;
}

// ---------------------------------------------------------------------------
// launch
// ---------------------------------------------------------------------------
extern "C" void kernel_launch(void* const* d_in, const int* in_sizes, int n_in,
                              void* d_out, int out_size, void* d_ws, size_t ws_size,
                              hipStream_t stream)
{
    const float* x   = (const float*)d_in[0];
    const float* w0  = (const float*)d_in[1];
    const float* b0  = (const float*)d_in[2];
    const float* w1  = (const float*)d_in[3];
    const float* b1  = (const float*)d_in[4];
    const float* w2  = (const float*)d_in[5];
    const float* b2  = (const float*)d_in[6];
    const float* w3  = (const float*)d_in[7];
    const float* b3  = (const float*)d_in[8];
    const float* wc  = (const float*)d_in[9];
    const float* bc  = (const float*)d_in[10];
    const float* wl0 = (const float*)d_in[11];
    const float* bl0 = (const float*)d_in[12];
    const float* wl1 = (const float*)d_in[13];
    const float* bl1 = (const float*)d_in[14];
    float* out = (float*)d_out;

    // workspace layout: hcat fp16 first, then fp32/uint tail
    const size_t HCAT_N = (size_t)NBATCH * HCATW;        // halves
    const size_t EIG_N  = (size_t)NBATCH * 21;
    const size_t HPART_N = 2 * (size_t)NBATCH * HID;
    const size_t need_bytes = HCAT_N * 2 +
        (EIG_N + 4 + WREPSZ + WL0HSZ + HPART_N) * 4 + 16;
    if (ws_size < need_bytes) return;

    __half* hcat  = (__half*)d_ws;
    float* eigbuf = (float*)(hcat + HCAT_N);             // 2-byte*even = 4-aligned
    unsigned int* gmax = (unsigned int*)(eigbuf + EIG_N);
    float* wrep   = (float*)(gmax + 4);
    unsigned int* wl0h = (unsigned int*)(wrep + WREPSZ);
    float* hpart  = (float*)(wl0h + WL0HSZ);

    hipMemsetAsync(gmax, 0, 2 * sizeof(unsigned int), stream);

    prep_kernel<<<(WL0HSZ + 255) / 256, 256, 0, stream>>>(
        w0, b0, w1, b1, w2, b2, w3, b3, wl0, wrep, wl0h);
    conv_chain_eo<<<NBATCH * NCHK, 512, 0, stream>>>(x, wrep, hcat);
    cov_eig_kernel<<<NBATCH, 256, 0, stream>>>(x, eigbuf, gmax);
    feats_kernel<<<NBATCH, 256, 0, stream>>>(eigbuf, gmax, wc, bc, hcat);
    fc0_kernel<<<(NBATCH / FCNS) * 2, 512, 0, stream>>>(hcat, wl0h, hpart);
    fc1_kernel<<<(2 * NBATCH + 255) / 256, 256, 0, stream>>>(hpart, bl0, wl1, bl1, out);
}